// Round 2
// baseline (1694.720 us; speedup 1.0000x reference)
//
#include <hip/hip_runtime.h>
#include <hip/hip_bf16.h>

typedef __hip_bfloat16 bf16;

// Problem constants (B=32, H=W=56, C=192, NH=6, WS=7)
#define BB 32
#define HH 56
#define WW 56
#define CC 192
#define LL 3136            // 56*56
#define MM (BB*LL)         // 100352 tokens
#define C3 576
#define HIDN 384
#define NHEAD 6
#define HD 32
#define NWIN 2048          // B * 8*8

__device__ __forceinline__ float us2f(unsigned short u) {
    union { unsigned int i; float f; } v; v.i = ((unsigned int)u) << 16; return v.f;
}
__device__ __forceinline__ float b2f(bf16 h) { return __bfloat162float(h); }
__device__ __forceinline__ bf16 f2b(float f) { return __float2bfloat16(f); }
__device__ __forceinline__ float ldv(const bf16* p) { return b2f(*p); }
__device__ __forceinline__ float ldv(const float* p) { return *p; }
__device__ __forceinline__ void stv(bf16* p, float v) { *p = f2b(v); }
__device__ __forceinline__ void stv(float* p, float v) { *p = v; }
__device__ __forceinline__ float gelu_exact(float x) {
    return 0.5f * x * (1.0f + erff(x * 0.70710678118654752f));
}

// ---------------- LayerNorm: one wave (64 lanes) per row of 192 ----------------
template<typename IT>
__global__ __launch_bounds__(256)
void ln_kernel(const IT* __restrict__ in, const float* __restrict__ g,
               const float* __restrict__ bvec, bf16* __restrict__ out)
{
    int wid = threadIdx.x >> 6, lane = threadIdx.x & 63;
    int row = blockIdx.x * 4 + wid;
    const IT* p = in + (size_t)row * CC;
    float x0 = ldv(p + lane);
    float x1 = ldv(p + lane + 64);
    float x2 = ldv(p + lane + 128);
    float s  = x0 + x1 + x2;
    float sq = x0*x0 + x1*x1 + x2*x2;
    #pragma unroll
    for (int o = 32; o > 0; o >>= 1) {
        s  += __shfl_xor(s,  o, 64);
        sq += __shfl_xor(sq, o, 64);
    }
    float mean = s * (1.0f / CC);
    float var  = sq * (1.0f / CC) - mean * mean;
    float inv  = rsqrtf(fmaxf(var, 0.0f) + 1e-5f);
    bf16* q = out + (size_t)row * CC;
    q[lane]       = f2b((x0 - mean) * inv * g[lane]       + bvec[lane]);
    q[lane + 64]  = f2b((x1 - mean) * inv * g[lane + 64]  + bvec[lane + 64]);
    q[lane + 128] = f2b((x2 - mean) * inv * g[lane + 128] + bvec[lane + 128]);
}

// ---------------- Generic tiled GEMM: out[M,N] = act(A[M,K] @ W[N,K]^T + bias) (+resid) ----
// A is bf16 (workspace); W/bias are f32 (model inputs). ACT: 0=none, 1=gelu.
// Tiles: BM=BN=64, BK=32. 256 threads, 4x4 per thread.
template<int ACT, bool RESID, typename RT, typename OT>
__global__ __launch_bounds__(256)
void gemm_kernel(const bf16* __restrict__ A, const float* __restrict__ Wt,
                 const float* __restrict__ bias, const RT* __restrict__ resid,
                 OT* __restrict__ out, int Mm, int Nn, int Kk)
{
    __shared__ __align__(16) float As[32][68];
    __shared__ __align__(16) float Bs[32][68];
    const int m0 = blockIdx.y * 64;
    const int n0 = blockIdx.x * 64;
    const int t  = threadIdx.x;
    const int tx = t & 15, ty = t >> 4;
    float acc[4][4] = {{0.f}};

    for (int k0 = 0; k0 < Kk; k0 += 32) {
        #pragma unroll
        for (int vi = t; vi < 512; vi += 256) {
            int i = vi >> 3, k4 = vi & 7;
            uint2 p = *reinterpret_cast<const uint2*>(A + (size_t)(m0 + i) * Kk + k0 + (k4 << 2));
            As[(k4<<2)+0][i] = us2f((unsigned short)(p.x & 0xffff));
            As[(k4<<2)+1][i] = us2f((unsigned short)(p.x >> 16));
            As[(k4<<2)+2][i] = us2f((unsigned short)(p.y & 0xffff));
            As[(k4<<2)+3][i] = us2f((unsigned short)(p.y >> 16));
        }
        #pragma unroll
        for (int vi = t; vi < 512; vi += 256) {
            int i = vi >> 3, k4 = vi & 7;
            float4 p = *reinterpret_cast<const float4*>(Wt + (size_t)(n0 + i) * Kk + k0 + (k4 << 2));
            Bs[(k4<<2)+0][i] = p.x;
            Bs[(k4<<2)+1][i] = p.y;
            Bs[(k4<<2)+2][i] = p.z;
            Bs[(k4<<2)+3][i] = p.w;
        }
        __syncthreads();
        #pragma unroll
        for (int kk = 0; kk < 32; ++kk) {
            float4 av = *reinterpret_cast<const float4*>(&As[kk][ty << 2]);
            float4 bv = *reinterpret_cast<const float4*>(&Bs[kk][tx << 2]);
            float a_[4] = {av.x, av.y, av.z, av.w};
            float b_[4] = {bv.x, bv.y, bv.z, bv.w};
            #pragma unroll
            for (int u = 0; u < 4; ++u)
                #pragma unroll
                for (int v = 0; v < 4; ++v)
                    acc[u][v] += a_[u] * b_[v];
        }
        __syncthreads();
    }

    int rbase = m0 + (ty << 2), cbase = n0 + (tx << 2);
    #pragma unroll
    for (int u = 0; u < 4; ++u) {
        #pragma unroll
        for (int v = 0; v < 4; ++v) {
            float c = acc[u][v];
            if (bias) c += bias[cbase + v];
            if (ACT == 1) c = gelu_exact(c);
            if (RESID) c += ldv(resid + (size_t)(rbase + u) * Nn + cbase + v);
            stv(out + (size_t)(rbase + u) * Nn + cbase + v, c);
        }
    }
}

// ---------------- Window attention: one block per (window, head) ----------------
__global__ __launch_bounds__(256)
void winattn_kernel(const bf16* __restrict__ qkv, bf16* __restrict__ aw)
{
    const int wi = blockIdx.x;           // 0..2047
    const int head = blockIdx.y;         // 0..5
    const int b = wi >> 6;
    const int wr = wi & 63;
    const int wy = wr >> 3, wx = wr & 7;
    const int t = threadIdx.x;
    const float scale = 0.1767766952966369f;   // 32^-0.5

    __shared__ float qs[49][32], ks[49][32], vs[49][32];
    __shared__ float S[49][52];

    for (int e = t; e < 49 * 32; e += 256) {
        int i = e >> 5, d = e & 31;
        int iy = i / 7, ix = i % 7;
        size_t l = (size_t)(wy * 7 + iy) * 56 + wx * 7 + ix;
        const bf16* base = qkv + ((size_t)b * LL + l) * C3 + head * HD + d;
        qs[i][d] = b2f(base[0])   * scale;
        ks[i][d] = b2f(base[192]);
        vs[i][d] = b2f(base[384]);
    }
    __syncthreads();

    for (int e = t; e < 49 * 49; e += 256) {
        int i = e / 49, j = e % 49;
        float a = 0.f;
        #pragma unroll
        for (int d = 0; d < 32; ++d) a += qs[i][d] * ks[j][d];
        S[i][j] = a;
    }
    __syncthreads();

    if (t < 49) {
        float m = -1e30f;
        for (int j = 0; j < 49; ++j) m = fmaxf(m, S[t][j]);
        float s = 0.f;
        for (int j = 0; j < 49; ++j) { float e_ = expf(S[t][j] - m); S[t][j] = e_; s += e_; }
        float inv = 1.f / s;
        for (int j = 0; j < 49; ++j) S[t][j] *= inv;
    }
    __syncthreads();

    for (int e = t; e < 49 * 32; e += 256) {
        int i = e >> 5, d = e & 31;
        float a = 0.f;
        #pragma unroll
        for (int j = 0; j < 49; ++j) a += S[i][j] * vs[j][d];
        int iy = i / 7, ix = i % 7;
        size_t l = (size_t)(wy * 7 + iy) * 56 + wx * 7 + ix;
        aw[((size_t)b * LL + l) * CC + head * HD + d] = f2b(a);
    }
}

// ---------------- Depthwise 3x3 (SAME, zero pad) + exact GELU ----------------
__global__ __launch_bounds__(256)
void dwconv_kernel(const bf16* __restrict__ xn, const float* __restrict__ w,
                   bf16* __restrict__ out)
{
    int idx = blockIdx.x * 256 + threadIdx.x;
    if (idx >= MM * CC) return;
    int c  = idx % CC;
    int t1 = idx / CC;
    int w_ = t1 % WW;
    int t2 = t1 / WW;
    int h_ = t2 % HH;
    int b  = t2 / HH;
    float acc = 0.f;
    #pragma unroll
    for (int ky = 0; ky < 3; ++ky) {
        int hy = h_ + ky - 1;
        if (hy < 0 || hy >= HH) continue;
        #pragma unroll
        for (int kx = 0; kx < 3; ++kx) {
            int wx_ = w_ + kx - 1;
            if (wx_ < 0 || wx_ >= WW) continue;
            acc += b2f(xn[(((size_t)b * HH + hy) * WW + wx_) * CC + c]) *
                   w[c * 9 + ky * 3 + kx];
        }
    }
    out[idx] = f2b(gelu_exact(acc));
}

// ---------------- column (spatial) sum of xn per (b, c) ----------------
__global__ __launch_bounds__(192)
void colsum_kernel(const bf16* __restrict__ xn, float* __restrict__ colsum)
{
    int b = blockIdx.y, g = blockIdx.x, c = threadIdx.x;
    float acc = 0.f;
    int l0 = g * 196;
    for (int l = l0; l < l0 + 196; ++l)
        acc += b2f(xn[((size_t)b * LL + l) * CC + c]);
    atomicAdd(&colsum[b * CC + c], acc);
}

__global__ __launch_bounds__(192)
void gate_kernel(const float* __restrict__ colsum, const float* __restrict__ gw,
                 const float* __restrict__ gb, float* __restrict__ gate)
{
    __shared__ float cm[CC];
    int b = blockIdx.x, o = threadIdx.x;
    cm[o] = colsum[b * CC + o] * (1.0f / LL);
    __syncthreads();
    float acc = gb[o];
    for (int c = 0; c < CC; ++c) acc += gw[o * CC + c] * cm[c];
    gate[b * CC + o] = 1.0f / (1.0f + expf(-acc));
}

// ---------------- xf = x_attn + ld + xn * gate[b,c] ----------------
__global__ __launch_bounds__(256)
void combine_kernel(const bf16* __restrict__ xattn, const bf16* __restrict__ ld,
                    const bf16* __restrict__ xn, const float* __restrict__ gate,
                    bf16* __restrict__ xf)
{
    int idx = blockIdx.x * 256 + threadIdx.x;
    if (idx >= MM * CC) return;
    int c = idx % CC;
    int b = idx / (LL * CC);
    xf[idx] = f2b(b2f(xattn[idx]) + b2f(ld[idx]) + b2f(xn[idx]) * gate[b * CC + c]);
}

// ---------------- means over H (-> [B][W][C]) and over W (-> [B][H][C]) ----------------
__global__ __launch_bounds__(256)
void mean_h_kernel(const bf16* __restrict__ xf, float* __restrict__ mh)
{
    int idx = blockIdx.x * 256 + threadIdx.x;
    if (idx >= BB * WW * CC) return;
    int c  = idx % CC;
    int w_ = (idx / CC) % WW;
    int b  = idx / (CC * WW);
    float s = 0.f;
    for (int h_ = 0; h_ < HH; ++h_)
        s += b2f(xf[(((size_t)b * HH + h_) * WW + w_) * CC + c]);
    mh[idx] = s * (1.0f / HH);
}

__global__ __launch_bounds__(256)
void mean_w_kernel(const bf16* __restrict__ xf, float* __restrict__ mw)
{
    int idx = blockIdx.x * 256 + threadIdx.x;
    if (idx >= BB * HH * CC) return;
    int c  = idx % CC;
    int h_ = (idx / CC) % HH;
    int b  = idx / (CC * HH);
    float s = 0.f;
    for (int w_ = 0; w_ < WW; ++w_)
        s += b2f(xf[(((size_t)b * HH + h_) * WW + w_) * CC + c]);
    mw[idx] = s * (1.0f / WW);
}

// ---------------- logits over one spatial axis + softmax over the 56 positions ------------
// mean: [B][56][C] f32; out: [B][192][56] f32. One block per (o, b), 64 lanes.
__global__ __launch_bounds__(64)
void axsoftmax_kernel(const float* __restrict__ mean, const float* __restrict__ w,
                      const float* __restrict__ bias, float* __restrict__ out)
{
    __shared__ float wrow[CC];
    int o = blockIdx.x, b = blockIdx.y, lane = threadIdx.x;
    for (int c = lane; c < CC; c += 64) wrow[c] = w[o * CC + c];
    __syncthreads();
    float logit = -1e30f;
    if (lane < 56) {
        const float* mr = mean + ((size_t)b * 56 + lane) * CC;
        float a = bias[o];
        for (int c = 0; c < CC; ++c) a += wrow[c] * mr[c];
        logit = a;
    }
    float m = logit;
    #pragma unroll
    for (int off = 32; off > 0; off >>= 1) m = fmaxf(m, __shfl_xor(m, off, 64));
    float e = (lane < 56) ? expf(logit - m) : 0.f;
    float s = e;
    #pragma unroll
    for (int off = 32; off > 0; off >>= 1) s += __shfl_xor(s, off, 64);
    if (lane < 56) out[((size_t)b * CC + o) * 56 + lane] = e / s;
}

// ---------------- xf2 = xf * a_s[b,c,h] * a_t[b,c,w] * 2 ----------------
__global__ __launch_bounds__(256)
void modulate_kernel(const bf16* __restrict__ xf, const float* __restrict__ a_s,
                     const float* __restrict__ a_t, bf16* __restrict__ xf2)
{
    int idx = blockIdx.x * 256 + threadIdx.x;
    if (idx >= MM * CC) return;
    int c  = idx % CC;
    int t1 = idx / CC;
    int w_ = t1 % WW;
    int t2 = t1 / WW;
    int h_ = t2 % HH;
    int b  = t2 / HH;
    float v = b2f(xf[idx]) * a_s[((size_t)b * CC + c) * 56 + h_]
                           * a_t[((size_t)b * CC + c) * 56 + w_] * 2.0f;
    xf2[idx] = f2b(v);
}

// =======================================================================================
extern "C" void kernel_launch(void* const* d_in, const int* in_sizes, int n_in,
                              void* d_out, int out_size, void* d_ws, size_t ws_size,
                              hipStream_t stream)
{
    const float* x      = (const float*)d_in[0];
    const float* ln1_g  = (const float*)d_in[3];
    const float* ln1_b  = (const float*)d_in[4];
    const float* qkv_w  = (const float*)d_in[5];
    const float* qkv_b  = (const float*)d_in[6];
    const float* proj_w = (const float*)d_in[7];
    const float* proj_b = (const float*)d_in[8];
    const float* dw_w   = (const float*)d_in[9];
    const float* pw_w   = (const float*)d_in[10];
    const float* gate_w = (const float*)d_in[11];
    const float* gate_b = (const float*)d_in[12];
    const float* temp_w = (const float*)d_in[13];
    const float* temp_b = (const float*)d_in[14];
    const float* spec_w = (const float*)d_in[15];
    const float* spec_b = (const float*)d_in[16];
    const float* fuse_w = (const float*)d_in[17];
    const float* ln2_g  = (const float*)d_in[18];
    const float* ln2_b  = (const float*)d_in[19];
    const float* mlp1_w = (const float*)d_in[20];
    const float* mlp1_b = (const float*)d_in[21];
    const float* mlp2_w = (const float*)d_in[22];
    const float* mlp2_b = (const float*)d_in[23];
    float* out = (float*)d_out;

    const size_t SLOT = (size_t)MM * CC * sizeof(bf16);   // 38,535,168 B
    char* ws = (char*)d_ws;
    const size_t smalls = 2 * 6144 * 4 + 4 * (size_t)BB * 56 * CC * 4;
    if (ws_size < 5 * SLOT + smalls) return;   // workspace insufficient — visible failure

    bf16* s_xn    = (bf16*)(ws);
    bf16* s_qkv   = (bf16*)(ws + SLOT);        // 3 slots
    bf16* s_aw    = (bf16*)(ws + 4 * SLOT);
    bf16* s_xattn = (bf16*)(ws + SLOT);        // reuse qkv slot 1
    bf16* s_dwg   = (bf16*)(ws + 2 * SLOT);
    bf16* s_ld    = (bf16*)(ws + 3 * SLOT);
    bf16* s_xf    = (bf16*)(ws + 4 * SLOT);    // reuse aw
    bf16* s_xf2   = (bf16*)(ws);               // reuse xn
    bf16* s_x2    = (bf16*)(ws + SLOT);        // reuse xattn
    bf16* s_hn    = (bf16*)(ws + 2 * SLOT);
    bf16* s_h1    = (bf16*)(ws + 3 * SLOT);    // spans slots 3..4 (384 ch)

    float* colsum = (float*)(ws + 5 * SLOT);
    float* gatebuf = colsum + BB * CC;
    float* mean_h = gatebuf + BB * CC;
    float* mean_w = mean_h + (size_t)BB * 56 * CC;
    float* a_t    = mean_w + (size_t)BB * 56 * CC;
    float* a_s    = a_t    + (size_t)BB * CC * 56;

    const int EW_BLOCKS = (MM * CC + 255) / 256;   // 75264

    // 1. LN1
    ln_kernel<float><<<MM / 4, 256, 0, stream>>>(x, ln1_g, ln1_b, s_xn);
    // 2. qkv
    gemm_kernel<0, false, bf16, bf16><<<dim3(C3 / 64, MM / 64), 256, 0, stream>>>(
        s_xn, qkv_w, qkv_b, (const bf16*)nullptr, s_qkv, MM, C3, CC);
    // 3. window attention
    winattn_kernel<<<dim3(NWIN, NHEAD), 256, 0, stream>>>(s_qkv, s_aw);
    // 4. proj
    gemm_kernel<0, false, bf16, bf16><<<dim3(CC / 64, MM / 64), 256, 0, stream>>>(
        s_aw, proj_w, proj_b, (const bf16*)nullptr, s_xattn, MM, CC, CC);
    // 5. depthwise + gelu
    dwconv_kernel<<<EW_BLOCKS, 256, 0, stream>>>(s_xn, dw_w, s_dwg);
    // 6. pointwise (no bias)
    gemm_kernel<0, false, bf16, bf16><<<dim3(CC / 64, MM / 64), 256, 0, stream>>>(
        s_dwg, pw_w, (const float*)nullptr, (const bf16*)nullptr, s_ld, MM, CC, CC);
    // 7. gate
    hipMemsetAsync(colsum, 0, BB * CC * sizeof(float), stream);
    colsum_kernel<<<dim3(16, BB), 192, 0, stream>>>(s_xn, colsum);
    gate_kernel<<<BB, 192, 0, stream>>>(colsum, gate_w, gate_b, gatebuf);
    // 8. xf = x_attn + ld + xn*gate
    combine_kernel<<<EW_BLOCKS, 256, 0, stream>>>(s_xattn, s_ld, s_xn, gatebuf, s_xf);
    // 9. axis means
    mean_h_kernel<<<(BB * WW * CC + 255) / 256, 256, 0, stream>>>(s_xf, mean_h);
    mean_w_kernel<<<(BB * HH * CC + 255) / 256, 256, 0, stream>>>(s_xf, mean_w);
    // 10. a_t (temporal, over W) and a_s (spectral, over H)
    axsoftmax_kernel<<<dim3(CC, BB), 64, 0, stream>>>(mean_h, temp_w, temp_b, a_t);
    axsoftmax_kernel<<<dim3(CC, BB), 64, 0, stream>>>(mean_w, spec_w, spec_b, a_s);
    // 11. modulate
    modulate_kernel<<<EW_BLOCKS, 256, 0, stream>>>(s_xf, a_s, a_t, s_xf2);
    // 12. fuse (no bias) + residual from original x -> x2
    gemm_kernel<0, true, float, bf16><<<dim3(CC / 64, MM / 64), 256, 0, stream>>>(
        s_xf2, fuse_w, (const float*)nullptr, x, s_x2, MM, CC, CC);
    // 13. LN2
    ln_kernel<bf16><<<MM / 4, 256, 0, stream>>>(s_x2, ln2_g, ln2_b, s_hn);
    // 14. MLP1 + gelu
    gemm_kernel<1, false, bf16, bf16><<<dim3(HIDN / 64, MM / 64), 256, 0, stream>>>(
        s_hn, mlp1_w, mlp1_b, (const bf16*)nullptr, s_h1, MM, HIDN, CC);
    // 15. MLP2 + residual -> out (f32)
    gemm_kernel<0, true, bf16, float><<<dim3(CC / 64, MM / 64), 256, 0, stream>>>(
        s_h1, mlp2_w, mlp2_b, s_x2, out, MM, CC, HIDN);
}

// Round 3
// 987.202 us; speedup vs baseline: 1.7167x; 1.7167x over previous
//
#include <hip/hip_runtime.h>
#include <hip/hip_bf16.h>

typedef __hip_bfloat16 bf16;

// Problem constants (B=32, H=W=56, C=192, NH=6, WS=7)
#define BB 32
#define HH 56
#define WW 56
#define CC 192
#define LL 3136            // 56*56
#define MM (BB*LL)         // 100352 tokens
#define C3 576
#define HIDN 384
#define NHEAD 6
#define HD 32
#define NWIN 2048          // B * 8*8

typedef short short8 __attribute__((ext_vector_type(8)));
typedef float f32x4 __attribute__((ext_vector_type(4)));

__device__ __forceinline__ float us2f(unsigned short u) {
    union { unsigned int i; float f; } v; v.i = ((unsigned int)u) << 16; return v.f;
}
__device__ __forceinline__ float b2f(bf16 h) { return __bfloat162float(h); }
__device__ __forceinline__ bf16 f2b(float f) { return __float2bfloat16(f); }
__device__ __forceinline__ float ldv(const bf16* p) { return b2f(*p); }
__device__ __forceinline__ float ldv(const float* p) { return *p; }
__device__ __forceinline__ void stv(bf16* p, float v) { *p = f2b(v); }
__device__ __forceinline__ void stv(float* p, float v) { *p = v; }
__device__ __forceinline__ float gelu_exact(float x) {
    return 0.5f * x * (1.0f + erff(x * 0.70710678118654752f));
}

// ---------------- f32 -> bf16 weight conversion ----------------
__global__ __launch_bounds__(256)
void cvt_kernel(const float* __restrict__ src, bf16* __restrict__ dst, int n)
{
    int i = blockIdx.x * 256 + threadIdx.x;
    if (i < n) dst[i] = f2b(src[i]);
}

// ---------------- LayerNorm: one wave (64 lanes) per row of 192 ----------------
template<typename IT>
__global__ __launch_bounds__(256)
void ln_kernel(const IT* __restrict__ in, const float* __restrict__ g,
               const float* __restrict__ bvec, bf16* __restrict__ out)
{
    int wid = threadIdx.x >> 6, lane = threadIdx.x & 63;
    int row = blockIdx.x * 4 + wid;
    const IT* p = in + (size_t)row * CC;
    float x0 = ldv(p + lane);
    float x1 = ldv(p + lane + 64);
    float x2 = ldv(p + lane + 128);
    float s  = x0 + x1 + x2;
    float sq = x0*x0 + x1*x1 + x2*x2;
    #pragma unroll
    for (int o = 32; o > 0; o >>= 1) {
        s  += __shfl_xor(s,  o, 64);
        sq += __shfl_xor(sq, o, 64);
    }
    float mean = s * (1.0f / CC);
    float var  = sq * (1.0f / CC) - mean * mean;
    float inv  = rsqrtf(fmaxf(var, 0.0f) + 1e-5f);
    bf16* q = out + (size_t)row * CC;
    q[lane]       = f2b((x0 - mean) * inv * g[lane]       + bvec[lane]);
    q[lane + 64]  = f2b((x1 - mean) * inv * g[lane + 64]  + bvec[lane + 64]);
    q[lane + 128] = f2b((x2 - mean) * inv * g[lane + 128] + bvec[lane + 128]);
}

// ---------------- MFMA GEMM: out[M,NN] = act(A[M,KK] @ W[NN,KK]^T + bias) (+resid) ----
// A, W bf16 (K-contiguous both); bias f32. Block tile 128x64, BK=64, 2 waves,
// wave tile 64x64 (4x4 frags of 16x16x32). LDS chunks XOR-swizzled by row&7.
template<int ACT, bool RESID, int NN, int KK, typename RT, typename OT>
__global__ __launch_bounds__(128)
void mfma_gemm(const bf16* __restrict__ A, const bf16* __restrict__ W,
               const float* __restrict__ bias, const RT* __restrict__ resid,
               OT* __restrict__ out)
{
    __shared__ __align__(16) short As[128 * 64];
    __shared__ __align__(16) short Bs[64 * 64];
    const int t    = threadIdx.x;
    const int lane = t & 63;
    const int w    = t >> 6;
    const int m0   = blockIdx.y * 128;
    const int n0   = blockIdx.x * 64;
    const int lr   = lane & 15;     // row within 16
    const int lg   = lane >> 4;     // k-group 0..3

    f32x4 acc[4][4];
    #pragma unroll
    for (int i = 0; i < 4; ++i)
        #pragma unroll
        for (int j = 0; j < 4; ++j)
            acc[i][j] = (f32x4){0.f, 0.f, 0.f, 0.f};

    for (int k0 = 0; k0 < KK; k0 += 64) {
        // stage A: 128x64 bf16 = 1024 16B-chunks, 8 per thread
        #pragma unroll
        for (int li = 0; li < 8; ++li) {
            int chunk = li * 128 + t;
            int r = chunk >> 3, c = chunk & 7;
            uint4 p = *reinterpret_cast<const uint4*>(A + (size_t)(m0 + r) * KK + k0 + (c << 3));
            *reinterpret_cast<uint4*>(&As[(r << 6) + ((c ^ (r & 7)) << 3)]) = p;
        }
        // stage B: 64x64 bf16 = 512 chunks, 4 per thread
        #pragma unroll
        for (int li = 0; li < 4; ++li) {
            int chunk = li * 128 + t;
            int r = chunk >> 3, c = chunk & 7;
            uint4 p = *reinterpret_cast<const uint4*>(W + (size_t)(n0 + r) * KK + k0 + (c << 3));
            *reinterpret_cast<uint4*>(&Bs[(r << 6) + ((c ^ (r & 7)) << 3)]) = p;
        }
        __syncthreads();
        #pragma unroll
        for (int kf = 0; kf < 2; ++kf) {
            short8 a_[4], b_[4];
            #pragma unroll
            for (int mi = 0; mi < 4; ++mi) {
                int row = (w << 6) + (mi << 4) + lr;
                a_[mi] = *reinterpret_cast<const short8*>(
                    &As[(row << 6) + ((((kf << 2) + lg) ^ (row & 7)) << 3)]);
            }
            #pragma unroll
            for (int ni = 0; ni < 4; ++ni) {
                int rn = (ni << 4) + lr;
                b_[ni] = *reinterpret_cast<const short8*>(
                    &Bs[(rn << 6) + ((((kf << 2) + lg) ^ (rn & 7)) << 3)]);
            }
            #pragma unroll
            for (int mi = 0; mi < 4; ++mi)
                #pragma unroll
                for (int ni = 0; ni < 4; ++ni)
                    acc[mi][ni] = __builtin_amdgcn_mfma_f32_16x16x32_bf16(
                        a_[mi], b_[ni], acc[mi][ni], 0, 0, 0);
        }
        __syncthreads();
    }

    // epilogue: C/D layout col=lane&15, row=(lane>>4)*4+reg
    #pragma unroll
    for (int mi = 0; mi < 4; ++mi) {
        #pragma unroll
        for (int ni = 0; ni < 4; ++ni) {
            int col = n0 + (ni << 4) + lr;
            float bv = bias ? bias[col] : 0.f;
            #pragma unroll
            for (int r = 0; r < 4; ++r) {
                int row = m0 + (w << 6) + (mi << 4) + (lg << 2) + r;
                float c = acc[mi][ni][r] + bv;
                if (ACT == 1) c = gelu_exact(c);
                if (RESID) c += ldv(resid + (size_t)row * NN + col);
                stv(out + (size_t)row * NN + col, c);
            }
        }
    }
}

// ---------------- Window attention: one block per (window, head) ----------------
// qT/kT stored [d][i] so QK^T reads are stride-1; scores stored transposed
// ST[j][i] so softmax col-reduce and PV reads are conflict-free/broadcast.
__global__ __launch_bounds__(256)
void winattn_kernel(const bf16* __restrict__ qkv, bf16* __restrict__ aw)
{
    const int wi = blockIdx.x;           // 0..2047
    const int head = blockIdx.y;         // 0..5
    const int b = wi >> 6;
    const int wr = wi & 63;
    const int wy = wr >> 3, wx = wr & 7;
    const int t = threadIdx.x;
    const float scale = 0.1767766952966369f;   // 32^-0.5

    __shared__ float qs[32][52], ks[32][52];   // transposed
    __shared__ float vs[49][32];
    __shared__ float ST[49][52];               // ST[j][i] = P[i][j]

    if (t < 196) {
        int i = t >> 2, d0 = (t & 3) << 3;
        int iy = i / 7, ix = i - iy * 7;
        size_t l = (size_t)(wy * 7 + iy) * 56 + wx * 7 + ix;
        const bf16* base = qkv + ((size_t)b * LL + l) * C3 + head * HD + d0;
        uint4 pq = *reinterpret_cast<const uint4*>(base);
        uint4 pk = *reinterpret_cast<const uint4*>(base + 192);
        uint4 pv = *reinterpret_cast<const uint4*>(base + 384);
        unsigned short uq[8], uk[8], uv[8];
        *reinterpret_cast<uint4*>(uq) = pq;
        *reinterpret_cast<uint4*>(uk) = pk;
        *reinterpret_cast<uint4*>(uv) = pv;
        #pragma unroll
        for (int jj = 0; jj < 8; ++jj) {
            qs[d0 + jj][i] = us2f(uq[jj]) * scale;
            ks[d0 + jj][i] = us2f(uk[jj]);
            vs[i][d0 + jj] = us2f(uv[jj]);
        }
    }
    __syncthreads();

    for (int e = t; e < 49 * 49; e += 256) {
        int j = e / 49, i = e - j * 49;
        float a = 0.f;
        #pragma unroll
        for (int d = 0; d < 32; ++d) a += qs[d][i] * ks[d][j];
        ST[j][i] = a;
    }
    __syncthreads();

    if (t < 49) {
        float m = -1e30f;
        for (int j = 0; j < 49; ++j) m = fmaxf(m, ST[j][t]);
        float s = 0.f;
        for (int j = 0; j < 49; ++j) { float e_ = expf(ST[j][t] - m); ST[j][t] = e_; s += e_; }
        float inv = 1.f / s;
        for (int j = 0; j < 49; ++j) ST[j][t] *= inv;
    }
    __syncthreads();

    for (int e = t; e < 49 * 32; e += 256) {
        int i = e >> 5, d = e & 31;
        float a = 0.f;
        #pragma unroll
        for (int j = 0; j < 49; ++j) a += ST[j][i] * vs[j][d];
        int iy = i / 7, ix = i - iy * 7;
        size_t l = (size_t)(wy * 7 + iy) * 56 + wx * 7 + ix;
        aw[((size_t)b * LL + l) * CC + head * HD + d] = f2b(a);
    }
}

// ---------------- Depthwise 3x3 (SAME, zero pad) + exact GELU ----------------
__global__ __launch_bounds__(256)
void dwconv_kernel(const bf16* __restrict__ xn, const float* __restrict__ w,
                   bf16* __restrict__ out)
{
    int idx = blockIdx.x * 256 + threadIdx.x;
    if (idx >= MM * CC) return;
    int c  = idx % CC;
    int t1 = idx / CC;
    int w_ = t1 % WW;
    int t2 = t1 / WW;
    int h_ = t2 % HH;
    int b  = t2 / HH;
    float acc = 0.f;
    #pragma unroll
    for (int ky = 0; ky < 3; ++ky) {
        int hy = h_ + ky - 1;
        if (hy < 0 || hy >= HH) continue;
        #pragma unroll
        for (int kx = 0; kx < 3; ++kx) {
            int wx_ = w_ + kx - 1;
            if (wx_ < 0 || wx_ >= WW) continue;
            acc += b2f(xn[(((size_t)b * HH + hy) * WW + wx_) * CC + c]) *
                   w[c * 9 + ky * 3 + kx];
        }
    }
    out[idx] = f2b(gelu_exact(acc));
}

// ---------------- column (spatial) sum of xn per (b, c) ----------------
__global__ __launch_bounds__(192)
void colsum_kernel(const bf16* __restrict__ xn, float* __restrict__ colsum)
{
    int b = blockIdx.y, g = blockIdx.x, c = threadIdx.x;
    float acc = 0.f;
    int l0 = g * 196;
    for (int l = l0; l < l0 + 196; ++l)
        acc += b2f(xn[((size_t)b * LL + l) * CC + c]);
    atomicAdd(&colsum[b * CC + c], acc);
}

__global__ __launch_bounds__(192)
void gate_kernel(const float* __restrict__ colsum, const float* __restrict__ gw,
                 const float* __restrict__ gb, float* __restrict__ gate)
{
    __shared__ float cm[CC];
    int b = blockIdx.x, o = threadIdx.x;
    cm[o] = colsum[b * CC + o] * (1.0f / LL);
    __syncthreads();
    float acc = gb[o];
    for (int c = 0; c < CC; ++c) acc += gw[o * CC + c] * cm[c];
    gate[b * CC + o] = 1.0f / (1.0f + expf(-acc));
}

// ---------------- xf = x_attn + ld + xn * gate[b,c] ----------------
__global__ __launch_bounds__(256)
void combine_kernel(const bf16* __restrict__ xattn, const bf16* __restrict__ ld,
                    const bf16* __restrict__ xn, const float* __restrict__ gate,
                    bf16* __restrict__ xf)
{
    int idx = blockIdx.x * 256 + threadIdx.x;
    if (idx >= MM * CC) return;
    int c = idx % CC;
    int b = idx / (LL * CC);
    xf[idx] = f2b(b2f(xattn[idx]) + b2f(ld[idx]) + b2f(xn[idx]) * gate[b * CC + c]);
}

// ---------------- means over H (-> [B][W][C]) and over W (-> [B][H][C]) ----------------
__global__ __launch_bounds__(256)
void mean_h_kernel(const bf16* __restrict__ xf, float* __restrict__ mh)
{
    int idx = blockIdx.x * 256 + threadIdx.x;
    if (idx >= BB * WW * CC) return;
    int c  = idx % CC;
    int w_ = (idx / CC) % WW;
    int b  = idx / (CC * WW);
    float s = 0.f;
    for (int h_ = 0; h_ < HH; ++h_)
        s += b2f(xf[(((size_t)b * HH + h_) * WW + w_) * CC + c]);
    mh[idx] = s * (1.0f / HH);
}

__global__ __launch_bounds__(256)
void mean_w_kernel(const bf16* __restrict__ xf, float* __restrict__ mw)
{
    int idx = blockIdx.x * 256 + threadIdx.x;
    if (idx >= BB * HH * CC) return;
    int c  = idx % CC;
    int h_ = (idx / CC) % HH;
    int b  = idx / (CC * HH);
    float s = 0.f;
    for (int w_ = 0; w_ < WW; ++w_)
        s += b2f(xf[(((size_t)b * HH + h_) * WW + w_) * CC + c]);
    mw[idx] = s * (1.0f / WW);
}

// ---------------- logits over one spatial axis + softmax over the 56 positions ------------
__global__ __launch_bounds__(64)
void axsoftmax_kernel(const float* __restrict__ mean, const float* __restrict__ w,
                      const float* __restrict__ bias, float* __restrict__ out)
{
    __shared__ float wrow[CC];
    int o = blockIdx.x, b = blockIdx.y, lane = threadIdx.x;
    for (int c = lane; c < CC; c += 64) wrow[c] = w[o * CC + c];
    __syncthreads();
    float logit = -1e30f;
    if (lane < 56) {
        const float* mr = mean + ((size_t)b * 56 + lane) * CC;
        float a = bias[o];
        for (int c = 0; c < CC; ++c) a += wrow[c] * mr[c];
        logit = a;
    }
    float m = logit;
    #pragma unroll
    for (int off = 32; off > 0; off >>= 1) m = fmaxf(m, __shfl_xor(m, off, 64));
    float e = (lane < 56) ? expf(logit - m) : 0.f;
    float s = e;
    #pragma unroll
    for (int off = 32; off > 0; off >>= 1) s += __shfl_xor(s, off, 64);
    if (lane < 56) out[((size_t)b * CC + o) * 56 + lane] = e / s;
}

// ---------------- xf2 = xf * a_s[b,c,h] * a_t[b,c,w] * 2 ----------------
__global__ __launch_bounds__(256)
void modulate_kernel(const bf16* __restrict__ xf, const float* __restrict__ a_s,
                     const float* __restrict__ a_t, bf16* __restrict__ xf2)
{
    int idx = blockIdx.x * 256 + threadIdx.x;
    if (idx >= MM * CC) return;
    int c  = idx % CC;
    int t1 = idx / CC;
    int w_ = t1 % WW;
    int t2 = t1 / WW;
    int h_ = t2 % HH;
    int b  = t2 / HH;
    float v = b2f(xf[idx]) * a_s[((size_t)b * CC + c) * 56 + h_]
                           * a_t[((size_t)b * CC + c) * 56 + w_] * 2.0f;
    xf2[idx] = f2b(v);
}

// =======================================================================================
extern "C" void kernel_launch(void* const* d_in, const int* in_sizes, int n_in,
                              void* d_out, int out_size, void* d_ws, size_t ws_size,
                              hipStream_t stream)
{
    const float* x      = (const float*)d_in[0];
    const float* ln1_g  = (const float*)d_in[3];
    const float* ln1_b  = (const float*)d_in[4];
    const float* qkv_w  = (const float*)d_in[5];
    const float* qkv_b  = (const float*)d_in[6];
    const float* proj_w = (const float*)d_in[7];
    const float* proj_b = (const float*)d_in[8];
    const float* dw_w   = (const float*)d_in[9];
    const float* pw_w   = (const float*)d_in[10];
    const float* gate_w = (const float*)d_in[11];
    const float* gate_b = (const float*)d_in[12];
    const float* temp_w = (const float*)d_in[13];
    const float* temp_b = (const float*)d_in[14];
    const float* spec_w = (const float*)d_in[15];
    const float* spec_b = (const float*)d_in[16];
    const float* fuse_w = (const float*)d_in[17];
    const float* ln2_g  = (const float*)d_in[18];
    const float* ln2_b  = (const float*)d_in[19];
    const float* mlp1_w = (const float*)d_in[20];
    const float* mlp1_b = (const float*)d_in[21];
    const float* mlp2_w = (const float*)d_in[22];
    const float* mlp2_b = (const float*)d_in[23];
    float* out = (float*)d_out;

    const size_t SLOT = (size_t)MM * CC * sizeof(bf16);   // 38,535,168 B
    char* ws = (char*)d_ws;

    bf16* s_xn    = (bf16*)(ws);
    bf16* s_qkv   = (bf16*)(ws + SLOT);        // 3 slots
    bf16* s_aw    = (bf16*)(ws + 4 * SLOT);
    bf16* s_xattn = (bf16*)(ws + SLOT);        // reuse qkv slot 1
    bf16* s_dwg   = (bf16*)(ws + 2 * SLOT);
    bf16* s_ld    = (bf16*)(ws + 3 * SLOT);
    bf16* s_xf    = (bf16*)(ws + 4 * SLOT);    // reuse aw
    bf16* s_xf2   = (bf16*)(ws);               // reuse xn
    bf16* s_x2    = (bf16*)(ws + SLOT);        // reuse xattn
    bf16* s_hn    = (bf16*)(ws + 2 * SLOT);
    bf16* s_h1    = (bf16*)(ws + 3 * SLOT);    // spans slots 3..4 (384 ch)

    float* colsum  = (float*)(ws + 5 * SLOT);
    float* gatebuf = colsum + BB * CC;
    float* mean_h  = gatebuf + BB * CC;
    float* mean_w  = mean_h + (size_t)BB * 56 * CC;
    float* a_t     = mean_w + (size_t)BB * 56 * CC;
    float* a_s     = a_t    + (size_t)BB * CC * 56;
    // bf16 weight copies
    bf16* wb_qkv  = (bf16*)(a_s + (size_t)BB * CC * 56);
    bf16* wb_proj = wb_qkv  + C3 * CC;
    bf16* wb_pw   = wb_proj + CC * CC;
    bf16* wb_fuse = wb_pw   + CC * CC;
    bf16* wb_mlp1 = wb_fuse + CC * CC;
    bf16* wb_mlp2 = wb_mlp1 + HIDN * CC;
    size_t total_need = (char*)(wb_mlp2 + CC * HIDN) - ws;
    if (ws_size < total_need) return;   // workspace insufficient — visible failure

    const int EW_BLOCKS = (MM * CC + 255) / 256;   // 75264

    // 0. weight conversions (f32 -> bf16)
    cvt_kernel<<<(C3 * CC + 255) / 256, 256, 0, stream>>>(qkv_w, wb_qkv, C3 * CC);
    cvt_kernel<<<(CC * CC + 255) / 256, 256, 0, stream>>>(proj_w, wb_proj, CC * CC);
    cvt_kernel<<<(CC * CC + 255) / 256, 256, 0, stream>>>(pw_w, wb_pw, CC * CC);
    cvt_kernel<<<(CC * CC + 255) / 256, 256, 0, stream>>>(fuse_w, wb_fuse, CC * CC);
    cvt_kernel<<<(HIDN * CC + 255) / 256, 256, 0, stream>>>(mlp1_w, wb_mlp1, HIDN * CC);
    cvt_kernel<<<(CC * HIDN + 255) / 256, 256, 0, stream>>>(mlp2_w, wb_mlp2, CC * HIDN);

    // 1. LN1
    ln_kernel<float><<<MM / 4, 256, 0, stream>>>(x, ln1_g, ln1_b, s_xn);
    // 2. qkv
    mfma_gemm<0, false, C3, CC, bf16, bf16><<<dim3(C3 / 64, MM / 128), 128, 0, stream>>>(
        s_xn, wb_qkv, qkv_b, (const bf16*)nullptr, s_qkv);
    // 3. window attention
    winattn_kernel<<<dim3(NWIN, NHEAD), 256, 0, stream>>>(s_qkv, s_aw);
    // 4. proj
    mfma_gemm<0, false, CC, CC, bf16, bf16><<<dim3(CC / 64, MM / 128), 128, 0, stream>>>(
        s_aw, wb_proj, proj_b, (const bf16*)nullptr, s_xattn);
    // 5. depthwise + gelu
    dwconv_kernel<<<EW_BLOCKS, 256, 0, stream>>>(s_xn, dw_w, s_dwg);
    // 6. pointwise (no bias)
    mfma_gemm<0, false, CC, CC, bf16, bf16><<<dim3(CC / 64, MM / 128), 128, 0, stream>>>(
        s_dwg, wb_pw, (const float*)nullptr, (const bf16*)nullptr, s_ld);
    // 7. gate
    hipMemsetAsync(colsum, 0, BB * CC * sizeof(float), stream);
    colsum_kernel<<<dim3(16, BB), 192, 0, stream>>>(s_xn, colsum);
    gate_kernel<<<BB, 192, 0, stream>>>(colsum, gate_w, gate_b, gatebuf);
    // 8. xf = x_attn + ld + xn*gate
    combine_kernel<<<EW_BLOCKS, 256, 0, stream>>>(s_xattn, s_ld, s_xn, gatebuf, s_xf);
    // 9. axis means
    mean_h_kernel<<<(BB * WW * CC + 255) / 256, 256, 0, stream>>>(s_xf, mean_h);
    mean_w_kernel<<<(BB * HH * CC + 255) / 256, 256, 0, stream>>>(s_xf, mean_w);
    // 10. a_t (temporal, over W) and a_s (spectral, over H)
    axsoftmax_kernel<<<dim3(CC, BB), 64, 0, stream>>>(mean_h, temp_w, temp_b, a_t);
    axsoftmax_kernel<<<dim3(CC, BB), 64, 0, stream>>>(mean_w, spec_w, spec_b, a_s);
    // 11. modulate
    modulate_kernel<<<EW_BLOCKS, 256, 0, stream>>>(s_xf, a_s, a_t, s_xf2);
    // 12. fuse (no bias) + residual from original x -> x2
    mfma_gemm<0, true, CC, CC, float, bf16><<<dim3(CC / 64, MM / 128), 128, 0, stream>>>(
        s_xf2, wb_fuse, (const float*)nullptr, x, s_x2);
    // 13. LN2
    ln_kernel<bf16><<<MM / 4, 256, 0, stream>>>(s_x2, ln2_g, ln2_b, s_hn);
    // 14. MLP1 + gelu
    mfma_gemm<1, false, HIDN, CC, bf16, bf16><<<dim3(HIDN / 64, MM / 128), 128, 0, stream>>>(
        s_hn, wb_mlp1, mlp1_b, (const bf16*)nullptr, s_h1);
    // 15. MLP2 + residual -> out (f32)
    mfma_gemm<0, true, CC, HIDN, bf16, float><<<dim3(CC / 64, MM / 128), 128, 0, stream>>>(
        s_h1, wb_mlp2, mlp2_b, s_x2, out);
}

// Round 4
// 815.600 us; speedup vs baseline: 2.0779x; 1.2104x over previous
//
#include <hip/hip_runtime.h>
#include <hip/hip_bf16.h>

typedef __hip_bfloat16 bf16;

// Problem constants (B=32, H=W=56, C=192, NH=6, WS=7)
#define BB 32
#define HH 56
#define WW 56
#define CC 192
#define LL 3136            // 56*56
#define MM (BB*LL)         // 100352 tokens
#define C3 576
#define HIDN 384
#define NHEAD 6
#define HD 32
#define NWIN 2048          // B * 8*8

typedef short short8 __attribute__((ext_vector_type(8)));
typedef float f32x4 __attribute__((ext_vector_type(4)));

__device__ __forceinline__ float us2f(unsigned short u) {
    union { unsigned int i; float f; } v; v.i = ((unsigned int)u) << 16; return v.f;
}
__device__ __forceinline__ float b2f(bf16 h) { return __bfloat162float(h); }
__device__ __forceinline__ bf16 f2b(float f) { return __float2bfloat16(f); }
__device__ __forceinline__ short f2bs(float f) { bf16 h = f2b(f); return *reinterpret_cast<short*>(&h); }
__device__ __forceinline__ float ldv(const bf16* p) { return b2f(*p); }
__device__ __forceinline__ float ldv(const float* p) { return *p; }
__device__ __forceinline__ void stv(bf16* p, float v) { *p = f2b(v); }
__device__ __forceinline__ void stv(float* p, float v) { *p = v; }
__device__ __forceinline__ float gelu_exact(float x) {
    return 0.5f * x * (1.0f + erff(x * 0.70710678118654752f));
}
__device__ __forceinline__ void async_lds16(const void* g, void* l) {
    __builtin_amdgcn_global_load_lds(
        (const __attribute__((address_space(1))) void*)g,
        (__attribute__((address_space(3))) void*)l, 16, 0, 0);
}

// ---------------- f32 -> bf16 weight conversion ----------------
__global__ __launch_bounds__(256)
void cvt_kernel(const float* __restrict__ src, bf16* __restrict__ dst, int n)
{
    int i = blockIdx.x * 256 + threadIdx.x;
    if (i < n) dst[i] = f2b(src[i]);
}

// ---------------- LayerNorm: one wave (64 lanes) per row of 192 ----------------
template<typename IT>
__global__ __launch_bounds__(256)
void ln_kernel(const IT* __restrict__ in, const float* __restrict__ g,
               const float* __restrict__ bvec, bf16* __restrict__ out)
{
    int wid = threadIdx.x >> 6, lane = threadIdx.x & 63;
    int row = blockIdx.x * 4 + wid;
    const IT* p = in + (size_t)row * CC;
    float x0 = ldv(p + lane);
    float x1 = ldv(p + lane + 64);
    float x2 = ldv(p + lane + 128);
    float s  = x0 + x1 + x2;
    float sq = x0*x0 + x1*x1 + x2*x2;
    #pragma unroll
    for (int o = 32; o > 0; o >>= 1) {
        s  += __shfl_xor(s,  o, 64);
        sq += __shfl_xor(sq, o, 64);
    }
    float mean = s * (1.0f / CC);
    float var  = sq * (1.0f / CC) - mean * mean;
    float inv  = rsqrtf(fmaxf(var, 0.0f) + 1e-5f);
    bf16* q = out + (size_t)row * CC;
    q[lane]       = f2b((x0 - mean) * inv * g[lane]       + bvec[lane]);
    q[lane + 64]  = f2b((x1 - mean) * inv * g[lane + 64]  + bvec[lane + 64]);
    q[lane + 128] = f2b((x2 - mean) * inv * g[lane + 128] + bvec[lane + 128]);
}

// ---------------- MFMA GEMM: out[M,NN] = act(A[M,KK] @ W[NN,KK]^T + bias) (+resid) ----
// Block tile 128x64, BK=64, 2 waves, wave tile 64x64 (4x4 frags of 16x16x32).
// Staging via global_load_lds: LDS dest linear, global SOURCE pre-swizzled
// (chunk c -> c^(r&7)); reads swizzle the LDS address identically.
template<int ACT, bool RESID, int NN, int KK, typename RT, typename OT>
__global__ __launch_bounds__(128)
void mfma_gemm(const bf16* __restrict__ A, const bf16* __restrict__ W,
               const float* __restrict__ bias, const RT* __restrict__ resid,
               OT* __restrict__ out)
{
    __shared__ __align__(16) short As[128 * 64];
    __shared__ __align__(16) short Bs[64 * 64];
    const int t    = threadIdx.x;
    const int lane = t & 63;
    const int w    = t >> 6;
    const int m0   = blockIdx.y * 128;
    const int n0   = blockIdx.x * 64;
    const int lr   = lane & 15;     // row within 16
    const int lg   = lane >> 4;     // k-group 0..3

    f32x4 acc[4][4];
    #pragma unroll
    for (int i = 0; i < 4; ++i)
        #pragma unroll
        for (int j = 0; j < 4; ++j)
            acc[i][j] = (f32x4){0.f, 0.f, 0.f, 0.f};

    for (int k0 = 0; k0 < KK; k0 += 64) {
        const bf16* Ab = A + (size_t)m0 * KK + k0;
        const bf16* Wb = W + (size_t)n0 * KK + k0;
        // stage A: 128x64 bf16 = 1024 16B-chunks, 8 gload_lds per thread
        #pragma unroll
        for (int li = 0; li < 8; ++li) {
            int chunk = li * 128 + t;
            int r = chunk >> 3, c = chunk & 7;
            int cs = c ^ (r & 7);
            async_lds16(Ab + (size_t)r * KK + (cs << 3),
                        &As[(li * 128 + w * 64) << 3]);
        }
        // stage B: 64x64 bf16 = 512 chunks, 4 per thread
        #pragma unroll
        for (int li = 0; li < 4; ++li) {
            int chunk = li * 128 + t;
            int r = chunk >> 3, c = chunk & 7;
            int cs = c ^ (r & 7);
            async_lds16(Wb + (size_t)r * KK + (cs << 3),
                        &Bs[(li * 128 + w * 64) << 3]);
        }
        __syncthreads();
        #pragma unroll
        for (int kf = 0; kf < 2; ++kf) {
            short8 a_[4], b_[4];
            #pragma unroll
            for (int mi = 0; mi < 4; ++mi) {
                int row = (w << 6) + (mi << 4) + lr;
                a_[mi] = *reinterpret_cast<const short8*>(
                    &As[(row << 6) + ((((kf << 2) + lg) ^ (row & 7)) << 3)]);
            }
            #pragma unroll
            for (int ni = 0; ni < 4; ++ni) {
                int rn = (ni << 4) + lr;
                b_[ni] = *reinterpret_cast<const short8*>(
                    &Bs[(rn << 6) + ((((kf << 2) + lg) ^ (rn & 7)) << 3)]);
            }
            #pragma unroll
            for (int mi = 0; mi < 4; ++mi)
                #pragma unroll
                for (int ni = 0; ni < 4; ++ni)
                    acc[mi][ni] = __builtin_amdgcn_mfma_f32_16x16x32_bf16(
                        a_[mi], b_[ni], acc[mi][ni], 0, 0, 0);
        }
        __syncthreads();
    }

    // epilogue: C/D layout col=lane&15, row=(lane>>4)*4+reg
    #pragma unroll
    for (int mi = 0; mi < 4; ++mi) {
        #pragma unroll
        for (int ni = 0; ni < 4; ++ni) {
            int col = n0 + (ni << 4) + lr;
            float bv = bias ? bias[col] : 0.f;
            #pragma unroll
            for (int r = 0; r < 4; ++r) {
                int row = m0 + (w << 6) + (mi << 4) + (lg << 2) + r;
                float c = acc[mi][ni][r] + bv;
                if (ACT == 1) c = gelu_exact(c);
                if (RESID) c += ldv(resid + (size_t)row * NN + col);
                stv(out + (size_t)row * NN + col, c);
            }
        }
    }
}

// ---------------- MFMA window attention: one wave per (window, head) ----------------
// Q,K row-major [64][40] bf16 (80B stride -> 2-way bank alias = free);
// V transposed [32][72]; softmax in-register on C-layout; P via LDS bf16
// (unnormalized, row-sums kept in regs, normalize after PV).
__global__ __launch_bounds__(64)
void winattn_kernel(const bf16* __restrict__ qkv, bf16* __restrict__ aw)
{
    __shared__ __align__(16) short Qs[64 * 40];
    __shared__ __align__(16) short Ks[64 * 40];
    __shared__ __align__(16) short Ps[64 * 40];
    __shared__ __align__(16) short Vt[32 * 72];

    const int wi   = blockIdx.x;         // 0..2047
    const int head = blockIdx.y;         // 0..5
    const int b  = wi >> 6;
    const int wr = wi & 63;
    const int wy = wr >> 3, wx = wr & 7;
    const int t  = threadIdx.x;          // 0..63
    const int lc = t & 15;               // col-in-16 / frag row
    const int lg = t >> 4;               // k-group / C-row group
    const float scale = 0.1767766952966369f;   // 32^-0.5

    // zero pad: K rows 48..63 (cols 0..31), Vt cols 48..63 (all 32 rows)
    #pragma unroll
    for (int e = t; e < 256; e += 64) {
        int r = 48 + (e >> 4), c = (e & 15) << 1;
        *reinterpret_cast<int*>(&Ks[r * 40 + c]) = 0;
    }
    #pragma unroll
    for (int e = t; e < 512; e += 64) {
        int r = e >> 4, c = 48 + (e & 15);
        Vt[r * 72 + c] = 0;
    }

    // stage Q,K row-major; V transposed
    for (int e = t; e < 196; e += 64) {
        int tok = e >> 2, part = e & 3;
        int iy = tok / 7, ix = tok - iy * 7;
        size_t l = (size_t)(wy * 7 + iy) * 56 + wx * 7 + ix;
        const bf16* base = qkv + ((size_t)b * LL + l) * C3 + head * HD + (part << 3);
        uint4 pq = *reinterpret_cast<const uint4*>(base);
        uint4 pk = *reinterpret_cast<const uint4*>(base + 192);
        uint4 pv = *reinterpret_cast<const uint4*>(base + 384);
        *reinterpret_cast<uint4*>(&Qs[tok * 40 + (part << 3)]) = pq;
        *reinterpret_cast<uint4*>(&Ks[tok * 40 + (part << 3)]) = pk;
        unsigned short uv[8];
        *reinterpret_cast<uint4*>(uv) = pv;
        #pragma unroll
        for (int jj = 0; jj < 8; ++jj)
            Vt[((part << 3) + jj) * 72 + tok] = (short)uv[jj];
    }
    __syncthreads();

    // S = Q K^T  (A: row=lc, k=lg*8+j  -- same mapping the passing GEMM verified)
    f32x4 acc[4][4];
    #pragma unroll
    for (int i = 0; i < 4; ++i)
        #pragma unroll
        for (int j = 0; j < 4; ++j)
            acc[i][j] = (f32x4){0.f, 0.f, 0.f, 0.f};
    {
        short8 a_[4], b_[4];
        #pragma unroll
        for (int mi = 0; mi < 4; ++mi)
            a_[mi] = *reinterpret_cast<const short8*>(&Qs[((mi << 4) + lc) * 40 + (lg << 3)]);
        #pragma unroll
        for (int ni = 0; ni < 4; ++ni)
            b_[ni] = *reinterpret_cast<const short8*>(&Ks[((ni << 4) + lc) * 40 + (lg << 3)]);
        #pragma unroll
        for (int mi = 0; mi < 4; ++mi)
            #pragma unroll
            for (int ni = 0; ni < 4; ++ni)
                acc[mi][ni] = __builtin_amdgcn_mfma_f32_16x16x32_bf16(
                    a_[mi], b_[ni], acc[mi][ni], 0, 0, 0);
    }

    // softmax over j (cols); C layout: row = mi*16 + lg*4 + r, col = ni*16 + lc.
    // valid j < 49: mask ni==3 && lc!=0. scale folded into exp.
    float rinv[4][4];
    #pragma unroll
    for (int mi = 0; mi < 4; ++mi) {
        #pragma unroll
        for (int r = 0; r < 4; ++r) {
            float mx = -1e30f;
            #pragma unroll
            for (int ni = 0; ni < 4; ++ni) {
                float v = acc[mi][ni][r];
                if (ni == 3 && lc != 0) v = -1e30f;
                mx = fmaxf(mx, v);
            }
            mx = fmaxf(mx, __shfl_xor(mx, 1, 64));
            mx = fmaxf(mx, __shfl_xor(mx, 2, 64));
            mx = fmaxf(mx, __shfl_xor(mx, 4, 64));
            mx = fmaxf(mx, __shfl_xor(mx, 8, 64));
            float sm = 0.f;
            int row = (mi << 4) + (lg << 2) + r;
            #pragma unroll
            for (int ni = 0; ni < 4; ++ni) {
                float e = (ni == 3 && lc != 0) ? 0.f
                        : __expf(scale * (acc[mi][ni][r] - mx));
                Ps[row * 40 + (ni << 4) + lc] = f2bs(e);
                sm += e;
            }
            sm += __shfl_xor(sm, 1, 64);
            sm += __shfl_xor(sm, 2, 64);
            sm += __shfl_xor(sm, 4, 64);
            sm += __shfl_xor(sm, 8, 64);
            rinv[mi][r] = 1.0f / sm;
        }
    }
    __syncthreads();

    // O = P V   (A = P rows, B = Vt)
    f32x4 o[4][2];
    #pragma unroll
    for (int i = 0; i < 4; ++i) {
        o[i][0] = (f32x4){0.f, 0.f, 0.f, 0.f};
        o[i][1] = (f32x4){0.f, 0.f, 0.f, 0.f};
    }
    #pragma unroll
    for (int kf = 0; kf < 2; ++kf) {
        short8 pa[4], vb[2];
        #pragma unroll
        for (int mi = 0; mi < 4; ++mi)
            pa[mi] = *reinterpret_cast<const short8*>(
                &Ps[((mi << 4) + lc) * 40 + (kf << 5) + (lg << 3)]);
        #pragma unroll
        for (int n2 = 0; n2 < 2; ++n2)
            vb[n2] = *reinterpret_cast<const short8*>(
                &Vt[((n2 << 4) + lc) * 72 + (kf << 5) + (lg << 3)]);
        #pragma unroll
        for (int mi = 0; mi < 4; ++mi)
            #pragma unroll
            for (int n2 = 0; n2 < 2; ++n2)
                o[mi][n2] = __builtin_amdgcn_mfma_f32_16x16x32_bf16(
                    pa[mi], vb[n2], o[mi][n2], 0, 0, 0);
    }

    // write: row = mi*16 + lg*4 + r (token), col d = n2*16 + lc
    #pragma unroll
    for (int mi = 0; mi < 4; ++mi) {
        #pragma unroll
        for (int r = 0; r < 4; ++r) {
            int row = (mi << 4) + (lg << 2) + r;
            if (row < 49) {
                int iy = row / 7, ix = row - iy * 7;
                size_t l = (size_t)(wy * 7 + iy) * 56 + wx * 7 + ix;
                bf16* dst = aw + ((size_t)b * LL + l) * CC + head * HD + lc;
                float inv = rinv[mi][r];
                dst[0]  = f2b(o[mi][0][r] * inv);
                dst[16] = f2b(o[mi][1][r] * inv);
            }
        }
    }
}

// ---------------- Depthwise 3x3 (SAME, zero pad) + exact GELU ----------------
__global__ __launch_bounds__(256)
void dwconv_kernel(const bf16* __restrict__ xn, const float* __restrict__ w,
                   bf16* __restrict__ out)
{
    int idx = blockIdx.x * 256 + threadIdx.x;
    if (idx >= MM * CC) return;
    int c  = idx % CC;
    int t1 = idx / CC;
    int w_ = t1 % WW;
    int t2 = t1 / WW;
    int h_ = t2 % HH;
    int b  = t2 / HH;
    float acc = 0.f;
    #pragma unroll
    for (int ky = 0; ky < 3; ++ky) {
        int hy = h_ + ky - 1;
        if (hy < 0 || hy >= HH) continue;
        #pragma unroll
        for (int kx = 0; kx < 3; ++kx) {
            int wx_ = w_ + kx - 1;
            if (wx_ < 0 || wx_ >= WW) continue;
            acc += b2f(xn[(((size_t)b * HH + hy) * WW + wx_) * CC + c]) *
                   w[c * 9 + ky * 3 + kx];
        }
    }
    out[idx] = f2b(gelu_exact(acc));
}

// ---------------- column (spatial) sum of xn per (b, c) ----------------
__global__ __launch_bounds__(192)
void colsum_kernel(const bf16* __restrict__ xn, float* __restrict__ colsum)
{
    int b = blockIdx.y, g = blockIdx.x, c = threadIdx.x;
    float acc = 0.f;
    int l0 = g * 196;
    for (int l = l0; l < l0 + 196; ++l)
        acc += b2f(xn[((size_t)b * LL + l) * CC + c]);
    atomicAdd(&colsum[b * CC + c], acc);
}

__global__ __launch_bounds__(192)
void gate_kernel(const float* __restrict__ colsum, const float* __restrict__ gw,
                 const float* __restrict__ gb, float* __restrict__ gate)
{
    __shared__ float cm[CC];
    int b = blockIdx.x, o = threadIdx.x;
    cm[o] = colsum[b * CC + o] * (1.0f / LL);
    __syncthreads();
    float acc = gb[o];
    for (int c = 0; c < CC; ++c) acc += gw[o * CC + c] * cm[c];
    gate[b * CC + o] = 1.0f / (1.0f + expf(-acc));
}

// ---------------- xf = x_attn + ld + xn * gate[b,c] ----------------
__global__ __launch_bounds__(256)
void combine_kernel(const bf16* __restrict__ xattn, const bf16* __restrict__ ld,
                    const bf16* __restrict__ xn, const float* __restrict__ gate,
                    bf16* __restrict__ xf)
{
    int idx = blockIdx.x * 256 + threadIdx.x;
    if (idx >= MM * CC) return;
    int c = idx % CC;
    int b = idx / (LL * CC);
    xf[idx] = f2b(b2f(xattn[idx]) + b2f(ld[idx]) + b2f(xn[idx]) * gate[b * CC + c]);
}

// ---------------- means over H (-> [B][W][C]) and over W (-> [B][H][C]) ----------------
__global__ __launch_bounds__(256)
void mean_h_kernel(const bf16* __restrict__ xf, float* __restrict__ mh)
{
    int idx = blockIdx.x * 256 + threadIdx.x;
    if (idx >= BB * WW * CC) return;
    int c  = idx % CC;
    int w_ = (idx / CC) % WW;
    int b  = idx / (CC * WW);
    float s = 0.f;
    for (int h_ = 0; h_ < HH; ++h_)
        s += b2f(xf[(((size_t)b * HH + h_) * WW + w_) * CC + c]);
    mh[idx] = s * (1.0f / HH);
}

__global__ __launch_bounds__(256)
void mean_w_kernel(const bf16* __restrict__ xf, float* __restrict__ mw)
{
    int idx = blockIdx.x * 256 + threadIdx.x;
    if (idx >= BB * HH * CC) return;
    int c  = idx % CC;
    int h_ = (idx / CC) % HH;
    int b  = idx / (CC * HH);
    float s = 0.f;
    for (int w_ = 0; w_ < WW; ++w_)
        s += b2f(xf[(((size_t)b * HH + h_) * WW + w_) * CC + c]);
    mw[idx] = s * (1.0f / WW);
}

// ---------------- logits over one spatial axis + softmax over the 56 positions ------------
__global__ __launch_bounds__(64)
void axsoftmax_kernel(const float* __restrict__ mean, const float* __restrict__ w,
                      const float* __restrict__ bias, float* __restrict__ out)
{
    __shared__ float wrow[CC];
    int o = blockIdx.x, b = blockIdx.y, lane = threadIdx.x;
    for (int c = lane; c < CC; c += 64) wrow[c] = w[o * CC + c];
    __syncthreads();
    float logit = -1e30f;
    if (lane < 56) {
        const float* mr = mean + ((size_t)b * 56 + lane) * CC;
        float a = bias[o];
        for (int c = 0; c < CC; ++c) a += wrow[c] * mr[c];
        logit = a;
    }
    float m = logit;
    #pragma unroll
    for (int off = 32; off > 0; off >>= 1) m = fmaxf(m, __shfl_xor(m, off, 64));
    float e = (lane < 56) ? expf(logit - m) : 0.f;
    float s = e;
    #pragma unroll
    for (int off = 32; off > 0; off >>= 1) s += __shfl_xor(s, off, 64);
    if (lane < 56) out[((size_t)b * CC + o) * 56 + lane] = e / s;
}

// ---------------- xf2 = xf * a_s[b,c,h] * a_t[b,c,w] * 2 ----------------
__global__ __launch_bounds__(256)
void modulate_kernel(const bf16* __restrict__ xf, const float* __restrict__ a_s,
                     const float* __restrict__ a_t, bf16* __restrict__ xf2)
{
    int idx = blockIdx.x * 256 + threadIdx.x;
    if (idx >= MM * CC) return;
    int c  = idx % CC;
    int t1 = idx / CC;
    int w_ = t1 % WW;
    int t2 = t1 / WW;
    int h_ = t2 % HH;
    int b  = t2 / HH;
    float v = b2f(xf[idx]) * a_s[((size_t)b * CC + c) * 56 + h_]
                           * a_t[((size_t)b * CC + c) * 56 + w_] * 2.0f;
    xf2[idx] = f2b(v);
}

// =======================================================================================
extern "C" void kernel_launch(void* const* d_in, const int* in_sizes, int n_in,
                              void* d_out, int out_size, void* d_ws, size_t ws_size,
                              hipStream_t stream)
{
    const float* x      = (const float*)d_in[0];
    const float* ln1_g  = (const float*)d_in[3];
    const float* ln1_b  = (const float*)d_in[4];
    const float* qkv_w  = (const float*)d_in[5];
    const float* qkv_b  = (const float*)d_in[6];
    const float* proj_w = (const float*)d_in[7];
    const float* proj_b = (const float*)d_in[8];
    const float* dw_w   = (const float*)d_in[9];
    const float* pw_w   = (const float*)d_in[10];
    const float* gate_w = (const float*)d_in[11];
    const float* gate_b = (const float*)d_in[12];
    const float* temp_w = (const float*)d_in[13];
    const float* temp_b = (const float*)d_in[14];
    const float* spec_w = (const float*)d_in[15];
    const float* spec_b = (const float*)d_in[16];
    const float* fuse_w = (const float*)d_in[17];
    const float* ln2_g  = (const float*)d_in[18];
    const float* ln2_b  = (const float*)d_in[19];
    const float* mlp1_w = (const float*)d_in[20];
    const float* mlp1_b = (const float*)d_in[21];
    const float* mlp2_w = (const float*)d_in[22];
    const float* mlp2_b = (const float*)d_in[23];
    float* out = (float*)d_out;

    const size_t SLOT = (size_t)MM * CC * sizeof(bf16);   // 38,535,168 B
    char* ws = (char*)d_ws;

    bf16* s_xn    = (bf16*)(ws);
    bf16* s_qkv   = (bf16*)(ws + SLOT);        // 3 slots
    bf16* s_aw    = (bf16*)(ws + 4 * SLOT);
    bf16* s_xattn = (bf16*)(ws + SLOT);        // reuse qkv slot 1
    bf16* s_dwg   = (bf16*)(ws + 2 * SLOT);
    bf16* s_ld    = (bf16*)(ws + 3 * SLOT);
    bf16* s_xf    = (bf16*)(ws + 4 * SLOT);    // reuse aw
    bf16* s_xf2   = (bf16*)(ws);               // reuse xn
    bf16* s_x2    = (bf16*)(ws + SLOT);        // reuse xattn
    bf16* s_hn    = (bf16*)(ws + 2 * SLOT);
    bf16* s_h1    = (bf16*)(ws + 3 * SLOT);    // spans slots 3..4 (384 ch)

    float* colsum  = (float*)(ws + 5 * SLOT);
    float* gatebuf = colsum + BB * CC;
    float* mean_h  = gatebuf + BB * CC;
    float* mean_w  = mean_h + (size_t)BB * 56 * CC;
    float* a_t     = mean_w + (size_t)BB * 56 * CC;
    float* a_s     = a_t    + (size_t)BB * CC * 56;
    // bf16 weight copies
    bf16* wb_qkv  = (bf16*)(a_s + (size_t)BB * CC * 56);
    bf16* wb_proj = wb_qkv  + C3 * CC;
    bf16* wb_pw   = wb_proj + CC * CC;
    bf16* wb_fuse = wb_pw   + CC * CC;
    bf16* wb_mlp1 = wb_fuse + CC * CC;
    bf16* wb_mlp2 = wb_mlp1 + HIDN * CC;
    size_t total_need = (char*)(wb_mlp2 + CC * HIDN) - ws;
    if (ws_size < total_need) return;   // workspace insufficient — visible failure

    const int EW_BLOCKS = (MM * CC + 255) / 256;   // 75264

    // 0. weight conversions (f32 -> bf16)
    cvt_kernel<<<(C3 * CC + 255) / 256, 256, 0, stream>>>(qkv_w, wb_qkv, C3 * CC);
    cvt_kernel<<<(CC * CC + 255) / 256, 256, 0, stream>>>(proj_w, wb_proj, CC * CC);
    cvt_kernel<<<(CC * CC + 255) / 256, 256, 0, stream>>>(pw_w, wb_pw, CC * CC);
    cvt_kernel<<<(CC * CC + 255) / 256, 256, 0, stream>>>(fuse_w, wb_fuse, CC * CC);
    cvt_kernel<<<(HIDN * CC + 255) / 256, 256, 0, stream>>>(mlp1_w, wb_mlp1, HIDN * CC);
    cvt_kernel<<<(CC * HIDN + 255) / 256, 256, 0, stream>>>(mlp2_w, wb_mlp2, CC * HIDN);

    // 1. LN1
    ln_kernel<float><<<MM / 4, 256, 0, stream>>>(x, ln1_g, ln1_b, s_xn);
    // 2. qkv
    mfma_gemm<0, false, C3, CC, bf16, bf16><<<dim3(C3 / 64, MM / 128), 128, 0, stream>>>(
        s_xn, wb_qkv, qkv_b, (const bf16*)nullptr, s_qkv);
    // 3. window attention (MFMA, 1 wave per (window, head))
    winattn_kernel<<<dim3(NWIN, NHEAD), 64, 0, stream>>>(s_qkv, s_aw);
    // 4. proj
    mfma_gemm<0, false, CC, CC, bf16, bf16><<<dim3(CC / 64, MM / 128), 128, 0, stream>>>(
        s_aw, wb_proj, proj_b, (const bf16*)nullptr, s_xattn);
    // 5. depthwise + gelu
    dwconv_kernel<<<EW_BLOCKS, 256, 0, stream>>>(s_xn, dw_w, s_dwg);
    // 6. pointwise (no bias)
    mfma_gemm<0, false, CC, CC, bf16, bf16><<<dim3(CC / 64, MM / 128), 128, 0, stream>>>(
        s_dwg, wb_pw, (const float*)nullptr, (const bf16*)nullptr, s_ld);
    // 7. gate
    hipMemsetAsync(colsum, 0, BB * CC * sizeof(float), stream);
    colsum_kernel<<<dim3(16, BB), 192, 0, stream>>>(s_xn, colsum);
    gate_kernel<<<BB, 192, 0, stream>>>(colsum, gate_w, gate_b, gatebuf);
    // 8. xf = x_attn + ld + xn*gate
    combine_kernel<<<EW_BLOCKS, 256, 0, stream>>>(s_xattn, s_ld, s_xn, gatebuf, s_xf);
    // 9. axis means
    mean_h_kernel<<<(BB * WW * CC + 255) / 256, 256, 0, stream>>>(s_xf, mean_h);
    mean_w_kernel<<<(BB * HH * CC + 255) / 256, 256, 0, stream>>>(s_xf, mean_w);
    // 10. a_t (temporal, over W) and a_s (spectral, over H)
    axsoftmax_kernel<<<dim3(CC, BB), 64, 0, stream>>>(mean_h, temp_w, temp_b, a_t);
    axsoftmax_kernel<<<dim3(CC, BB), 64, 0, stream>>>(mean_w, spec_w, spec_b, a_s);
    // 11. modulate
    modulate_kernel<<<EW_BLOCKS, 256, 0, stream>>>(s_xf, a_s, a_t, s_xf2);
    // 12. fuse (no bias) + residual from original x -> x2
    mfma_gemm<0, true, CC, CC, float, bf16><<<dim3(CC / 64, MM / 128), 128, 0, stream>>>(
        s_xf2, wb_fuse, (const float*)nullptr, x, s_x2);
    // 13. LN2
    ln_kernel<bf16><<<MM / 4, 256, 0, stream>>>(s_x2, ln2_g, ln2_b, s_hn);
    // 14. MLP1 + gelu
    mfma_gemm<1, false, HIDN, CC, bf16, bf16><<<dim3(HIDN / 64, MM / 128), 128, 0, stream>>>(
        s_hn, wb_mlp1, mlp1_b, (const bf16*)nullptr, s_h1);
    // 15. MLP2 + residual -> out (f32)
    mfma_gemm<0, true, CC, HIDN, bf16, float><<<dim3(CC / 64, MM / 128), 128, 0, stream>>>(
        s_h1, wb_mlp2, mlp2_b, s_x2, out);
}

// Round 5
// 655.545 us; speedup vs baseline: 2.5852x; 1.2442x over previous
//
#include <hip/hip_runtime.h>
#include <hip/hip_bf16.h>

typedef __hip_bfloat16 bf16;

// Problem constants (B=32, H=W=56, C=192, NH=6, WS=7)
#define BB 32
#define HH 56
#define WW 56
#define CC 192
#define LL 3136            // 56*56
#define MM (BB*LL)         // 100352 tokens
#define C3 576
#define HIDN 384
#define NHEAD 6
#define HD 32
#define NWIN 2048          // B * 8*8

typedef short short8 __attribute__((ext_vector_type(8)));
typedef float f32x4 __attribute__((ext_vector_type(4)));

__device__ __forceinline__ float us2f(unsigned short u) {
    union { unsigned int i; float f; } v; v.i = ((unsigned int)u) << 16; return v.f;
}
__device__ __forceinline__ float b2f(bf16 h) { return __bfloat162float(h); }
__device__ __forceinline__ bf16 f2b(float f) { return __float2bfloat16(f); }
__device__ __forceinline__ short f2bs(float f) { bf16 h = f2b(f); return *reinterpret_cast<short*>(&h); }
__device__ __forceinline__ float ldv(const bf16* p) { return b2f(*p); }
__device__ __forceinline__ float ldv(const float* p) { return *p; }
__device__ __forceinline__ void stv(bf16* p, float v) { *p = f2b(v); }
__device__ __forceinline__ void stv(float* p, float v) { *p = v; }
__device__ __forceinline__ float gelu_exact(float x) {
    return 0.5f * x * (1.0f + erff(x * 0.70710678118654752f));
}
__device__ __forceinline__ void async_lds16(const void* g, void* l) {
    __builtin_amdgcn_global_load_lds(
        (const __attribute__((address_space(1))) void*)g,
        (__attribute__((address_space(3))) void*)l, 16, 0, 0);
}

// ---------------- f32 -> bf16 weight conversion ----------------
__global__ __launch_bounds__(256)
void cvt_kernel(const float* __restrict__ src, bf16* __restrict__ dst, int n)
{
    int i = blockIdx.x * 256 + threadIdx.x;
    if (i < n) dst[i] = f2b(src[i]);
}

// ---------------- LayerNorm: one wave (64 lanes) per row of 192 ----------------
template<typename IT>
__global__ __launch_bounds__(256)
void ln_kernel(const IT* __restrict__ in, const float* __restrict__ g,
               const float* __restrict__ bvec, bf16* __restrict__ out)
{
    int wid = threadIdx.x >> 6, lane = threadIdx.x & 63;
    int row = blockIdx.x * 4 + wid;
    const IT* p = in + (size_t)row * CC;
    float x0 = ldv(p + lane);
    float x1 = ldv(p + lane + 64);
    float x2 = ldv(p + lane + 128);
    float s  = x0 + x1 + x2;
    float sq = x0*x0 + x1*x1 + x2*x2;
    #pragma unroll
    for (int o = 32; o > 0; o >>= 1) {
        s  += __shfl_xor(s,  o, 64);
        sq += __shfl_xor(sq, o, 64);
    }
    float mean = s * (1.0f / CC);
    float var  = sq * (1.0f / CC) - mean * mean;
    float inv  = rsqrtf(fmaxf(var, 0.0f) + 1e-5f);
    bf16* q = out + (size_t)row * CC;
    q[lane]       = f2b((x0 - mean) * inv * g[lane]       + bvec[lane]);
    q[lane + 64]  = f2b((x1 - mean) * inv * g[lane + 64]  + bvec[lane + 64]);
    q[lane + 128] = f2b((x2 - mean) * inv * g[lane + 128] + bvec[lane + 128]);
}

// ---------------- MFMA GEMM: out[M,NN] = act(A[M,KK] @ W[NN,KK]^T + bias) (+resid) ----
template<int ACT, bool RESID, int NN, int KK, typename RT, typename OT>
__global__ __launch_bounds__(128)
void mfma_gemm(const bf16* __restrict__ A, const bf16* __restrict__ W,
               const float* __restrict__ bias, const RT* __restrict__ resid,
               OT* __restrict__ out)
{
    __shared__ __align__(16) short As[128 * 64];
    __shared__ __align__(16) short Bs[64 * 64];
    const int t    = threadIdx.x;
    const int lane = t & 63;
    const int w    = t >> 6;
    const int m0   = blockIdx.y * 128;
    const int n0   = blockIdx.x * 64;
    const int lr   = lane & 15;     // row within 16
    const int lg   = lane >> 4;     // k-group 0..3

    f32x4 acc[4][4];
    #pragma unroll
    for (int i = 0; i < 4; ++i)
        #pragma unroll
        for (int j = 0; j < 4; ++j)
            acc[i][j] = (f32x4){0.f, 0.f, 0.f, 0.f};

    for (int k0 = 0; k0 < KK; k0 += 64) {
        const bf16* Ab = A + (size_t)m0 * KK + k0;
        const bf16* Wb = W + (size_t)n0 * KK + k0;
        #pragma unroll
        for (int li = 0; li < 8; ++li) {
            int chunk = li * 128 + t;
            int r = chunk >> 3, c = chunk & 7;
            int cs = c ^ (r & 7);
            async_lds16(Ab + (size_t)r * KK + (cs << 3),
                        &As[(li * 128 + w * 64) << 3]);
        }
        #pragma unroll
        for (int li = 0; li < 4; ++li) {
            int chunk = li * 128 + t;
            int r = chunk >> 3, c = chunk & 7;
            int cs = c ^ (r & 7);
            async_lds16(Wb + (size_t)r * KK + (cs << 3),
                        &Bs[(li * 128 + w * 64) << 3]);
        }
        __syncthreads();
        #pragma unroll
        for (int kf = 0; kf < 2; ++kf) {
            short8 a_[4], b_[4];
            #pragma unroll
            for (int mi = 0; mi < 4; ++mi) {
                int row = (w << 6) + (mi << 4) + lr;
                a_[mi] = *reinterpret_cast<const short8*>(
                    &As[(row << 6) + ((((kf << 2) + lg) ^ (row & 7)) << 3)]);
            }
            #pragma unroll
            for (int ni = 0; ni < 4; ++ni) {
                int rn = (ni << 4) + lr;
                b_[ni] = *reinterpret_cast<const short8*>(
                    &Bs[(rn << 6) + ((((kf << 2) + lg) ^ (rn & 7)) << 3)]);
            }
            #pragma unroll
            for (int mi = 0; mi < 4; ++mi)
                #pragma unroll
                for (int ni = 0; ni < 4; ++ni)
                    acc[mi][ni] = __builtin_amdgcn_mfma_f32_16x16x32_bf16(
                        a_[mi], b_[ni], acc[mi][ni], 0, 0, 0);
        }
        __syncthreads();
    }

    #pragma unroll
    for (int mi = 0; mi < 4; ++mi) {
        #pragma unroll
        for (int ni = 0; ni < 4; ++ni) {
            int col = n0 + (ni << 4) + lr;
            float bv = bias ? bias[col] : 0.f;
            #pragma unroll
            for (int r = 0; r < 4; ++r) {
                int row = m0 + (w << 6) + (mi << 4) + (lg << 2) + r;
                float c = acc[mi][ni][r] + bv;
                if (ACT == 1) c = gelu_exact(c);
                if (RESID) c += ldv(resid + (size_t)row * NN + col);
                stv(out + (size_t)row * NN + col, c);
            }
        }
    }
}

// ---------------- MFMA window attention: one wave per (window, head) ----------------
__global__ __launch_bounds__(64)
void winattn_kernel(const bf16* __restrict__ qkv, bf16* __restrict__ aw)
{
    __shared__ __align__(16) short Qs[64 * 40];
    __shared__ __align__(16) short Ks[64 * 40];
    __shared__ __align__(16) short Ps[64 * 40];
    __shared__ __align__(16) short Vt[32 * 72];

    const int wi   = blockIdx.x;         // 0..2047
    const int head = blockIdx.y;         // 0..5
    const int b  = wi >> 6;
    const int wr = wi & 63;
    const int wy = wr >> 3, wx = wr & 7;
    const int t  = threadIdx.x;          // 0..63
    const int lc = t & 15;
    const int lg = t >> 4;
    const float scale = 0.1767766952966369f;   // 32^-0.5

    #pragma unroll
    for (int e = t; e < 256; e += 64) {
        int r = 48 + (e >> 4), c = (e & 15) << 1;
        *reinterpret_cast<int*>(&Ks[r * 40 + c]) = 0;
    }
    #pragma unroll
    for (int e = t; e < 512; e += 64) {
        int r = e >> 4, c = 48 + (e & 15);
        Vt[r * 72 + c] = 0;
    }

    for (int e = t; e < 196; e += 64) {
        int tok = e >> 2, part = e & 3;
        int iy = tok / 7, ix = tok - iy * 7;
        size_t l = (size_t)(wy * 7 + iy) * 56 + wx * 7 + ix;
        const bf16* base = qkv + ((size_t)b * LL + l) * C3 + head * HD + (part << 3);
        uint4 pq = *reinterpret_cast<const uint4*>(base);
        uint4 pk = *reinterpret_cast<const uint4*>(base + 192);
        uint4 pv = *reinterpret_cast<const uint4*>(base + 384);
        *reinterpret_cast<uint4*>(&Qs[tok * 40 + (part << 3)]) = pq;
        *reinterpret_cast<uint4*>(&Ks[tok * 40 + (part << 3)]) = pk;
        unsigned short uv[8];
        *reinterpret_cast<uint4*>(uv) = pv;
        #pragma unroll
        for (int jj = 0; jj < 8; ++jj)
            Vt[((part << 3) + jj) * 72 + tok] = (short)uv[jj];
    }
    __syncthreads();

    f32x4 acc[4][4];
    #pragma unroll
    for (int i = 0; i < 4; ++i)
        #pragma unroll
        for (int j = 0; j < 4; ++j)
            acc[i][j] = (f32x4){0.f, 0.f, 0.f, 0.f};
    {
        short8 a_[4], b_[4];
        #pragma unroll
        for (int mi = 0; mi < 4; ++mi)
            a_[mi] = *reinterpret_cast<const short8*>(&Qs[((mi << 4) + lc) * 40 + (lg << 3)]);
        #pragma unroll
        for (int ni = 0; ni < 4; ++ni)
            b_[ni] = *reinterpret_cast<const short8*>(&Ks[((ni << 4) + lc) * 40 + (lg << 3)]);
        #pragma unroll
        for (int mi = 0; mi < 4; ++mi)
            #pragma unroll
            for (int ni = 0; ni < 4; ++ni)
                acc[mi][ni] = __builtin_amdgcn_mfma_f32_16x16x32_bf16(
                    a_[mi], b_[ni], acc[mi][ni], 0, 0, 0);
    }

    float rinv[4][4];
    #pragma unroll
    for (int mi = 0; mi < 4; ++mi) {
        #pragma unroll
        for (int r = 0; r < 4; ++r) {
            float mx = -1e30f;
            #pragma unroll
            for (int ni = 0; ni < 4; ++ni) {
                float v = acc[mi][ni][r];
                if (ni == 3 && lc != 0) v = -1e30f;
                mx = fmaxf(mx, v);
            }
            mx = fmaxf(mx, __shfl_xor(mx, 1, 64));
            mx = fmaxf(mx, __shfl_xor(mx, 2, 64));
            mx = fmaxf(mx, __shfl_xor(mx, 4, 64));
            mx = fmaxf(mx, __shfl_xor(mx, 8, 64));
            float sm = 0.f;
            int row = (mi << 4) + (lg << 2) + r;
            #pragma unroll
            for (int ni = 0; ni < 4; ++ni) {
                float e = (ni == 3 && lc != 0) ? 0.f
                        : __expf(scale * (acc[mi][ni][r] - mx));
                Ps[row * 40 + (ni << 4) + lc] = f2bs(e);
                sm += e;
            }
            sm += __shfl_xor(sm, 1, 64);
            sm += __shfl_xor(sm, 2, 64);
            sm += __shfl_xor(sm, 4, 64);
            sm += __shfl_xor(sm, 8, 64);
            rinv[mi][r] = 1.0f / sm;
        }
    }
    __syncthreads();

    f32x4 o[4][2];
    #pragma unroll
    for (int i = 0; i < 4; ++i) {
        o[i][0] = (f32x4){0.f, 0.f, 0.f, 0.f};
        o[i][1] = (f32x4){0.f, 0.f, 0.f, 0.f};
    }
    #pragma unroll
    for (int kf = 0; kf < 2; ++kf) {
        short8 pa[4], vb[2];
        #pragma unroll
        for (int mi = 0; mi < 4; ++mi)
            pa[mi] = *reinterpret_cast<const short8*>(
                &Ps[((mi << 4) + lc) * 40 + (kf << 5) + (lg << 3)]);
        #pragma unroll
        for (int n2 = 0; n2 < 2; ++n2)
            vb[n2] = *reinterpret_cast<const short8*>(
                &Vt[((n2 << 4) + lc) * 72 + (kf << 5) + (lg << 3)]);
        #pragma unroll
        for (int mi = 0; mi < 4; ++mi)
            #pragma unroll
            for (int n2 = 0; n2 < 2; ++n2)
                o[mi][n2] = __builtin_amdgcn_mfma_f32_16x16x32_bf16(
                    pa[mi], vb[n2], o[mi][n2], 0, 0, 0);
    }

    #pragma unroll
    for (int mi = 0; mi < 4; ++mi) {
        #pragma unroll
        for (int r = 0; r < 4; ++r) {
            int row = (mi << 4) + (lg << 2) + r;
            if (row < 49) {
                int iy = row / 7, ix = row - iy * 7;
                size_t l = (size_t)(wy * 7 + iy) * 56 + wx * 7 + ix;
                bf16* dst = aw + ((size_t)b * LL + l) * CC + head * HD + lc;
                float inv = rinv[mi][r];
                dst[0]  = f2b(o[mi][0][r] * inv);
                dst[16] = f2b(o[mi][1][r] * inv);
            }
        }
    }
}

// ---------------- Depthwise 3x3 (SAME) + exact GELU, vectorized 8-ch/thread ----------
// Weights in LDS padded to 12 f32 per 8-ch group: 16B-aligned float4 reads,
// lane stride 12 -> ~free bank pattern. Thread e: pixel e/24, channels (e%24)*8..+8.
__global__ __launch_bounds__(256)
void dwconv_kernel(const bf16* __restrict__ xn, const float* __restrict__ w,
                   bf16* __restrict__ out)
{
    __shared__ float wl[9 * 288];
    const int t = threadIdx.x;
    for (int i = t; i < CC * 9; i += 256) {
        int c = i / 9, k = i - c * 9;
        wl[k * 288 + (c >> 3) * 12 + (c & 7)] = w[i];
    }
    __syncthreads();
    int e = blockIdx.x * 256 + t;          // 0 .. MM*24-1 (exact grid)
    int cg = e % 24;
    int pix = e / 24;
    int w_ = pix % WW;
    int t2 = pix / WW;
    int h_ = t2 % HH;
    int b  = t2 / HH;
    float acc[8] = {0.f,0.f,0.f,0.f,0.f,0.f,0.f,0.f};
    const bf16* rowbase = xn + ((size_t)b * HH * WW) * CC + (size_t)cg * 8;
    #pragma unroll
    for (int ky = 0; ky < 3; ++ky) {
        int hy = h_ + ky - 1;
        if (hy < 0 || hy >= HH) continue;
        #pragma unroll
        for (int kx = 0; kx < 3; ++kx) {
            int wx_ = w_ + kx - 1;
            if (wx_ < 0 || wx_ >= WW) continue;
            int k = ky * 3 + kx;
            const float4* wp = reinterpret_cast<const float4*>(&wl[k * 288 + cg * 12]);
            float4 w0 = wp[0];
            float4 w1 = wp[1];
            unsigned short u[8];
            *reinterpret_cast<uint4*>(u) = *reinterpret_cast<const uint4*>(
                rowbase + ((size_t)hy * WW + wx_) * CC);
            acc[0] += us2f(u[0]) * w0.x;
            acc[1] += us2f(u[1]) * w0.y;
            acc[2] += us2f(u[2]) * w0.z;
            acc[3] += us2f(u[3]) * w0.w;
            acc[4] += us2f(u[4]) * w1.x;
            acc[5] += us2f(u[5]) * w1.y;
            acc[6] += us2f(u[6]) * w1.z;
            acc[7] += us2f(u[7]) * w1.w;
        }
    }
    bf16 o8[8];
    #pragma unroll
    for (int j = 0; j < 8; ++j) o8[j] = f2b(gelu_exact(acc[j]));
    *reinterpret_cast<uint4*>(out + (size_t)e * 8) = *reinterpret_cast<uint4*>(o8);
}

// ---------------- column (spatial) sum of xn per (b, c) ----------------
__global__ __launch_bounds__(192)
void colsum_kernel(const bf16* __restrict__ xn, float* __restrict__ colsum)
{
    int b = blockIdx.y, g = blockIdx.x, c = threadIdx.x;
    float acc = 0.f;
    int l0 = g * 196;
    for (int l = l0; l < l0 + 196; ++l)
        acc += b2f(xn[((size_t)b * LL + l) * CC + c]);
    atomicAdd(&colsum[b * CC + c], acc);
}

__global__ __launch_bounds__(192)
void gate_kernel(const float* __restrict__ colsum, const float* __restrict__ gw,
                 const float* __restrict__ gb, float* __restrict__ gate)
{
    __shared__ float cm[CC];
    int b = blockIdx.x, o = threadIdx.x;
    cm[o] = colsum[b * CC + o] * (1.0f / LL);
    __syncthreads();
    float acc = gb[o];
    for (int c = 0; c < CC; ++c) acc += gw[o * CC + c] * cm[c];
    gate[b * CC + o] = 1.0f / (1.0f + expf(-acc));
}

// ---------------- xf = x_attn + ld + xn * gate[b,c] (vec8) ----------------
__global__ __launch_bounds__(256)
void combine_kernel(const bf16* __restrict__ xattn, const bf16* __restrict__ ld,
                    const bf16* __restrict__ xn, const float* __restrict__ gate,
                    bf16* __restrict__ xf)
{
    int e = blockIdx.x * 256 + threadIdx.x;    // 0 .. MM*24-1
    int cg = e % 24, c0 = cg << 3;
    int b  = e / (LL * 24);
    size_t base = (size_t)e * 8;
    unsigned short ua[8], ul[8], ux[8];
    *reinterpret_cast<uint4*>(ua) = *reinterpret_cast<const uint4*>(xattn + base);
    *reinterpret_cast<uint4*>(ul) = *reinterpret_cast<const uint4*>(ld + base);
    *reinterpret_cast<uint4*>(ux) = *reinterpret_cast<const uint4*>(xn + base);
    const float4* gp = reinterpret_cast<const float4*>(gate + b * CC + c0);
    float4 g0 = gp[0], g1 = gp[1];
    float gg[8] = {g0.x, g0.y, g0.z, g0.w, g1.x, g1.y, g1.z, g1.w};
    bf16 o8[8];
    #pragma unroll
    for (int j = 0; j < 8; ++j)
        o8[j] = f2b(us2f(ua[j]) + us2f(ul[j]) + us2f(ux[j]) * gg[j]);
    *reinterpret_cast<uint4*>(xf + base) = *reinterpret_cast<uint4*>(o8);
}

// ---------------- means over H (-> [B][W][C]) and over W (-> [B][H][C]), vec8 --------
__global__ __launch_bounds__(256)
void mean_h_kernel(const bf16* __restrict__ xf, float* __restrict__ mh)
{
    int e = blockIdx.x * 256 + threadIdx.x;   // BB*WW*24
    if (e >= BB * WW * 24) return;
    int cg = e % 24, c0 = cg << 3;
    int w_ = (e / 24) % WW;
    int b  = e / (24 * WW);
    float s[8] = {0.f,0.f,0.f,0.f,0.f,0.f,0.f,0.f};
    const bf16* base = xf + ((size_t)b * HH * WW + w_) * CC + c0;
    for (int h_ = 0; h_ < HH; ++h_) {
        unsigned short u[8];
        *reinterpret_cast<uint4*>(u) = *reinterpret_cast<const uint4*>(base + (size_t)h_ * WW * CC);
        #pragma unroll
        for (int j = 0; j < 8; ++j) s[j] += us2f(u[j]);
    }
    float* dst = mh + ((size_t)b * WW + w_) * CC + c0;
    #pragma unroll
    for (int j = 0; j < 8; ++j) dst[j] = s[j] * (1.0f / HH);
}

__global__ __launch_bounds__(256)
void mean_w_kernel(const bf16* __restrict__ xf, float* __restrict__ mw)
{
    int e = blockIdx.x * 256 + threadIdx.x;   // BB*HH*24
    if (e >= BB * HH * 24) return;
    int cg = e % 24, c0 = cg << 3;
    int h_ = (e / 24) % HH;
    int b  = e / (24 * HH);
    float s[8] = {0.f,0.f,0.f,0.f,0.f,0.f,0.f,0.f};
    const bf16* base = xf + ((size_t)b * HH + h_) * WW * CC + c0;
    for (int w_ = 0; w_ < WW; ++w_) {
        unsigned short u[8];
        *reinterpret_cast<uint4*>(u) = *reinterpret_cast<const uint4*>(base + (size_t)w_ * CC);
        #pragma unroll
        for (int j = 0; j < 8; ++j) s[j] += us2f(u[j]);
    }
    float* dst = mw + ((size_t)b * HH + h_) * CC + c0;
    #pragma unroll
    for (int j = 0; j < 8; ++j) dst[j] = s[j] * (1.0f / WW);
}

// ---------------- logits over one spatial axis + softmax over the 56 positions ------------
__global__ __launch_bounds__(64)
void axsoftmax_kernel(const float* __restrict__ mean, const float* __restrict__ w,
                      const float* __restrict__ bias, float* __restrict__ out)
{
    __shared__ float wrow[CC];
    int o = blockIdx.x, b = blockIdx.y, lane = threadIdx.x;
    for (int c = lane; c < CC; c += 64) wrow[c] = w[o * CC + c];
    __syncthreads();
    float logit = -1e30f;
    if (lane < 56) {
        const float* mr = mean + ((size_t)b * 56 + lane) * CC;
        float a = bias[o];
        for (int c = 0; c < CC; ++c) a += wrow[c] * mr[c];
        logit = a;
    }
    float m = logit;
    #pragma unroll
    for (int off = 32; off > 0; off >>= 1) m = fmaxf(m, __shfl_xor(m, off, 64));
    float e = (lane < 56) ? expf(logit - m) : 0.f;
    float s = e;
    #pragma unroll
    for (int off = 32; off > 0; off >>= 1) s += __shfl_xor(s, off, 64);
    if (lane < 56) out[((size_t)b * CC + o) * 56 + lane] = e / s;
}

// ---------------- xf2 = xf * a_s[b,c,h] * a_t[b,c,w] * 2  (vec8) ----------------
__global__ __launch_bounds__(256)
void modulate_kernel(const bf16* __restrict__ xf, const float* __restrict__ a_s,
                     const float* __restrict__ a_t, bf16* __restrict__ xf2)
{
    int e = blockIdx.x * 256 + threadIdx.x;    // 0 .. MM*24-1
    int cg = e % 24, c0 = cg << 3;
    int pix = e / 24;
    int w_ = pix % WW;
    int t2 = pix / WW;
    int h_ = t2 % HH;
    int b  = t2 / HH;
    unsigned short u[8];
    size_t base = (size_t)e * 8;
    *reinterpret_cast<uint4*>(u) = *reinterpret_cast<const uint4*>(xf + base);
    bf16 o8[8];
    #pragma unroll
    for (int j = 0; j < 8; ++j) {
        int c = c0 + j;
        float v = us2f(u[j]) * a_s[((size_t)b * CC + c) * 56 + h_]
                             * a_t[((size_t)b * CC + c) * 56 + w_] * 2.0f;
        o8[j] = f2b(v);
    }
    *reinterpret_cast<uint4*>(xf2 + base) = *reinterpret_cast<uint4*>(o8);
}

// =======================================================================================
extern "C" void kernel_launch(void* const* d_in, const int* in_sizes, int n_in,
                              void* d_out, int out_size, void* d_ws, size_t ws_size,
                              hipStream_t stream)
{
    const float* x      = (const float*)d_in[0];
    const float* ln1_g  = (const float*)d_in[3];
    const float* ln1_b  = (const float*)d_in[4];
    const float* qkv_w  = (const float*)d_in[5];
    const float* qkv_b  = (const float*)d_in[6];
    const float* proj_w = (const float*)d_in[7];
    const float* proj_b = (const float*)d_in[8];
    const float* dw_w   = (const float*)d_in[9];
    const float* pw_w   = (const float*)d_in[10];
    const float* gate_w = (const float*)d_in[11];
    const float* gate_b = (const float*)d_in[12];
    const float* temp_w = (const float*)d_in[13];
    const float* temp_b = (const float*)d_in[14];
    const float* spec_w = (const float*)d_in[15];
    const float* spec_b = (const float*)d_in[16];
    const float* fuse_w = (const float*)d_in[17];
    const float* ln2_g  = (const float*)d_in[18];
    const float* ln2_b  = (const float*)d_in[19];
    const float* mlp1_w = (const float*)d_in[20];
    const float* mlp1_b = (const float*)d_in[21];
    const float* mlp2_w = (const float*)d_in[22];
    const float* mlp2_b = (const float*)d_in[23];
    float* out = (float*)d_out;

    const size_t SLOT = (size_t)MM * CC * sizeof(bf16);   // 38,535,168 B
    char* ws = (char*)d_ws;

    bf16* s_xn    = (bf16*)(ws);
    bf16* s_qkv   = (bf16*)(ws + SLOT);        // 3 slots
    bf16* s_aw    = (bf16*)(ws + 4 * SLOT);
    bf16* s_xattn = (bf16*)(ws + SLOT);        // reuse qkv slot 1
    bf16* s_dwg   = (bf16*)(ws + 2 * SLOT);
    bf16* s_ld    = (bf16*)(ws + 3 * SLOT);
    bf16* s_xf    = (bf16*)(ws + 4 * SLOT);    // reuse aw
    bf16* s_xf2   = (bf16*)(ws);               // reuse xn
    bf16* s_x2    = (bf16*)(ws + SLOT);        // reuse xattn
    bf16* s_hn    = (bf16*)(ws + 2 * SLOT);
    bf16* s_h1    = (bf16*)(ws + 3 * SLOT);    // spans slots 3..4 (384 ch)

    float* colsum  = (float*)(ws + 5 * SLOT);
    float* gatebuf = colsum + BB * CC;
    float* mean_h  = gatebuf + BB * CC;
    float* mean_w  = mean_h + (size_t)BB * 56 * CC;
    float* a_t     = mean_w + (size_t)BB * 56 * CC;
    float* a_s     = a_t    + (size_t)BB * CC * 56;
    // bf16 weight copies
    bf16* wb_qkv  = (bf16*)(a_s + (size_t)BB * CC * 56);
    bf16* wb_proj = wb_qkv  + C3 * CC;
    bf16* wb_pw   = wb_proj + CC * CC;
    bf16* wb_fuse = wb_pw   + CC * CC;
    bf16* wb_mlp1 = wb_fuse + CC * CC;
    bf16* wb_mlp2 = wb_mlp1 + HIDN * CC;
    size_t total_need = (char*)(wb_mlp2 + CC * HIDN) - ws;
    if (ws_size < total_need) return;   // workspace insufficient — visible failure

    const int VEC_BLOCKS = MM * 24 / 256;   // 9408, exact

    // 0. weight conversions (f32 -> bf16)
    cvt_kernel<<<(C3 * CC + 255) / 256, 256, 0, stream>>>(qkv_w, wb_qkv, C3 * CC);
    cvt_kernel<<<(CC * CC + 255) / 256, 256, 0, stream>>>(proj_w, wb_proj, CC * CC);
    cvt_kernel<<<(CC * CC + 255) / 256, 256, 0, stream>>>(pw_w, wb_pw, CC * CC);
    cvt_kernel<<<(CC * CC + 255) / 256, 256, 0, stream>>>(fuse_w, wb_fuse, CC * CC);
    cvt_kernel<<<(HIDN * CC + 255) / 256, 256, 0, stream>>>(mlp1_w, wb_mlp1, HIDN * CC);
    cvt_kernel<<<(CC * HIDN + 255) / 256, 256, 0, stream>>>(mlp2_w, wb_mlp2, CC * HIDN);

    // 1. LN1
    ln_kernel<float><<<MM / 4, 256, 0, stream>>>(x, ln1_g, ln1_b, s_xn);
    // 2. qkv
    mfma_gemm<0, false, C3, CC, bf16, bf16><<<dim3(C3 / 64, MM / 128), 128, 0, stream>>>(
        s_xn, wb_qkv, qkv_b, (const bf16*)nullptr, s_qkv);
    // 3. window attention (MFMA, 1 wave per (window, head))
    winattn_kernel<<<dim3(NWIN, NHEAD), 64, 0, stream>>>(s_qkv, s_aw);
    // 4. proj
    mfma_gemm<0, false, CC, CC, bf16, bf16><<<dim3(CC / 64, MM / 128), 128, 0, stream>>>(
        s_aw, wb_proj, proj_b, (const bf16*)nullptr, s_xattn);
    // 5. depthwise + gelu (vec8)
    dwconv_kernel<<<VEC_BLOCKS, 256, 0, stream>>>(s_xn, dw_w, s_dwg);
    // 6. pointwise (no bias)
    mfma_gemm<0, false, CC, CC, bf16, bf16><<<dim3(CC / 64, MM / 128), 128, 0, stream>>>(
        s_dwg, wb_pw, (const float*)nullptr, (const bf16*)nullptr, s_ld);
    // 7. gate
    hipMemsetAsync(colsum, 0, BB * CC * sizeof(float), stream);
    colsum_kernel<<<dim3(16, BB), 192, 0, stream>>>(s_xn, colsum);
    gate_kernel<<<BB, 192, 0, stream>>>(colsum, gate_w, gate_b, gatebuf);
    // 8. xf = x_attn + ld + xn*gate
    combine_kernel<<<VEC_BLOCKS, 256, 0, stream>>>(s_xattn, s_ld, s_xn, gatebuf, s_xf);
    // 9. axis means
    mean_h_kernel<<<(BB * WW * 24 + 255) / 256, 256, 0, stream>>>(s_xf, mean_h);
    mean_w_kernel<<<(BB * HH * 24 + 255) / 256, 256, 0, stream>>>(s_xf, mean_w);
    // 10. a_t (temporal, over W) and a_s (spectral, over H)
    axsoftmax_kernel<<<dim3(CC, BB), 64, 0, stream>>>(mean_h, temp_w, temp_b, a_t);
    axsoftmax_kernel<<<dim3(CC, BB), 64, 0, stream>>>(mean_w, spec_w, spec_b, a_s);
    // 11. modulate
    modulate_kernel<<<VEC_BLOCKS, 256, 0, stream>>>(s_xf, a_s, a_t, s_xf2);
    // 12. fuse (no bias) + residual from original x -> x2
    mfma_gemm<0, true, CC, CC, float, bf16><<<dim3(CC / 64, MM / 128), 128, 0, stream>>>(
        s_xf2, wb_fuse, (const float*)nullptr, x, s_x2);
    // 13. LN2
    ln_kernel<bf16><<<MM / 4, 256, 0, stream>>>(s_x2, ln2_g, ln2_b, s_hn);
    // 14. MLP1 + gelu
    mfma_gemm<1, false, HIDN, CC, bf16, bf16><<<dim3(HIDN / 64, MM / 128), 128, 0, stream>>>(
        s_hn, wb_mlp1, mlp1_b, (const bf16*)nullptr, s_h1);
    // 15. MLP2 + residual -> out (f32)
    mfma_gemm<0, true, CC, HIDN, bf16, float><<<dim3(CC / 64, MM / 128), 128, 0, stream>>>(
        s_h1, wb_mlp2, mlp2_b, s_x2, out);
}

// Round 6
// 592.654 us; speedup vs baseline: 2.8595x; 1.1061x over previous
//
#include <hip/hip_runtime.h>
#include <hip/hip_bf16.h>

typedef __hip_bfloat16 bf16;

// Problem constants (B=32, H=W=56, C=192, NH=6, WS=7)
#define BB 32
#define HH 56
#define WW 56
#define CC 192
#define LL 3136            // 56*56
#define MM (BB*LL)         // 100352 tokens
#define C3 576
#define HIDN 384
#define NHEAD 6
#define HD 32
#define NWIN 2048          // B * 8*8

typedef short short8 __attribute__((ext_vector_type(8)));
typedef float f32x4 __attribute__((ext_vector_type(4)));

__device__ __forceinline__ float us2f(unsigned short u) {
    union { unsigned int i; float f; } v; v.i = ((unsigned int)u) << 16; return v.f;
}
__device__ __forceinline__ float b2f(bf16 h) { return __bfloat162float(h); }
__device__ __forceinline__ bf16 f2b(float f) { return __float2bfloat16(f); }
__device__ __forceinline__ short f2bs(float f) { bf16 h = f2b(f); return *reinterpret_cast<short*>(&h); }
__device__ __forceinline__ float ldv(const bf16* p) { return b2f(*p); }
__device__ __forceinline__ float ldv(const float* p) { return *p; }
__device__ __forceinline__ void stv(bf16* p, float v) { *p = f2b(v); }
__device__ __forceinline__ void stv(float* p, float v) { *p = v; }
__device__ __forceinline__ float gelu_exact(float x) {
    return 0.5f * x * (1.0f + erff(x * 0.70710678118654752f));
}
__device__ __forceinline__ void async_lds16(const void* g, void* l) {
    __builtin_amdgcn_global_load_lds(
        (const __attribute__((address_space(1))) void*)g,
        (__attribute__((address_space(3))) void*)l, 16, 0, 0);
}

// ---------------- f32 -> bf16 weight conversion ----------------
__global__ __launch_bounds__(256)
void cvt_kernel(const float* __restrict__ src, bf16* __restrict__ dst, int n)
{
    int i = blockIdx.x * 256 + threadIdx.x;
    if (i < n) dst[i] = f2b(src[i]);
}

// ---------------- LayerNorm: one wave (64 lanes) per row of 192 ----------------
template<typename IT>
__global__ __launch_bounds__(256)
void ln_kernel(const IT* __restrict__ in, const float* __restrict__ g,
               const float* __restrict__ bvec, bf16* __restrict__ out)
{
    int wid = threadIdx.x >> 6, lane = threadIdx.x & 63;
    int row = blockIdx.x * 4 + wid;
    const IT* p = in + (size_t)row * CC;
    float x0 = ldv(p + lane);
    float x1 = ldv(p + lane + 64);
    float x2 = ldv(p + lane + 128);
    float s  = x0 + x1 + x2;
    float sq = x0*x0 + x1*x1 + x2*x2;
    #pragma unroll
    for (int o = 32; o > 0; o >>= 1) {
        s  += __shfl_xor(s,  o, 64);
        sq += __shfl_xor(sq, o, 64);
    }
    float mean = s * (1.0f / CC);
    float var  = sq * (1.0f / CC) - mean * mean;
    float inv  = rsqrtf(fmaxf(var, 0.0f) + 1e-5f);
    bf16* q = out + (size_t)row * CC;
    q[lane]       = f2b((x0 - mean) * inv * g[lane]       + bvec[lane]);
    q[lane + 64]  = f2b((x1 - mean) * inv * g[lane + 64]  + bvec[lane + 64]);
    q[lane + 128] = f2b((x2 - mean) * inv * g[lane + 128] + bvec[lane + 128]);
}

// ---------------- MFMA GEMM: out[M,NN] = epi(A[M,KK] @ W[NN,KK]^T + bias) ----
// EPI: 0=none, 1=gelu, 2=combine (out = acc + resid + b2f(xn2)*gate[b,c]).
// RESID adds resid separately (EPI!=2 path).
template<int EPI, bool RESID, int NN, int KK, typename RT, typename OT>
__global__ __launch_bounds__(128)
void mfma_gemm(const bf16* __restrict__ A, const bf16* __restrict__ W,
               const float* __restrict__ bias, const RT* __restrict__ resid,
               OT* __restrict__ out,
               const bf16* __restrict__ xn2, const float* __restrict__ gate)
{
    __shared__ __align__(16) short As[128 * 64];
    __shared__ __align__(16) short Bs[64 * 64];
    const int t    = threadIdx.x;
    const int lane = t & 63;
    const int w    = t >> 6;
    const int m0   = blockIdx.y * 128;
    const int n0   = blockIdx.x * 64;
    const int lr   = lane & 15;     // row within 16
    const int lg   = lane >> 4;     // k-group 0..3

    f32x4 acc[4][4];
    #pragma unroll
    for (int i = 0; i < 4; ++i)
        #pragma unroll
        for (int j = 0; j < 4; ++j)
            acc[i][j] = (f32x4){0.f, 0.f, 0.f, 0.f};

    for (int k0 = 0; k0 < KK; k0 += 64) {
        const bf16* Ab = A + (size_t)m0 * KK + k0;
        const bf16* Wb = W + (size_t)n0 * KK + k0;
        #pragma unroll
        for (int li = 0; li < 8; ++li) {
            int chunk = li * 128 + t;
            int r = chunk >> 3, c = chunk & 7;
            int cs = c ^ (r & 7);
            async_lds16(Ab + (size_t)r * KK + (cs << 3),
                        &As[(li * 128 + w * 64) << 3]);
        }
        #pragma unroll
        for (int li = 0; li < 4; ++li) {
            int chunk = li * 128 + t;
            int r = chunk >> 3, c = chunk & 7;
            int cs = c ^ (r & 7);
            async_lds16(Wb + (size_t)r * KK + (cs << 3),
                        &Bs[(li * 128 + w * 64) << 3]);
        }
        __syncthreads();
        #pragma unroll
        for (int kf = 0; kf < 2; ++kf) {
            short8 a_[4], b_[4];
            #pragma unroll
            for (int mi = 0; mi < 4; ++mi) {
                int row = (w << 6) + (mi << 4) + lr;
                a_[mi] = *reinterpret_cast<const short8*>(
                    &As[(row << 6) + ((((kf << 2) + lg) ^ (row & 7)) << 3)]);
            }
            #pragma unroll
            for (int ni = 0; ni < 4; ++ni) {
                int rn = (ni << 4) + lr;
                b_[ni] = *reinterpret_cast<const short8*>(
                    &Bs[(rn << 6) + ((((kf << 2) + lg) ^ (rn & 7)) << 3)]);
            }
            #pragma unroll
            for (int mi = 0; mi < 4; ++mi)
                #pragma unroll
                for (int ni = 0; ni < 4; ++ni)
                    acc[mi][ni] = __builtin_amdgcn_mfma_f32_16x16x32_bf16(
                        a_[mi], b_[ni], acc[mi][ni], 0, 0, 0);
        }
        __syncthreads();
    }

    #pragma unroll
    for (int mi = 0; mi < 4; ++mi) {
        #pragma unroll
        for (int ni = 0; ni < 4; ++ni) {
            int col = n0 + (ni << 4) + lr;
            float bv = bias ? bias[col] : 0.f;
            #pragma unroll
            for (int r = 0; r < 4; ++r) {
                int row = m0 + (w << 6) + (mi << 4) + (lg << 2) + r;
                float c = acc[mi][ni][r] + bv;
                if (EPI == 1) c = gelu_exact(c);
                if (EPI == 2) {
                    int bidx = row / LL;
                    c += ldv(resid + (size_t)row * NN + col)
                       + b2f(xn2[(size_t)row * NN + col]) * gate[bidx * CC + col];
                }
                if (RESID) c += ldv(resid + (size_t)row * NN + col);
                stv(out + (size_t)row * NN + col, c);
            }
        }
    }
}

// ---------------- MFMA window attention: one wave per (window, head) ----------------
__global__ __launch_bounds__(64)
void winattn_kernel(const bf16* __restrict__ qkv, bf16* __restrict__ aw)
{
    __shared__ __align__(16) short Qs[64 * 40];
    __shared__ __align__(16) short Ks[64 * 40];
    __shared__ __align__(16) short Ps[64 * 40];
    __shared__ __align__(16) short Vt[32 * 72];

    const int wi   = blockIdx.x;         // 0..2047
    const int head = blockIdx.y;         // 0..5
    const int b  = wi >> 6;
    const int wr = wi & 63;
    const int wy = wr >> 3, wx = wr & 7;
    const int t  = threadIdx.x;          // 0..63
    const int lc = t & 15;
    const int lg = t >> 4;
    const float scale = 0.1767766952966369f;   // 32^-0.5

    #pragma unroll
    for (int e = t; e < 256; e += 64) {
        int r = 48 + (e >> 4), c = (e & 15) << 1;
        *reinterpret_cast<int*>(&Ks[r * 40 + c]) = 0;
    }
    #pragma unroll
    for (int e = t; e < 512; e += 64) {
        int r = e >> 4, c = 48 + (e & 15);
        Vt[r * 72 + c] = 0;
    }

    for (int e = t; e < 196; e += 64) {
        int tok = e >> 2, part = e & 3;
        int iy = tok / 7, ix = tok - iy * 7;
        size_t l = (size_t)(wy * 7 + iy) * 56 + wx * 7 + ix;
        const bf16* base = qkv + ((size_t)b * LL + l) * C3 + head * HD + (part << 3);
        uint4 pq = *reinterpret_cast<const uint4*>(base);
        uint4 pk = *reinterpret_cast<const uint4*>(base + 192);
        uint4 pv = *reinterpret_cast<const uint4*>(base + 384);
        *reinterpret_cast<uint4*>(&Qs[tok * 40 + (part << 3)]) = pq;
        *reinterpret_cast<uint4*>(&Ks[tok * 40 + (part << 3)]) = pk;
        unsigned short uv[8];
        *reinterpret_cast<uint4*>(uv) = pv;
        #pragma unroll
        for (int jj = 0; jj < 8; ++jj)
            Vt[((part << 3) + jj) * 72 + tok] = (short)uv[jj];
    }
    __syncthreads();

    f32x4 acc[4][4];
    #pragma unroll
    for (int i = 0; i < 4; ++i)
        #pragma unroll
        for (int j = 0; j < 4; ++j)
            acc[i][j] = (f32x4){0.f, 0.f, 0.f, 0.f};
    {
        short8 a_[4], b_[4];
        #pragma unroll
        for (int mi = 0; mi < 4; ++mi)
            a_[mi] = *reinterpret_cast<const short8*>(&Qs[((mi << 4) + lc) * 40 + (lg << 3)]);
        #pragma unroll
        for (int ni = 0; ni < 4; ++ni)
            b_[ni] = *reinterpret_cast<const short8*>(&Ks[((ni << 4) + lc) * 40 + (lg << 3)]);
        #pragma unroll
        for (int mi = 0; mi < 4; ++mi)
            #pragma unroll
            for (int ni = 0; ni < 4; ++ni)
                acc[mi][ni] = __builtin_amdgcn_mfma_f32_16x16x32_bf16(
                    a_[mi], b_[ni], acc[mi][ni], 0, 0, 0);
    }

    float rinv[4][4];
    #pragma unroll
    for (int mi = 0; mi < 4; ++mi) {
        #pragma unroll
        for (int r = 0; r < 4; ++r) {
            float mx = -1e30f;
            #pragma unroll
            for (int ni = 0; ni < 4; ++ni) {
                float v = acc[mi][ni][r];
                if (ni == 3 && lc != 0) v = -1e30f;
                mx = fmaxf(mx, v);
            }
            mx = fmaxf(mx, __shfl_xor(mx, 1, 64));
            mx = fmaxf(mx, __shfl_xor(mx, 2, 64));
            mx = fmaxf(mx, __shfl_xor(mx, 4, 64));
            mx = fmaxf(mx, __shfl_xor(mx, 8, 64));
            float sm = 0.f;
            int row = (mi << 4) + (lg << 2) + r;
            #pragma unroll
            for (int ni = 0; ni < 4; ++ni) {
                float e = (ni == 3 && lc != 0) ? 0.f
                        : __expf(scale * (acc[mi][ni][r] - mx));
                Ps[row * 40 + (ni << 4) + lc] = f2bs(e);
                sm += e;
            }
            sm += __shfl_xor(sm, 1, 64);
            sm += __shfl_xor(sm, 2, 64);
            sm += __shfl_xor(sm, 4, 64);
            sm += __shfl_xor(sm, 8, 64);
            rinv[mi][r] = 1.0f / sm;
        }
    }
    __syncthreads();

    f32x4 o[4][2];
    #pragma unroll
    for (int i = 0; i < 4; ++i) {
        o[i][0] = (f32x4){0.f, 0.f, 0.f, 0.f};
        o[i][1] = (f32x4){0.f, 0.f, 0.f, 0.f};
    }
    #pragma unroll
    for (int kf = 0; kf < 2; ++kf) {
        short8 pa[4], vb[2];
        #pragma unroll
        for (int mi = 0; mi < 4; ++mi)
            pa[mi] = *reinterpret_cast<const short8*>(
                &Ps[((mi << 4) + lc) * 40 + (kf << 5) + (lg << 3)]);
        #pragma unroll
        for (int n2 = 0; n2 < 2; ++n2)
            vb[n2] = *reinterpret_cast<const short8*>(
                &Vt[((n2 << 4) + lc) * 72 + (kf << 5) + (lg << 3)]);
        #pragma unroll
        for (int mi = 0; mi < 4; ++mi)
            #pragma unroll
            for (int n2 = 0; n2 < 2; ++n2)
                o[mi][n2] = __builtin_amdgcn_mfma_f32_16x16x32_bf16(
                    pa[mi], vb[n2], o[mi][n2], 0, 0, 0);
    }

    #pragma unroll
    for (int mi = 0; mi < 4; ++mi) {
        #pragma unroll
        for (int r = 0; r < 4; ++r) {
            int row = (mi << 4) + (lg << 2) + r;
            if (row < 49) {
                int iy = row / 7, ix = row - iy * 7;
                size_t l = (size_t)(wy * 7 + iy) * 56 + wx * 7 + ix;
                bf16* dst = aw + ((size_t)b * LL + l) * CC + head * HD + lc;
                float inv = rinv[mi][r];
                dst[0]  = f2b(o[mi][0][r] * inv);
                dst[16] = f2b(o[mi][1][r] * inv);
            }
        }
    }
}

// ---------------- Depthwise 3x3 (SAME) + exact GELU, vectorized 8-ch/thread ----------
__global__ __launch_bounds__(256)
void dwconv_kernel(const bf16* __restrict__ xn, const float* __restrict__ w,
                   bf16* __restrict__ out)
{
    __shared__ float wl[9 * 288];
    const int t = threadIdx.x;
    for (int i = t; i < CC * 9; i += 256) {
        int c = i / 9, k = i - c * 9;
        wl[k * 288 + (c >> 3) * 12 + (c & 7)] = w[i];
    }
    __syncthreads();
    int e = blockIdx.x * 256 + t;          // 0 .. MM*24-1 (exact grid)
    int cg = e % 24;
    int pix = e / 24;
    int w_ = pix % WW;
    int t2 = pix / WW;
    int h_ = t2 % HH;
    int b  = t2 / HH;
    float acc[8] = {0.f,0.f,0.f,0.f,0.f,0.f,0.f,0.f};
    const bf16* rowbase = xn + ((size_t)b * HH * WW) * CC + (size_t)cg * 8;
    #pragma unroll
    for (int ky = 0; ky < 3; ++ky) {
        int hy = h_ + ky - 1;
        if (hy < 0 || hy >= HH) continue;
        #pragma unroll
        for (int kx = 0; kx < 3; ++kx) {
            int wx_ = w_ + kx - 1;
            if (wx_ < 0 || wx_ >= WW) continue;
            int k = ky * 3 + kx;
            const float4* wp = reinterpret_cast<const float4*>(&wl[k * 288 + cg * 12]);
            float4 w0 = wp[0];
            float4 w1 = wp[1];
            unsigned short u[8];
            *reinterpret_cast<uint4*>(u) = *reinterpret_cast<const uint4*>(
                rowbase + ((size_t)hy * WW + wx_) * CC);
            acc[0] += us2f(u[0]) * w0.x;
            acc[1] += us2f(u[1]) * w0.y;
            acc[2] += us2f(u[2]) * w0.z;
            acc[3] += us2f(u[3]) * w0.w;
            acc[4] += us2f(u[4]) * w1.x;
            acc[5] += us2f(u[5]) * w1.y;
            acc[6] += us2f(u[6]) * w1.z;
            acc[7] += us2f(u[7]) * w1.w;
        }
    }
    bf16 o8[8];
    #pragma unroll
    for (int j = 0; j < 8; ++j) o8[j] = f2b(gelu_exact(acc[j]));
    *reinterpret_cast<uint4*>(out + (size_t)e * 8) = *reinterpret_cast<uint4*>(o8);
}

// ---------------- column (spatial) sum of xn per (b, c) ----------------
__global__ __launch_bounds__(192)
void colsum_kernel(const bf16* __restrict__ xn, float* __restrict__ colsum)
{
    int b = blockIdx.y, g = blockIdx.x, c = threadIdx.x;
    float acc = 0.f;
    int l0 = g * 196;
    for (int l = l0; l < l0 + 196; ++l)
        acc += b2f(xn[((size_t)b * LL + l) * CC + c]);
    atomicAdd(&colsum[b * CC + c], acc);
}

__global__ __launch_bounds__(192)
void gate_kernel(const float* __restrict__ colsum, const float* __restrict__ gw,
                 const float* __restrict__ gb, float* __restrict__ gate)
{
    __shared__ float cm[CC];
    int b = blockIdx.x, o = threadIdx.x;
    cm[o] = colsum[b * CC + o] * (1.0f / LL);
    __syncthreads();
    float acc = gb[o];
    for (int c = 0; c < CC; ++c) acc += gw[o * CC + c] * cm[c];
    gate[b * CC + o] = 1.0f / (1.0f + expf(-acc));
}

// ---------------- means over H (-> [B][W][C]) and over W (-> [B][H][C]), vec8 --------
__global__ __launch_bounds__(256)
void mean_h_kernel(const bf16* __restrict__ xf, float* __restrict__ mh)
{
    int e = blockIdx.x * 256 + threadIdx.x;   // BB*WW*24
    if (e >= BB * WW * 24) return;
    int cg = e % 24, c0 = cg << 3;
    int w_ = (e / 24) % WW;
    int b  = e / (24 * WW);
    float s[8] = {0.f,0.f,0.f,0.f,0.f,0.f,0.f,0.f};
    const bf16* base = xf + ((size_t)b * HH * WW + w_) * CC + c0;
    for (int h_ = 0; h_ < HH; ++h_) {
        unsigned short u[8];
        *reinterpret_cast<uint4*>(u) = *reinterpret_cast<const uint4*>(base + (size_t)h_ * WW * CC);
        #pragma unroll
        for (int j = 0; j < 8; ++j) s[j] += us2f(u[j]);
    }
    float* dst = mh + ((size_t)b * WW + w_) * CC + c0;
    #pragma unroll
    for (int j = 0; j < 8; ++j) dst[j] = s[j] * (1.0f / HH);
}

__global__ __launch_bounds__(256)
void mean_w_kernel(const bf16* __restrict__ xf, float* __restrict__ mw)
{
    int e = blockIdx.x * 256 + threadIdx.x;   // BB*HH*24
    if (e >= BB * HH * 24) return;
    int cg = e % 24, c0 = cg << 3;
    int h_ = (e / 24) % HH;
    int b  = e / (24 * HH);
    float s[8] = {0.f,0.f,0.f,0.f,0.f,0.f,0.f,0.f};
    const bf16* base = xf + ((size_t)b * HH + h_) * WW * CC + c0;
    for (int w_ = 0; w_ < WW; ++w_) {
        unsigned short u[8];
        *reinterpret_cast<uint4*>(u) = *reinterpret_cast<const uint4*>(base + (size_t)w_ * CC);
        #pragma unroll
        for (int j = 0; j < 8; ++j) s[j] += us2f(u[j]);
    }
    float* dst = mw + ((size_t)b * HH + h_) * CC + c0;
    #pragma unroll
    for (int j = 0; j < 8; ++j) dst[j] = s[j] * (1.0f / WW);
}

// ---------------- logits over one spatial axis + softmax over the 56 positions ------------
// out layout TRANSPOSED: [B][56][CC] so downstream reads are channel-contiguous.
__global__ __launch_bounds__(64)
void axsoftmax_kernel(const float* __restrict__ mean, const float* __restrict__ w,
                      const float* __restrict__ bias, float* __restrict__ out)
{
    __shared__ float wrow[CC];
    int o = blockIdx.x, b = blockIdx.y, lane = threadIdx.x;
    for (int c = lane; c < CC; c += 64) wrow[c] = w[o * CC + c];
    __syncthreads();
    float logit = -1e30f;
    if (lane < 56) {
        const float* mr = mean + ((size_t)b * 56 + lane) * CC;
        float a = bias[o];
        for (int c = 0; c < CC; ++c) a += wrow[c] * mr[c];
        logit = a;
    }
    float m = logit;
    #pragma unroll
    for (int off = 32; off > 0; off >>= 1) m = fmaxf(m, __shfl_xor(m, off, 64));
    float e = (lane < 56) ? expf(logit - m) : 0.f;
    float s = e;
    #pragma unroll
    for (int off = 32; off > 0; off >>= 1) s += __shfl_xor(s, off, 64);
    if (lane < 56) out[((size_t)b * 56 + lane) * CC + o] = e / s;
}

// ---------------- xf2 = xf * a_s[b,h,c] * a_t[b,w,c] * 2  (vec8, coalesced) ----------
__global__ __launch_bounds__(256)
void modulate_kernel(const bf16* __restrict__ xf, const float* __restrict__ a_s,
                     const float* __restrict__ a_t, bf16* __restrict__ xf2)
{
    int e = blockIdx.x * 256 + threadIdx.x;    // 0 .. MM*24-1
    int cg = e % 24, c0 = cg << 3;
    int pix = e / 24;
    int w_ = pix % WW;
    int t2 = pix / WW;
    int h_ = t2 % HH;
    int b  = t2 / HH;
    unsigned short u[8];
    size_t base = (size_t)e * 8;
    *reinterpret_cast<uint4*>(u) = *reinterpret_cast<const uint4*>(xf + base);
    const float4* sp = reinterpret_cast<const float4*>(a_s + ((size_t)b * 56 + h_) * CC + c0);
    const float4* tp = reinterpret_cast<const float4*>(a_t + ((size_t)b * 56 + w_) * CC + c0);
    float4 s0 = sp[0], s1 = sp[1];
    float4 t0 = tp[0], t1 = tp[1];
    float ss[8] = {s0.x, s0.y, s0.z, s0.w, s1.x, s1.y, s1.z, s1.w};
    float tt[8] = {t0.x, t0.y, t0.z, t0.w, t1.x, t1.y, t1.z, t1.w};
    bf16 o8[8];
    #pragma unroll
    for (int j = 0; j < 8; ++j)
        o8[j] = f2b(us2f(u[j]) * ss[j] * tt[j] * 2.0f);
    *reinterpret_cast<uint4*>(xf2 + base) = *reinterpret_cast<uint4*>(o8);
}

// =======================================================================================
extern "C" void kernel_launch(void* const* d_in, const int* in_sizes, int n_in,
                              void* d_out, int out_size, void* d_ws, size_t ws_size,
                              hipStream_t stream)
{
    const float* x      = (const float*)d_in[0];
    const float* ln1_g  = (const float*)d_in[3];
    const float* ln1_b  = (const float*)d_in[4];
    const float* qkv_w  = (const float*)d_in[5];
    const float* qkv_b  = (const float*)d_in[6];
    const float* proj_w = (const float*)d_in[7];
    const float* proj_b = (const float*)d_in[8];
    const float* dw_w   = (const float*)d_in[9];
    const float* pw_w   = (const float*)d_in[10];
    const float* gate_w = (const float*)d_in[11];
    const float* gate_b = (const float*)d_in[12];
    const float* temp_w = (const float*)d_in[13];
    const float* temp_b = (const float*)d_in[14];
    const float* spec_w = (const float*)d_in[15];
    const float* spec_b = (const float*)d_in[16];
    const float* fuse_w = (const float*)d_in[17];
    const float* ln2_g  = (const float*)d_in[18];
    const float* ln2_b  = (const float*)d_in[19];
    const float* mlp1_w = (const float*)d_in[20];
    const float* mlp1_b = (const float*)d_in[21];
    const float* mlp2_w = (const float*)d_in[22];
    const float* mlp2_b = (const float*)d_in[23];
    float* out = (float*)d_out;

    const size_t SLOT = (size_t)MM * CC * sizeof(bf16);   // 38,535,168 B
    char* ws = (char*)d_ws;

    bf16* s_xn    = (bf16*)(ws);
    bf16* s_qkv   = (bf16*)(ws + SLOT);        // 3 slots
    bf16* s_aw    = (bf16*)(ws + 4 * SLOT);
    bf16* s_xattn = (bf16*)(ws + SLOT);        // reuse qkv slot 1
    bf16* s_dwg   = (bf16*)(ws + 2 * SLOT);
    bf16* s_xf    = (bf16*)(ws + 4 * SLOT);    // reuse aw (combine fused into pw gemm)
    bf16* s_xf2   = (bf16*)(ws + 3 * SLOT);
    bf16* s_x2    = (bf16*)(ws);               // reuse xn (xn dead after pw+combine)
    bf16* s_hn    = (bf16*)(ws + 2 * SLOT);
    bf16* s_h1    = (bf16*)(ws + 3 * SLOT);    // spans slots 3..4 (384 ch)

    float* colsum  = (float*)(ws + 5 * SLOT);
    float* gatebuf = colsum + BB * CC;
    float* mean_h  = gatebuf + BB * CC;
    float* mean_w  = mean_h + (size_t)BB * 56 * CC;
    float* a_t     = mean_w + (size_t)BB * 56 * CC;
    float* a_s     = a_t    + (size_t)BB * CC * 56;
    // bf16 weight copies
    bf16* wb_qkv  = (bf16*)(a_s + (size_t)BB * CC * 56);
    bf16* wb_proj = wb_qkv  + C3 * CC;
    bf16* wb_pw   = wb_proj + CC * CC;
    bf16* wb_fuse = wb_pw   + CC * CC;
    bf16* wb_mlp1 = wb_fuse + CC * CC;
    bf16* wb_mlp2 = wb_mlp1 + HIDN * CC;
    size_t total_need = (char*)(wb_mlp2 + CC * HIDN) - ws;
    if (ws_size < total_need) return;   // workspace insufficient — visible failure

    const int VEC_BLOCKS = MM * 24 / 256;   // 9408, exact

    // 0. weight conversions (f32 -> bf16)
    cvt_kernel<<<(C3 * CC + 255) / 256, 256, 0, stream>>>(qkv_w, wb_qkv, C3 * CC);
    cvt_kernel<<<(CC * CC + 255) / 256, 256, 0, stream>>>(proj_w, wb_proj, CC * CC);
    cvt_kernel<<<(CC * CC + 255) / 256, 256, 0, stream>>>(pw_w, wb_pw, CC * CC);
    cvt_kernel<<<(CC * CC + 255) / 256, 256, 0, stream>>>(fuse_w, wb_fuse, CC * CC);
    cvt_kernel<<<(HIDN * CC + 255) / 256, 256, 0, stream>>>(mlp1_w, wb_mlp1, HIDN * CC);
    cvt_kernel<<<(CC * HIDN + 255) / 256, 256, 0, stream>>>(mlp2_w, wb_mlp2, CC * HIDN);

    // 1. LN1
    ln_kernel<float><<<MM / 4, 256, 0, stream>>>(x, ln1_g, ln1_b, s_xn);
    // 2. qkv
    mfma_gemm<0, false, C3, CC, bf16, bf16><<<dim3(C3 / 64, MM / 128), 128, 0, stream>>>(
        s_xn, wb_qkv, qkv_b, (const bf16*)nullptr, s_qkv, nullptr, nullptr);
    // 3. window attention (MFMA, 1 wave per (window, head))
    winattn_kernel<<<dim3(NWIN, NHEAD), 64, 0, stream>>>(s_qkv, s_aw);
    // 4. proj
    mfma_gemm<0, false, CC, CC, bf16, bf16><<<dim3(CC / 64, MM / 128), 128, 0, stream>>>(
        s_aw, wb_proj, proj_b, (const bf16*)nullptr, s_xattn, nullptr, nullptr);
    // 5. depthwise + gelu (vec8)
    dwconv_kernel<<<VEC_BLOCKS, 256, 0, stream>>>(s_xn, dw_w, s_dwg);
    // 6. gate (needs only xn)
    hipMemsetAsync(colsum, 0, BB * CC * sizeof(float), stream);
    colsum_kernel<<<dim3(16, BB), 192, 0, stream>>>(s_xn, colsum);
    gate_kernel<<<BB, 192, 0, stream>>>(colsum, gate_w, gate_b, gatebuf);
    // 7. pointwise + fused combine: xf = dwg@pw^T + xattn + xn*gate
    mfma_gemm<2, false, CC, CC, bf16, bf16><<<dim3(CC / 64, MM / 128), 128, 0, stream>>>(
        s_dwg, wb_pw, (const float*)nullptr, s_xattn, s_xf, s_xn, gatebuf);
    // 8. axis means
    mean_h_kernel<<<(BB * WW * 24 + 255) / 256, 256, 0, stream>>>(s_xf, mean_h);
    mean_w_kernel<<<(BB * HH * 24 + 255) / 256, 256, 0, stream>>>(s_xf, mean_w);
    // 9. a_t (temporal, over W) and a_s (spectral, over H) — transposed [b][pos][c]
    axsoftmax_kernel<<<dim3(CC, BB), 64, 0, stream>>>(mean_h, temp_w, temp_b, a_t);
    axsoftmax_kernel<<<dim3(CC, BB), 64, 0, stream>>>(mean_w, spec_w, spec_b, a_s);
    // 10. modulate (coalesced)
    modulate_kernel<<<VEC_BLOCKS, 256, 0, stream>>>(s_xf, a_s, a_t, s_xf2);
    // 11. fuse (no bias) + residual from original x -> x2
    mfma_gemm<0, true, CC, CC, float, bf16><<<dim3(CC / 64, MM / 128), 128, 0, stream>>>(
        s_xf2, wb_fuse, (const float*)nullptr, x, s_x2, nullptr, nullptr);
    // 12. LN2
    ln_kernel<bf16><<<MM / 4, 256, 0, stream>>>(s_x2, ln2_g, ln2_b, s_hn);
    // 13. MLP1 + gelu
    mfma_gemm<1, false, HIDN, CC, bf16, bf16><<<dim3(HIDN / 64, MM / 128), 128, 0, stream>>>(
        s_hn, wb_mlp1, mlp1_b, (const bf16*)nullptr, s_h1, nullptr, nullptr);
    // 14. MLP2 + residual -> out (f32)
    mfma_gemm<0, true, CC, HIDN, bf16, float><<<dim3(CC / 64, MM / 128), 128, 0, stream>>>(
        s_h1, wb_mlp2, mlp2_b, s_x2, out, nullptr, nullptr);
}

// Round 7
// 490.220 us; speedup vs baseline: 3.4571x; 1.2090x over previous
//
#include <hip/hip_runtime.h>
#include <hip/hip_bf16.h>

typedef __hip_bfloat16 bf16;

// Problem constants (B=32, H=W=56, C=192, NH=6, WS=7)
#define BB 32
#define HH 56
#define WW 56
#define CC 192
#define LL 3136            // 56*56
#define MM (BB*LL)         // 100352 tokens
#define C3 576
#define HIDN 384
#define NHEAD 6
#define HD 32
#define NWIN 2048          // B * 8*8

typedef short short8 __attribute__((ext_vector_type(8)));
typedef float f32x4 __attribute__((ext_vector_type(4)));

__device__ __forceinline__ float us2f(unsigned short u) {
    union { unsigned int i; float f; } v; v.i = ((unsigned int)u) << 16; return v.f;
}
__device__ __forceinline__ float b2f(bf16 h) { return __bfloat162float(h); }
__device__ __forceinline__ bf16 f2b(float f) { return __float2bfloat16(f); }
__device__ __forceinline__ short f2bs(float f) { bf16 h = f2b(f); return *reinterpret_cast<short*>(&h); }
__device__ __forceinline__ float ldv(const bf16* p) { return b2f(*p); }
__device__ __forceinline__ float ldv(const float* p) { return *p; }
__device__ __forceinline__ void stv(bf16* p, float v) { *p = f2b(v); }
__device__ __forceinline__ void stv(float* p, float v) { *p = v; }
__device__ __forceinline__ float gelu_exact(float x) {
    return 0.5f * x * (1.0f + erff(x * 0.70710678118654752f));
}
__device__ __forceinline__ void async_lds16(const void* g, void* l) {
    __builtin_amdgcn_global_load_lds(
        (const __attribute__((address_space(1))) void*)g,
        (__attribute__((address_space(3))) void*)l, 16, 0, 0);
}

// ---------------- f32 -> bf16 weight conversion ----------------
__global__ __launch_bounds__(256)
void cvt_kernel(const float* __restrict__ src, bf16* __restrict__ dst, int n)
{
    int i = blockIdx.x * 256 + threadIdx.x;
    if (i < n) dst[i] = f2b(src[i]);
}

// ---------------- LayerNorm: one wave (64 lanes) per row of 192 ----------------
template<typename IT>
__global__ __launch_bounds__(256)
void ln_kernel(const IT* __restrict__ in, const float* __restrict__ g,
               const float* __restrict__ bvec, bf16* __restrict__ out)
{
    int wid = threadIdx.x >> 6, lane = threadIdx.x & 63;
    int row = blockIdx.x * 4 + wid;
    const IT* p = in + (size_t)row * CC;
    float x0 = ldv(p + lane);
    float x1 = ldv(p + lane + 64);
    float x2 = ldv(p + lane + 128);
    float s  = x0 + x1 + x2;
    float sq = x0*x0 + x1*x1 + x2*x2;
    #pragma unroll
    for (int o = 32; o > 0; o >>= 1) {
        s  += __shfl_xor(s,  o, 64);
        sq += __shfl_xor(sq, o, 64);
    }
    float mean = s * (1.0f / CC);
    float var  = sq * (1.0f / CC) - mean * mean;
    float inv  = rsqrtf(fmaxf(var, 0.0f) + 1e-5f);
    bf16* q = out + (size_t)row * CC;
    q[lane]       = f2b((x0 - mean) * inv * g[lane]       + bvec[lane]);
    q[lane + 64]  = f2b((x1 - mean) * inv * g[lane + 64]  + bvec[lane + 64]);
    q[lane + 128] = f2b((x2 - mean) * inv * g[lane + 128] + bvec[lane + 128]);
}

// ---------------- MFMA GEMM: out[M,NN] = epi(A[M,KK] @ W[NN,KK]^T + bias) ----
// EPI: 0=none, 1=gelu, 2=combine (out = acc + resid + b2f(xn2)*gate[b,c]).
// 256 threads = 4 waves, block tile 128x64, wave tile 32x64, BK=64.
// XCD-chunked block swizzle (bijective when nwg%8==0): consecutive work items
// (sharing an A-panel) land on the same XCD -> A fetched from HBM once.
template<int EPI, bool RESID, int NN, int KK, typename RT, typename OT>
__global__ __launch_bounds__(256)
void mfma_gemm(const bf16* __restrict__ A, const bf16* __restrict__ W,
               const float* __restrict__ bias, const RT* __restrict__ resid,
               OT* __restrict__ out,
               const bf16* __restrict__ xn2, const float* __restrict__ gate)
{
    __shared__ __align__(16) short As[128 * 64];
    __shared__ __align__(16) short Bs[64 * 64];
    const int t    = threadIdx.x;
    const int lane = t & 63;
    const int w    = t >> 6;        // wave 0..3
    const int nx   = gridDim.x;
    const int nwg  = gridDim.x * gridDim.y;
    int hw  = blockIdx.y * nx + blockIdx.x;
    int wid = (nwg & 7) ? hw : ((hw & 7) * (nwg >> 3) + (hw >> 3));
    const int m0   = (wid / nx) * 128;
    const int n0   = (wid % nx) * 64;
    const int lr   = lane & 15;     // row within 16
    const int lg   = lane >> 4;     // k-group 0..3

    f32x4 acc[2][4];
    #pragma unroll
    for (int i = 0; i < 2; ++i)
        #pragma unroll
        for (int j = 0; j < 4; ++j)
            acc[i][j] = (f32x4){0.f, 0.f, 0.f, 0.f};

    for (int k0 = 0; k0 < KK; k0 += 64) {
        const bf16* Ab = A + (size_t)m0 * KK + k0;
        const bf16* Wb = W + (size_t)n0 * KK + k0;
        // stage A: 128x64 bf16 = 1024 16B-chunks, 4 gload_lds per thread
        #pragma unroll
        for (int li = 0; li < 4; ++li) {
            int chunk = li * 256 + t;
            int r = chunk >> 3, c = chunk & 7;
            int cs = c ^ (r & 7);
            async_lds16(Ab + (size_t)r * KK + (cs << 3),
                        &As[(li * 256 + w * 64) << 3]);
        }
        // stage B: 64x64 bf16 = 512 chunks, 2 per thread
        #pragma unroll
        for (int li = 0; li < 2; ++li) {
            int chunk = li * 256 + t;
            int r = chunk >> 3, c = chunk & 7;
            int cs = c ^ (r & 7);
            async_lds16(Wb + (size_t)r * KK + (cs << 3),
                        &Bs[(li * 256 + w * 64) << 3]);
        }
        __syncthreads();
        #pragma unroll
        for (int kf = 0; kf < 2; ++kf) {
            short8 a_[2], b_[4];
            #pragma unroll
            for (int mi = 0; mi < 2; ++mi) {
                int row = (w << 5) + (mi << 4) + lr;
                a_[mi] = *reinterpret_cast<const short8*>(
                    &As[(row << 6) + ((((kf << 2) + lg) ^ (row & 7)) << 3)]);
            }
            #pragma unroll
            for (int ni = 0; ni < 4; ++ni) {
                int rn = (ni << 4) + lr;
                b_[ni] = *reinterpret_cast<const short8*>(
                    &Bs[(rn << 6) + ((((kf << 2) + lg) ^ (rn & 7)) << 3)]);
            }
            #pragma unroll
            for (int mi = 0; mi < 2; ++mi)
                #pragma unroll
                for (int ni = 0; ni < 4; ++ni)
                    acc[mi][ni] = __builtin_amdgcn_mfma_f32_16x16x32_bf16(
                        a_[mi], b_[ni], acc[mi][ni], 0, 0, 0);
        }
        __syncthreads();
    }

    #pragma unroll
    for (int mi = 0; mi < 2; ++mi) {
        #pragma unroll
        for (int ni = 0; ni < 4; ++ni) {
            int col = n0 + (ni << 4) + lr;
            float bv = bias ? bias[col] : 0.f;
            #pragma unroll
            for (int r = 0; r < 4; ++r) {
                int row = m0 + (w << 5) + (mi << 4) + (lg << 2) + r;
                float c = acc[mi][ni][r] + bv;
                if (EPI == 1) c = gelu_exact(c);
                if (EPI == 2) {
                    int bidx = row / LL;
                    c += ldv(resid + (size_t)row * NN + col)
                       + b2f(xn2[(size_t)row * NN + col]) * gate[bidx * CC + col];
                }
                if (RESID) c += ldv(resid + (size_t)row * NN + col);
                stv(out + (size_t)row * NN + col, c);
            }
        }
    }
}

// ---------------- MFMA window attention: one wave per (window, head) ----------------
__global__ __launch_bounds__(64)
void winattn_kernel(const bf16* __restrict__ qkv, bf16* __restrict__ aw)
{
    __shared__ __align__(16) short Qs[64 * 40];
    __shared__ __align__(16) short Ks[64 * 40];
    __shared__ __align__(16) short Ps[64 * 40];
    __shared__ __align__(16) short Vt[32 * 72];

    const int wi   = blockIdx.x;         // 0..2047
    const int head = blockIdx.y;         // 0..5
    const int b  = wi >> 6;
    const int wr = wi & 63;
    const int wy = wr >> 3, wx = wr & 7;
    const int t  = threadIdx.x;          // 0..63
    const int lc = t & 15;
    const int lg = t >> 4;
    const float scale = 0.1767766952966369f;   // 32^-0.5

    #pragma unroll
    for (int e = t; e < 256; e += 64) {
        int r = 48 + (e >> 4), c = (e & 15) << 1;
        *reinterpret_cast<int*>(&Ks[r * 40 + c]) = 0;
    }
    #pragma unroll
    for (int e = t; e < 512; e += 64) {
        int r = e >> 4, c = 48 + (e & 15);
        Vt[r * 72 + c] = 0;
    }

    for (int e = t; e < 196; e += 64) {
        int tok = e >> 2, part = e & 3;
        int iy = tok / 7, ix = tok - iy * 7;
        size_t l = (size_t)(wy * 7 + iy) * 56 + wx * 7 + ix;
        const bf16* base = qkv + ((size_t)b * LL + l) * C3 + head * HD + (part << 3);
        uint4 pq = *reinterpret_cast<const uint4*>(base);
        uint4 pk = *reinterpret_cast<const uint4*>(base + 192);
        uint4 pv = *reinterpret_cast<const uint4*>(base + 384);
        *reinterpret_cast<uint4*>(&Qs[tok * 40 + (part << 3)]) = pq;
        *reinterpret_cast<uint4*>(&Ks[tok * 40 + (part << 3)]) = pk;
        unsigned short uv[8];
        *reinterpret_cast<uint4*>(uv) = pv;
        #pragma unroll
        for (int jj = 0; jj < 8; ++jj)
            Vt[((part << 3) + jj) * 72 + tok] = (short)uv[jj];
    }
    __syncthreads();

    f32x4 acc[4][4];
    #pragma unroll
    for (int i = 0; i < 4; ++i)
        #pragma unroll
        for (int j = 0; j < 4; ++j)
            acc[i][j] = (f32x4){0.f, 0.f, 0.f, 0.f};
    {
        short8 a_[4], b_[4];
        #pragma unroll
        for (int mi = 0; mi < 4; ++mi)
            a_[mi] = *reinterpret_cast<const short8*>(&Qs[((mi << 4) + lc) * 40 + (lg << 3)]);
        #pragma unroll
        for (int ni = 0; ni < 4; ++ni)
            b_[ni] = *reinterpret_cast<const short8*>(&Ks[((ni << 4) + lc) * 40 + (lg << 3)]);
        #pragma unroll
        for (int mi = 0; mi < 4; ++mi)
            #pragma unroll
            for (int ni = 0; ni < 4; ++ni)
                acc[mi][ni] = __builtin_amdgcn_mfma_f32_16x16x32_bf16(
                    a_[mi], b_[ni], acc[mi][ni], 0, 0, 0);
    }

    float rinv[4][4];
    #pragma unroll
    for (int mi = 0; mi < 4; ++mi) {
        #pragma unroll
        for (int r = 0; r < 4; ++r) {
            float mx = -1e30f;
            #pragma unroll
            for (int ni = 0; ni < 4; ++ni) {
                float v = acc[mi][ni][r];
                if (ni == 3 && lc != 0) v = -1e30f;
                mx = fmaxf(mx, v);
            }
            mx = fmaxf(mx, __shfl_xor(mx, 1, 64));
            mx = fmaxf(mx, __shfl_xor(mx, 2, 64));
            mx = fmaxf(mx, __shfl_xor(mx, 4, 64));
            mx = fmaxf(mx, __shfl_xor(mx, 8, 64));
            float sm = 0.f;
            int row = (mi << 4) + (lg << 2) + r;
            #pragma unroll
            for (int ni = 0; ni < 4; ++ni) {
                float e = (ni == 3 && lc != 0) ? 0.f
                        : __expf(scale * (acc[mi][ni][r] - mx));
                Ps[row * 40 + (ni << 4) + lc] = f2bs(e);
                sm += e;
            }
            sm += __shfl_xor(sm, 1, 64);
            sm += __shfl_xor(sm, 2, 64);
            sm += __shfl_xor(sm, 4, 64);
            sm += __shfl_xor(sm, 8, 64);
            rinv[mi][r] = 1.0f / sm;
        }
    }
    __syncthreads();

    f32x4 o[4][2];
    #pragma unroll
    for (int i = 0; i < 4; ++i) {
        o[i][0] = (f32x4){0.f, 0.f, 0.f, 0.f};
        o[i][1] = (f32x4){0.f, 0.f, 0.f, 0.f};
    }
    #pragma unroll
    for (int kf = 0; kf < 2; ++kf) {
        short8 pa[4], vb[2];
        #pragma unroll
        for (int mi = 0; mi < 4; ++mi)
            pa[mi] = *reinterpret_cast<const short8*>(
                &Ps[((mi << 4) + lc) * 40 + (kf << 5) + (lg << 3)]);
        #pragma unroll
        for (int n2 = 0; n2 < 2; ++n2)
            vb[n2] = *reinterpret_cast<const short8*>(
                &Vt[((n2 << 4) + lc) * 72 + (kf << 5) + (lg << 3)]);
        #pragma unroll
        for (int mi = 0; mi < 4; ++mi)
            #pragma unroll
            for (int n2 = 0; n2 < 2; ++n2)
                o[mi][n2] = __builtin_amdgcn_mfma_f32_16x16x32_bf16(
                    pa[mi], vb[n2], o[mi][n2], 0, 0, 0);
    }

    #pragma unroll
    for (int mi = 0; mi < 4; ++mi) {
        #pragma unroll
        for (int r = 0; r < 4; ++r) {
            int row = (mi << 4) + (lg << 2) + r;
            if (row < 49) {
                int iy = row / 7, ix = row - iy * 7;
                size_t l = (size_t)(wy * 7 + iy) * 56 + wx * 7 + ix;
                bf16* dst = aw + ((size_t)b * LL + l) * CC + head * HD + lc;
                float inv = rinv[mi][r];
                dst[0]  = f2b(o[mi][0][r] * inv);
                dst[16] = f2b(o[mi][1][r] * inv);
            }
        }
    }
}

// ---------------- Depthwise 3x3 (SAME) + exact GELU, vectorized 8-ch/thread ----------
__global__ __launch_bounds__(256)
void dwconv_kernel(const bf16* __restrict__ xn, const float* __restrict__ w,
                   bf16* __restrict__ out)
{
    __shared__ float wl[9 * 288];
    const int t = threadIdx.x;
    for (int i = t; i < CC * 9; i += 256) {
        int c = i / 9, k = i - c * 9;
        wl[k * 288 + (c >> 3) * 12 + (c & 7)] = w[i];
    }
    __syncthreads();
    int e = blockIdx.x * 256 + t;          // 0 .. MM*24-1 (exact grid)
    int cg = e % 24;
    int pix = e / 24;
    int w_ = pix % WW;
    int t2 = pix / WW;
    int h_ = t2 % HH;
    int b  = t2 / HH;
    float acc[8] = {0.f,0.f,0.f,0.f,0.f,0.f,0.f,0.f};
    const bf16* rowbase = xn + ((size_t)b * HH * WW) * CC + (size_t)cg * 8;
    #pragma unroll
    for (int ky = 0; ky < 3; ++ky) {
        int hy = h_ + ky - 1;
        if (hy < 0 || hy >= HH) continue;
        #pragma unroll
        for (int kx = 0; kx < 3; ++kx) {
            int wx_ = w_ + kx - 1;
            if (wx_ < 0 || wx_ >= WW) continue;
            int k = ky * 3 + kx;
            const float4* wp = reinterpret_cast<const float4*>(&wl[k * 288 + cg * 12]);
            float4 w0 = wp[0];
            float4 w1 = wp[1];
            unsigned short u[8];
            *reinterpret_cast<uint4*>(u) = *reinterpret_cast<const uint4*>(
                rowbase + ((size_t)hy * WW + wx_) * CC);
            acc[0] += us2f(u[0]) * w0.x;
            acc[1] += us2f(u[1]) * w0.y;
            acc[2] += us2f(u[2]) * w0.z;
            acc[3] += us2f(u[3]) * w0.w;
            acc[4] += us2f(u[4]) * w1.x;
            acc[5] += us2f(u[5]) * w1.y;
            acc[6] += us2f(u[6]) * w1.z;
            acc[7] += us2f(u[7]) * w1.w;
        }
    }
    bf16 o8[8];
    #pragma unroll
    for (int j = 0; j < 8; ++j) o8[j] = f2b(gelu_exact(acc[j]));
    *reinterpret_cast<uint4*>(out + (size_t)e * 8) = *reinterpret_cast<uint4*>(o8);
}

// ---------------- column (spatial) sum of xn per (b, c) ----------------
__global__ __launch_bounds__(192)
void colsum_kernel(const bf16* __restrict__ xn, float* __restrict__ colsum)
{
    int b = blockIdx.y, g = blockIdx.x, c = threadIdx.x;
    float acc = 0.f;
    int l0 = g * 196;
    for (int l = l0; l < l0 + 196; ++l)
        acc += b2f(xn[((size_t)b * LL + l) * CC + c]);
    atomicAdd(&colsum[b * CC + c], acc);
}

__global__ __launch_bounds__(192)
void gate_kernel(const float* __restrict__ colsum, const float* __restrict__ gw,
                 const float* __restrict__ gb, float* __restrict__ gate)
{
    __shared__ float cm[CC];
    int b = blockIdx.x, o = threadIdx.x;
    cm[o] = colsum[b * CC + o] * (1.0f / LL);
    __syncthreads();
    float acc = gb[o];
    for (int c = 0; c < CC; ++c) acc += gw[o * CC + c] * cm[c];
    gate[b * CC + o] = 1.0f / (1.0f + expf(-acc));
}

// ---------------- means over H (-> [B][W][C]) and over W (-> [B][H][C]), vec8 --------
__global__ __launch_bounds__(256)
void mean_h_kernel(const bf16* __restrict__ xf, float* __restrict__ mh)
{
    int e = blockIdx.x * 256 + threadIdx.x;   // BB*WW*24
    if (e >= BB * WW * 24) return;
    int cg = e % 24, c0 = cg << 3;
    int w_ = (e / 24) % WW;
    int b  = e / (24 * WW);
    float s[8] = {0.f,0.f,0.f,0.f,0.f,0.f,0.f,0.f};
    const bf16* base = xf + ((size_t)b * HH * WW + w_) * CC + c0;
    for (int h_ = 0; h_ < HH; ++h_) {
        unsigned short u[8];
        *reinterpret_cast<uint4*>(u) = *reinterpret_cast<const uint4*>(base + (size_t)h_ * WW * CC);
        #pragma unroll
        for (int j = 0; j < 8; ++j) s[j] += us2f(u[j]);
    }
    float* dst = mh + ((size_t)b * WW + w_) * CC + c0;
    #pragma unroll
    for (int j = 0; j < 8; ++j) dst[j] = s[j] * (1.0f / HH);
}

__global__ __launch_bounds__(256)
void mean_w_kernel(const bf16* __restrict__ xf, float* __restrict__ mw)
{
    int e = blockIdx.x * 256 + threadIdx.x;   // BB*HH*24
    if (e >= BB * HH * 24) return;
    int cg = e % 24, c0 = cg << 3;
    int h_ = (e / 24) % HH;
    int b  = e / (24 * HH);
    float s[8] = {0.f,0.f,0.f,0.f,0.f,0.f,0.f,0.f};
    const bf16* base = xf + ((size_t)b * HH + h_) * WW * CC + c0;
    for (int w_ = 0; w_ < WW; ++w_) {
        unsigned short u[8];
        *reinterpret_cast<uint4*>(u) = *reinterpret_cast<const uint4*>(base + (size_t)w_ * CC);
        #pragma unroll
        for (int j = 0; j < 8; ++j) s[j] += us2f(u[j]);
    }
    float* dst = mw + ((size_t)b * HH + h_) * CC + c0;
    #pragma unroll
    for (int j = 0; j < 8; ++j) dst[j] = s[j] * (1.0f / WW);
}

// ---------------- logits over one spatial axis + softmax over the 56 positions ------------
// out layout TRANSPOSED: [B][56][CC] so downstream reads are channel-contiguous.
__global__ __launch_bounds__(64)
void axsoftmax_kernel(const float* __restrict__ mean, const float* __restrict__ w,
                      const float* __restrict__ bias, float* __restrict__ out)
{
    __shared__ float wrow[CC];
    int o = blockIdx.x, b = blockIdx.y, lane = threadIdx.x;
    for (int c = lane; c < CC; c += 64) wrow[c] = w[o * CC + c];
    __syncthreads();
    float logit = -1e30f;
    if (lane < 56) {
        const float* mr = mean + ((size_t)b * 56 + lane) * CC;
        float a = bias[o];
        for (int c = 0; c < CC; ++c) a += wrow[c] * mr[c];
        logit = a;
    }
    float m = logit;
    #pragma unroll
    for (int off = 32; off > 0; off >>= 1) m = fmaxf(m, __shfl_xor(m, off, 64));
    float e = (lane < 56) ? expf(logit - m) : 0.f;
    float s = e;
    #pragma unroll
    for (int off = 32; off > 0; off >>= 1) s += __shfl_xor(s, off, 64);
    if (lane < 56) out[((size_t)b * 56 + lane) * CC + o] = e / s;
}

// ---------------- xf2 = xf * a_s[b,h,c] * a_t[b,w,c] * 2  (vec8, coalesced) ----------
__global__ __launch_bounds__(256)
void modulate_kernel(const bf16* __restrict__ xf, const float* __restrict__ a_s,
                     const float* __restrict__ a_t, bf16* __restrict__ xf2)
{
    int e = blockIdx.x * 256 + threadIdx.x;    // 0 .. MM*24-1
    int cg = e % 24, c0 = cg << 3;
    int pix = e / 24;
    int w_ = pix % WW;
    int t2 = pix / WW;
    int h_ = t2 % HH;
    int b  = t2 / HH;
    unsigned short u[8];
    size_t base = (size_t)e * 8;
    *reinterpret_cast<uint4*>(u) = *reinterpret_cast<const uint4*>(xf + base);
    const float4* sp = reinterpret_cast<const float4*>(a_s + ((size_t)b * 56 + h_) * CC + c0);
    const float4* tp = reinterpret_cast<const float4*>(a_t + ((size_t)b * 56 + w_) * CC + c0);
    float4 s0 = sp[0], s1 = sp[1];
    float4 t0 = tp[0], t1 = tp[1];
    float ss[8] = {s0.x, s0.y, s0.z, s0.w, s1.x, s1.y, s1.z, s1.w};
    float tt[8] = {t0.x, t0.y, t0.z, t0.w, t1.x, t1.y, t1.z, t1.w};
    bf16 o8[8];
    #pragma unroll
    for (int j = 0; j < 8; ++j)
        o8[j] = f2b(us2f(u[j]) * ss[j] * tt[j] * 2.0f);
    *reinterpret_cast<uint4*>(xf2 + base) = *reinterpret_cast<uint4*>(o8);
}

// =======================================================================================
extern "C" void kernel_launch(void* const* d_in, const int* in_sizes, int n_in,
                              void* d_out, int out_size, void* d_ws, size_t ws_size,
                              hipStream_t stream)
{
    const float* x      = (const float*)d_in[0];
    const float* ln1_g  = (const float*)d_in[3];
    const float* ln1_b  = (const float*)d_in[4];
    const float* qkv_w  = (const float*)d_in[5];
    const float* qkv_b  = (const float*)d_in[6];
    const float* proj_w = (const float*)d_in[7];
    const float* proj_b = (const float*)d_in[8];
    const float* dw_w   = (const float*)d_in[9];
    const float* pw_w   = (const float*)d_in[10];
    const float* gate_w = (const float*)d_in[11];
    const float* gate_b = (const float*)d_in[12];
    const float* temp_w = (const float*)d_in[13];
    const float* temp_b = (const float*)d_in[14];
    const float* spec_w = (const float*)d_in[15];
    const float* spec_b = (const float*)d_in[16];
    const float* fuse_w = (const float*)d_in[17];
    const float* ln2_g  = (const float*)d_in[18];
    const float* ln2_b  = (const float*)d_in[19];
    const float* mlp1_w = (const float*)d_in[20];
    const float* mlp1_b = (const float*)d_in[21];
    const float* mlp2_w = (const float*)d_in[22];
    const float* mlp2_b = (const float*)d_in[23];
    float* out = (float*)d_out;

    const size_t SLOT = (size_t)MM * CC * sizeof(bf16);   // 38,535,168 B
    char* ws = (char*)d_ws;

    bf16* s_xn    = (bf16*)(ws);
    bf16* s_qkv   = (bf16*)(ws + SLOT);        // 3 slots
    bf16* s_aw    = (bf16*)(ws + 4 * SLOT);
    bf16* s_xattn = (bf16*)(ws + SLOT);        // reuse qkv slot 1
    bf16* s_dwg   = (bf16*)(ws + 2 * SLOT);
    bf16* s_xf    = (bf16*)(ws + 4 * SLOT);    // reuse aw (combine fused into pw gemm)
    bf16* s_xf2   = (bf16*)(ws + 3 * SLOT);
    bf16* s_x2    = (bf16*)(ws);               // reuse xn (xn dead after pw+combine)
    bf16* s_hn    = (bf16*)(ws + 2 * SLOT);
    bf16* s_h1    = (bf16*)(ws + 3 * SLOT);    // spans slots 3..4 (384 ch)

    float* colsum  = (float*)(ws + 5 * SLOT);
    float* gatebuf = colsum + BB * CC;
    float* mean_h  = gatebuf + BB * CC;
    float* mean_w  = mean_h + (size_t)BB * 56 * CC;
    float* a_t     = mean_w + (size_t)BB * 56 * CC;
    float* a_s     = a_t    + (size_t)BB * CC * 56;
    // bf16 weight copies
    bf16* wb_qkv  = (bf16*)(a_s + (size_t)BB * CC * 56);
    bf16* wb_proj = wb_qkv  + C3 * CC;
    bf16* wb_pw   = wb_proj + CC * CC;
    bf16* wb_fuse = wb_pw   + CC * CC;
    bf16* wb_mlp1 = wb_fuse + CC * CC;
    bf16* wb_mlp2 = wb_mlp1 + HIDN * CC;
    size_t total_need = (char*)(wb_mlp2 + CC * HIDN) - ws;
    if (ws_size < total_need) return;   // workspace insufficient — visible failure

    const int VEC_BLOCKS = MM * 24 / 256;   // 9408, exact

    // 0. weight conversions (f32 -> bf16)
    cvt_kernel<<<(C3 * CC + 255) / 256, 256, 0, stream>>>(qkv_w, wb_qkv, C3 * CC);
    cvt_kernel<<<(CC * CC + 255) / 256, 256, 0, stream>>>(proj_w, wb_proj, CC * CC);
    cvt_kernel<<<(CC * CC + 255) / 256, 256, 0, stream>>>(pw_w, wb_pw, CC * CC);
    cvt_kernel<<<(CC * CC + 255) / 256, 256, 0, stream>>>(fuse_w, wb_fuse, CC * CC);
    cvt_kernel<<<(HIDN * CC + 255) / 256, 256, 0, stream>>>(mlp1_w, wb_mlp1, HIDN * CC);
    cvt_kernel<<<(CC * HIDN + 255) / 256, 256, 0, stream>>>(mlp2_w, wb_mlp2, CC * HIDN);

    // 1. LN1
    ln_kernel<float><<<MM / 4, 256, 0, stream>>>(x, ln1_g, ln1_b, s_xn);
    // 2. qkv
    mfma_gemm<0, false, C3, CC, bf16, bf16><<<dim3(C3 / 64, MM / 128), 256, 0, stream>>>(
        s_xn, wb_qkv, qkv_b, (const bf16*)nullptr, s_qkv, nullptr, nullptr);
    // 3. window attention (MFMA, 1 wave per (window, head))
    winattn_kernel<<<dim3(NWIN, NHEAD), 64, 0, stream>>>(s_qkv, s_aw);
    // 4. proj
    mfma_gemm<0, false, CC, CC, bf16, bf16><<<dim3(CC / 64, MM / 128), 256, 0, stream>>>(
        s_aw, wb_proj, proj_b, (const bf16*)nullptr, s_xattn, nullptr, nullptr);
    // 5. depthwise + gelu (vec8)
    dwconv_kernel<<<VEC_BLOCKS, 256, 0, stream>>>(s_xn, dw_w, s_dwg);
    // 6. gate (needs only xn)
    hipMemsetAsync(colsum, 0, BB * CC * sizeof(float), stream);
    colsum_kernel<<<dim3(16, BB), 192, 0, stream>>>(s_xn, colsum);
    gate_kernel<<<BB, 192, 0, stream>>>(colsum, gate_w, gate_b, gatebuf);
    // 7. pointwise + fused combine: xf = dwg@pw^T + xattn + xn*gate
    mfma_gemm<2, false, CC, CC, bf16, bf16><<<dim3(CC / 64, MM / 128), 256, 0, stream>>>(
        s_dwg, wb_pw, (const float*)nullptr, s_xattn, s_xf, s_xn, gatebuf);
    // 8. axis means
    mean_h_kernel<<<(BB * WW * 24 + 255) / 256, 256, 0, stream>>>(s_xf, mean_h);
    mean_w_kernel<<<(BB * HH * 24 + 255) / 256, 256, 0, stream>>>(s_xf, mean_w);
    // 9. a_t (temporal, over W) and a_s (spectral, over H) — transposed [b][pos][c]
    axsoftmax_kernel<<<dim3(CC, BB), 64, 0, stream>>>(mean_h, temp_w, temp_b, a_t);
    axsoftmax_kernel<<<dim3(CC, BB), 64, 0, stream>>>(mean_w, spec_w, spec_b, a_s);
    // 10. modulate (coalesced)
    modulate_kernel<<<VEC_BLOCKS, 256, 0, stream>>>(s_xf, a_s, a_t, s_xf2);
    // 11. fuse (no bias) + residual from original x -> x2
    mfma_gemm<0, true, CC, CC, float, bf16><<<dim3(CC / 64, MM / 128), 256, 0, stream>>>(
        s_xf2, wb_fuse, (const float*)nullptr, x, s_x2, nullptr, nullptr);
    // 12. LN2
    ln_kernel<bf16><<<MM / 4, 256, 0, stream>>>(s_x2, ln2_g, ln2_b, s_hn);
    // 13. MLP1 + gelu
    mfma_gemm<1, false, HIDN, CC, bf16, bf16><<<dim3(HIDN / 64, MM / 128), 256, 0, stream>>>(
        s_hn, wb_mlp1, mlp1_b, (const bf16*)nullptr, s_h1, nullptr, nullptr);
    // 14. MLP2 + residual -> out (f32)
    mfma_gemm<0, true, CC, HIDN, bf16, float><<<dim3(CC / 64, MM / 128), 256, 0, stream>>>(
        s_h1, wb_mlp2, mlp2_b, s_x2, out, nullptr, nullptr);
}

// Round 8
// 475.085 us; speedup vs baseline: 3.5672x; 1.0319x over previous
//
#include <hip/hip_runtime.h>
#include <hip/hip_bf16.h>

typedef __hip_bfloat16 bf16;

// Problem constants (B=32, H=W=56, C=192, NH=6, WS=7)
#define BB 32
#define HH 56
#define WW 56
#define CC 192
#define LL 3136            // 56*56
#define MM (BB*LL)         // 100352 tokens
#define C3 576
#define HIDN 384
#define NHEAD 6
#define HD 32
#define NWIN 2048          // B * 8*8

typedef short short8 __attribute__((ext_vector_type(8)));
typedef float f32x4 __attribute__((ext_vector_type(4)));

__device__ __forceinline__ float us2f(unsigned short u) {
    union { unsigned int i; float f; } v; v.i = ((unsigned int)u) << 16; return v.f;
}
__device__ __forceinline__ float b2f(bf16 h) { return __bfloat162float(h); }
__device__ __forceinline__ bf16 f2b(float f) { return __float2bfloat16(f); }
__device__ __forceinline__ short f2bs(float f) { bf16 h = f2b(f); return *reinterpret_cast<short*>(&h); }
__device__ __forceinline__ float ldv(const bf16* p) { return b2f(*p); }
__device__ __forceinline__ float ldv(const float* p) { return *p; }
__device__ __forceinline__ void stv(bf16* p, float v) { *p = f2b(v); }
__device__ __forceinline__ void stv(float* p, float v) { *p = v; }
__device__ __forceinline__ float gelu_exact(float x) {
    return 0.5f * x * (1.0f + erff(x * 0.70710678118654752f));
}
__device__ __forceinline__ void async_lds16(const void* g, void* l) {
    __builtin_amdgcn_global_load_lds(
        (const __attribute__((address_space(1))) void*)g,
        (__attribute__((address_space(3))) void*)l, 16, 0, 0);
}

// ---------------- f32 -> bf16 weight conversion ----------------
__global__ __launch_bounds__(256)
void cvt_kernel(const float* __restrict__ src, bf16* __restrict__ dst, int n)
{
    int i = blockIdx.x * 256 + threadIdx.x;
    if (i < n) dst[i] = f2b(src[i]);
}

// ---------------- LayerNorm: one wave (64 lanes) per row of 192 ----------------
template<typename IT>
__global__ __launch_bounds__(256)
void ln_kernel(const IT* __restrict__ in, const float* __restrict__ g,
               const float* __restrict__ bvec, bf16* __restrict__ out)
{
    int wid = threadIdx.x >> 6, lane = threadIdx.x & 63;
    int row = blockIdx.x * 4 + wid;
    const IT* p = in + (size_t)row * CC;
    float x0 = ldv(p + lane);
    float x1 = ldv(p + lane + 64);
    float x2 = ldv(p + lane + 128);
    float s  = x0 + x1 + x2;
    float sq = x0*x0 + x1*x1 + x2*x2;
    #pragma unroll
    for (int o = 32; o > 0; o >>= 1) {
        s  += __shfl_xor(s,  o, 64);
        sq += __shfl_xor(sq, o, 64);
    }
    float mean = s * (1.0f / CC);
    float var  = sq * (1.0f / CC) - mean * mean;
    float inv  = rsqrtf(fmaxf(var, 0.0f) + 1e-5f);
    bf16* q = out + (size_t)row * CC;
    q[lane]       = f2b((x0 - mean) * inv * g[lane]       + bvec[lane]);
    q[lane + 64]  = f2b((x1 - mean) * inv * g[lane + 64]  + bvec[lane + 64]);
    q[lane + 128] = f2b((x2 - mean) * inv * g[lane + 128] + bvec[lane + 128]);
}

// ---------------- MFMA GEMM: out[M,NN] = epi(A[M,KK] @ W[NN,KK]^T + bias) ----
// EPI: 0=none, 1=gelu, 2=combine (out = acc + resid + b2f(xn2)*gate[b,c]).
// 256 threads = 4 waves, block tile 128x64, wave tile 32x64, BK=64.
// XCD-chunked block swizzle (bijective when nwg%8==0).
template<int EPI, bool RESID, int NN, int KK, typename RT, typename OT>
__global__ __launch_bounds__(256)
void mfma_gemm(const bf16* __restrict__ A, const bf16* __restrict__ W,
               const float* __restrict__ bias, const RT* __restrict__ resid,
               OT* __restrict__ out,
               const bf16* __restrict__ xn2, const float* __restrict__ gate)
{
    __shared__ __align__(16) short As[128 * 64];
    __shared__ __align__(16) short Bs[64 * 64];
    const int t    = threadIdx.x;
    const int lane = t & 63;
    const int w    = t >> 6;        // wave 0..3
    const int nx   = gridDim.x;
    const int nwg  = gridDim.x * gridDim.y;
    int hw  = blockIdx.y * nx + blockIdx.x;
    int wid = (nwg & 7) ? hw : ((hw & 7) * (nwg >> 3) + (hw >> 3));
    const int m0   = (wid / nx) * 128;
    const int n0   = (wid % nx) * 64;
    const int lr   = lane & 15;     // row within 16
    const int lg   = lane >> 4;     // k-group 0..3

    f32x4 acc[2][4];
    #pragma unroll
    for (int i = 0; i < 2; ++i)
        #pragma unroll
        for (int j = 0; j < 4; ++j)
            acc[i][j] = (f32x4){0.f, 0.f, 0.f, 0.f};

    for (int k0 = 0; k0 < KK; k0 += 64) {
        const bf16* Ab = A + (size_t)m0 * KK + k0;
        const bf16* Wb = W + (size_t)n0 * KK + k0;
        #pragma unroll
        for (int li = 0; li < 4; ++li) {
            int chunk = li * 256 + t;
            int r = chunk >> 3, c = chunk & 7;
            int cs = c ^ (r & 7);
            async_lds16(Ab + (size_t)r * KK + (cs << 3),
                        &As[(li * 256 + w * 64) << 3]);
        }
        #pragma unroll
        for (int li = 0; li < 2; ++li) {
            int chunk = li * 256 + t;
            int r = chunk >> 3, c = chunk & 7;
            int cs = c ^ (r & 7);
            async_lds16(Wb + (size_t)r * KK + (cs << 3),
                        &Bs[(li * 256 + w * 64) << 3]);
        }
        __syncthreads();
        #pragma unroll
        for (int kf = 0; kf < 2; ++kf) {
            short8 a_[2], b_[4];
            #pragma unroll
            for (int mi = 0; mi < 2; ++mi) {
                int row = (w << 5) + (mi << 4) + lr;
                a_[mi] = *reinterpret_cast<const short8*>(
                    &As[(row << 6) + ((((kf << 2) + lg) ^ (row & 7)) << 3)]);
            }
            #pragma unroll
            for (int ni = 0; ni < 4; ++ni) {
                int rn = (ni << 4) + lr;
                b_[ni] = *reinterpret_cast<const short8*>(
                    &Bs[(rn << 6) + ((((kf << 2) + lg) ^ (rn & 7)) << 3)]);
            }
            #pragma unroll
            for (int mi = 0; mi < 2; ++mi)
                #pragma unroll
                for (int ni = 0; ni < 4; ++ni)
                    acc[mi][ni] = __builtin_amdgcn_mfma_f32_16x16x32_bf16(
                        a_[mi], b_[ni], acc[mi][ni], 0, 0, 0);
        }
        __syncthreads();
    }

    #pragma unroll
    for (int mi = 0; mi < 2; ++mi) {
        #pragma unroll
        for (int ni = 0; ni < 4; ++ni) {
            int col = n0 + (ni << 4) + lr;
            float bv = bias ? bias[col] : 0.f;
            #pragma unroll
            for (int r = 0; r < 4; ++r) {
                int row = m0 + (w << 5) + (mi << 4) + (lg << 2) + r;
                float c = acc[mi][ni][r] + bv;
                if (EPI == 1) c = gelu_exact(c);
                if (EPI == 2) {
                    int bidx = row / LL;
                    c += ldv(resid + (size_t)row * NN + col)
                       + b2f(xn2[(size_t)row * NN + col]) * gate[bidx * CC + col];
                }
                if (RESID) c += ldv(resid + (size_t)row * NN + col);
                stv(out + (size_t)row * NN + col, c);
            }
        }
    }
}

// ---------------- MFMA window attention v2: one wave per (window, head) -------------
// Q,K fragments loaded DIRECTLY global->registers (predicated, token<49).
// LDS only for P (64x40) and V^T (32x72) -> 9.7 KB -> 16 blocks/CU.
// Single wave: no __syncthreads needed. Output staged through Ps for 16B stores.
__global__ __launch_bounds__(64)
void winattn_kernel(const bf16* __restrict__ qkv, bf16* __restrict__ aw)
{
    __shared__ __align__(16) short Ps[64 * 40];
    __shared__ __align__(16) short Vt[32 * 72];

    const int wi   = blockIdx.x;         // 0..2047
    const int head = blockIdx.y;         // 0..5
    const int b  = wi >> 6;
    const int wr = wi & 63;
    const int wy = wr >> 3, wx = wr & 7;
    const int t  = threadIdx.x;          // 0..63
    const int lc = t & 15;
    const int lg = t >> 4;
    const float scale = 0.1767766952966369f;   // 32^-0.5
    const bf16* qbase = qkv + (size_t)b * LL * C3 + head * HD;

    // zero pad Vt cols 48..63
    #pragma unroll
    for (int e = t; e < 512; e += 64) {
        int r = e >> 4, c = 48 + (e & 15);
        Vt[r * 72 + c] = 0;
    }
    // stage V transposed
    for (int e = t; e < 196; e += 64) {
        int tok = e >> 2, part = e & 3;
        int iy = tok / 7, ix = tok - iy * 7;
        size_t l = (size_t)(wy * 7 + iy) * 56 + wx * 7 + ix;
        uint4 pv = *reinterpret_cast<const uint4*>(qbase + l * C3 + 384 + (part << 3));
        unsigned short uv[8];
        *reinterpret_cast<uint4*>(uv) = pv;
        #pragma unroll
        for (int jj = 0; jj < 8; ++jj)
            Vt[((part << 3) + jj) * 72 + tok] = (short)uv[jj];
    }

    // Q, K fragments direct from global (predicated)
    const short8 zero8 = {0, 0, 0, 0, 0, 0, 0, 0};
    short8 a_[4], b_[4];
    #pragma unroll
    for (int mi = 0; mi < 4; ++mi) {
        int tk = (mi << 4) + lc;
        a_[mi] = zero8;
        if (tk < 49) {
            int iy = tk / 7, ix = tk - iy * 7;
            size_t l = (size_t)(wy * 7 + iy) * 56 + wx * 7 + ix;
            a_[mi] = *reinterpret_cast<const short8*>(qbase + l * C3 + (lg << 3));
        }
    }
    #pragma unroll
    for (int ni = 0; ni < 4; ++ni) {
        int rn = (ni << 4) + lc;
        b_[ni] = zero8;
        if (rn < 49) {
            int iy = rn / 7, ix = rn - iy * 7;
            size_t l = (size_t)(wy * 7 + iy) * 56 + wx * 7 + ix;
            b_[ni] = *reinterpret_cast<const short8*>(qbase + l * C3 + 192 + (lg << 3));
        }
    }

    // S = Q K^T
    f32x4 acc[4][4];
    #pragma unroll
    for (int i = 0; i < 4; ++i)
        #pragma unroll
        for (int j = 0; j < 4; ++j)
            acc[i][j] = (f32x4){0.f, 0.f, 0.f, 0.f};
    #pragma unroll
    for (int mi = 0; mi < 4; ++mi)
        #pragma unroll
        for (int ni = 0; ni < 4; ++ni)
            acc[mi][ni] = __builtin_amdgcn_mfma_f32_16x16x32_bf16(
                a_[mi], b_[ni], acc[mi][ni], 0, 0, 0);

    // softmax over cols; C layout: row = mi*16 + lg*4 + r, col = ni*16 + lc.
    float rinv[4][4];
    #pragma unroll
    for (int mi = 0; mi < 4; ++mi) {
        #pragma unroll
        for (int r = 0; r < 4; ++r) {
            float mx = -1e30f;
            #pragma unroll
            for (int ni = 0; ni < 4; ++ni) {
                float v = acc[mi][ni][r];
                if (ni == 3 && lc != 0) v = -1e30f;
                mx = fmaxf(mx, v);
            }
            mx = fmaxf(mx, __shfl_xor(mx, 1, 64));
            mx = fmaxf(mx, __shfl_xor(mx, 2, 64));
            mx = fmaxf(mx, __shfl_xor(mx, 4, 64));
            mx = fmaxf(mx, __shfl_xor(mx, 8, 64));
            float sm = 0.f;
            int row = (mi << 4) + (lg << 2) + r;
            #pragma unroll
            for (int ni = 0; ni < 4; ++ni) {
                float e = (ni == 3 && lc != 0) ? 0.f
                        : __expf(scale * (acc[mi][ni][r] - mx));
                Ps[row * 40 + (ni << 4) + lc] = f2bs(e);
                sm += e;
            }
            sm += __shfl_xor(sm, 1, 64);
            sm += __shfl_xor(sm, 2, 64);
            sm += __shfl_xor(sm, 4, 64);
            sm += __shfl_xor(sm, 8, 64);
            rinv[mi][r] = 1.0f / sm;
        }
    }

    // O = P V
    f32x4 o[4][2];
    #pragma unroll
    for (int i = 0; i < 4; ++i) {
        o[i][0] = (f32x4){0.f, 0.f, 0.f, 0.f};
        o[i][1] = (f32x4){0.f, 0.f, 0.f, 0.f};
    }
    #pragma unroll
    for (int kf = 0; kf < 2; ++kf) {
        short8 pa[4], vb[2];
        #pragma unroll
        for (int mi = 0; mi < 4; ++mi)
            pa[mi] = *reinterpret_cast<const short8*>(
                &Ps[((mi << 4) + lc) * 40 + (kf << 5) + (lg << 3)]);
        #pragma unroll
        for (int n2 = 0; n2 < 2; ++n2)
            vb[n2] = *reinterpret_cast<const short8*>(
                &Vt[((n2 << 4) + lc) * 72 + (kf << 5) + (lg << 3)]);
        #pragma unroll
        for (int mi = 0; mi < 4; ++mi)
            #pragma unroll
            for (int n2 = 0; n2 < 2; ++n2)
                o[mi][n2] = __builtin_amdgcn_mfma_f32_16x16x32_bf16(
                    pa[mi], vb[n2], o[mi][n2], 0, 0, 0);
    }

    // normalized O -> Ps, then coalesced 16B stores
    #pragma unroll
    for (int mi = 0; mi < 4; ++mi) {
        #pragma unroll
        for (int r = 0; r < 4; ++r) {
            int row = (mi << 4) + (lg << 2) + r;
            float inv = rinv[mi][r];
            Ps[row * 40 + lc]      = f2bs(o[mi][0][r] * inv);
            Ps[row * 40 + 16 + lc] = f2bs(o[mi][1][r] * inv);
        }
    }
    for (int e = t; e < 196; e += 64) {
        int tok = e >> 2, part = e & 3;
        int iy = tok / 7, ix = tok - iy * 7;
        size_t l = (size_t)(wy * 7 + iy) * 56 + wx * 7 + ix;
        *reinterpret_cast<uint4*>(aw + ((size_t)b * LL + l) * CC + head * HD + (part << 3)) =
            *reinterpret_cast<const uint4*>(&Ps[tok * 40 + (part << 3)]);
    }
}

// ---------------- Depthwise 3x3 (SAME) + exact GELU, vectorized 8-ch/thread ----------
__global__ __launch_bounds__(256)
void dwconv_kernel(const bf16* __restrict__ xn, const float* __restrict__ w,
                   bf16* __restrict__ out)
{
    __shared__ float wl[9 * 288];
    const int t = threadIdx.x;
    for (int i = t; i < CC * 9; i += 256) {
        int c = i / 9, k = i - c * 9;
        wl[k * 288 + (c >> 3) * 12 + (c & 7)] = w[i];
    }
    __syncthreads();
    int e = blockIdx.x * 256 + t;          // 0 .. MM*24-1 (exact grid)
    int cg = e % 24;
    int pix = e / 24;
    int w_ = pix % WW;
    int t2 = pix / WW;
    int h_ = t2 % HH;
    int b  = t2 / HH;
    float acc[8] = {0.f,0.f,0.f,0.f,0.f,0.f,0.f,0.f};
    const bf16* rowbase = xn + ((size_t)b * HH * WW) * CC + (size_t)cg * 8;
    #pragma unroll
    for (int ky = 0; ky < 3; ++ky) {
        int hy = h_ + ky - 1;
        if (hy < 0 || hy >= HH) continue;
        #pragma unroll
        for (int kx = 0; kx < 3; ++kx) {
            int wx_ = w_ + kx - 1;
            if (wx_ < 0 || wx_ >= WW) continue;
            int k = ky * 3 + kx;
            const float4* wp = reinterpret_cast<const float4*>(&wl[k * 288 + cg * 12]);
            float4 w0 = wp[0];
            float4 w1 = wp[1];
            unsigned short u[8];
            *reinterpret_cast<uint4*>(u) = *reinterpret_cast<const uint4*>(
                rowbase + ((size_t)hy * WW + wx_) * CC);
            acc[0] += us2f(u[0]) * w0.x;
            acc[1] += us2f(u[1]) * w0.y;
            acc[2] += us2f(u[2]) * w0.z;
            acc[3] += us2f(u[3]) * w0.w;
            acc[4] += us2f(u[4]) * w1.x;
            acc[5] += us2f(u[5]) * w1.y;
            acc[6] += us2f(u[6]) * w1.z;
            acc[7] += us2f(u[7]) * w1.w;
        }
    }
    bf16 o8[8];
    #pragma unroll
    for (int j = 0; j < 8; ++j) o8[j] = f2b(gelu_exact(acc[j]));
    *reinterpret_cast<uint4*>(out + (size_t)e * 8) = *reinterpret_cast<uint4*>(o8);
}

// ---------------- column (spatial) sum of xn per (b, c) ----------------
__global__ __launch_bounds__(192)
void colsum_kernel(const bf16* __restrict__ xn, float* __restrict__ colsum)
{
    int b = blockIdx.y, g = blockIdx.x, c = threadIdx.x;
    float acc = 0.f;
    int l0 = g * 196;
    for (int l = l0; l < l0 + 196; ++l)
        acc += b2f(xn[((size_t)b * LL + l) * CC + c]);
    atomicAdd(&colsum[b * CC + c], acc);
}

__global__ __launch_bounds__(192)
void gate_kernel(const float* __restrict__ colsum, const float* __restrict__ gw,
                 const float* __restrict__ gb, float* __restrict__ gate)
{
    __shared__ float cm[CC];
    int b = blockIdx.x, o = threadIdx.x;
    cm[o] = colsum[b * CC + o] * (1.0f / LL);
    __syncthreads();
    float acc = gb[o];
    for (int c = 0; c < CC; ++c) acc += gw[o * CC + c] * cm[c];
    gate[b * CC + o] = 1.0f / (1.0f + expf(-acc));
}

// ---------------- means over H (-> [B][W][C]) and over W (-> [B][H][C]), vec8 --------
__global__ __launch_bounds__(256)
void mean_h_kernel(const bf16* __restrict__ xf, float* __restrict__ mh)
{
    int e = blockIdx.x * 256 + threadIdx.x;   // BB*WW*24
    if (e >= BB * WW * 24) return;
    int cg = e % 24, c0 = cg << 3;
    int w_ = (e / 24) % WW;
    int b  = e / (24 * WW);
    float s[8] = {0.f,0.f,0.f,0.f,0.f,0.f,0.f,0.f};
    const bf16* base = xf + ((size_t)b * HH * WW + w_) * CC + c0;
    for (int h_ = 0; h_ < HH; ++h_) {
        unsigned short u[8];
        *reinterpret_cast<uint4*>(u) = *reinterpret_cast<const uint4*>(base + (size_t)h_ * WW * CC);
        #pragma unroll
        for (int j = 0; j < 8; ++j) s[j] += us2f(u[j]);
    }
    float* dst = mh + ((size_t)b * WW + w_) * CC + c0;
    #pragma unroll
    for (int j = 0; j < 8; ++j) dst[j] = s[j] * (1.0f / HH);
}

__global__ __launch_bounds__(256)
void mean_w_kernel(const bf16* __restrict__ xf, float* __restrict__ mw)
{
    int e = blockIdx.x * 256 + threadIdx.x;   // BB*HH*24
    if (e >= BB * HH * 24) return;
    int cg = e % 24, c0 = cg << 3;
    int h_ = (e / 24) % HH;
    int b  = e / (24 * HH);
    float s[8] = {0.f,0.f,0.f,0.f,0.f,0.f,0.f,0.f};
    const bf16* base = xf + ((size_t)b * HH + h_) * WW * CC + c0;
    for (int w_ = 0; w_ < WW; ++w_) {
        unsigned short u[8];
        *reinterpret_cast<uint4*>(u) = *reinterpret_cast<const uint4*>(base + (size_t)w_ * CC);
        #pragma unroll
        for (int j = 0; j < 8; ++j) s[j] += us2f(u[j]);
    }
    float* dst = mw + ((size_t)b * HH + h_) * CC + c0;
    #pragma unroll
    for (int j = 0; j < 8; ++j) dst[j] = s[j] * (1.0f / WW);
}

// ---------------- logits over one spatial axis + softmax over the 56 positions ------------
// out layout TRANSPOSED: [B][56][CC] so downstream reads are channel-contiguous.
__global__ __launch_bounds__(64)
void axsoftmax_kernel(const float* __restrict__ mean, const float* __restrict__ w,
                      const float* __restrict__ bias, float* __restrict__ out)
{
    __shared__ float wrow[CC];
    int o = blockIdx.x, b = blockIdx.y, lane = threadIdx.x;
    for (int c = lane; c < CC; c += 64) wrow[c] = w[o * CC + c];
    __syncthreads();
    float logit = -1e30f;
    if (lane < 56) {
        const float* mr = mean + ((size_t)b * 56 + lane) * CC;
        float a = bias[o];
        for (int c = 0; c < CC; ++c) a += wrow[c] * mr[c];
        logit = a;
    }
    float m = logit;
    #pragma unroll
    for (int off = 32; off > 0; off >>= 1) m = fmaxf(m, __shfl_xor(m, off, 64));
    float e = (lane < 56) ? expf(logit - m) : 0.f;
    float s = e;
    #pragma unroll
    for (int off = 32; off > 0; off >>= 1) s += __shfl_xor(s, off, 64);
    if (lane < 56) out[((size_t)b * 56 + lane) * CC + o] = e / s;
}

// ---------------- xf2 = xf * a_s[b,h,c] * a_t[b,w,c] * 2  (vec8, coalesced) ----------
__global__ __launch_bounds__(256)
void modulate_kernel(const bf16* __restrict__ xf, const float* __restrict__ a_s,
                     const float* __restrict__ a_t, bf16* __restrict__ xf2)
{
    int e = blockIdx.x * 256 + threadIdx.x;    // 0 .. MM*24-1
    int cg = e % 24, c0 = cg << 3;
    int pix = e / 24;
    int w_ = pix % WW;
    int t2 = pix / WW;
    int h_ = t2 % HH;
    int b  = t2 / HH;
    unsigned short u[8];
    size_t base = (size_t)e * 8;
    *reinterpret_cast<uint4*>(u) = *reinterpret_cast<const uint4*>(xf + base);
    const float4* sp = reinterpret_cast<const float4*>(a_s + ((size_t)b * 56 + h_) * CC + c0);
    const float4* tp = reinterpret_cast<const float4*>(a_t + ((size_t)b * 56 + w_) * CC + c0);
    float4 s0 = sp[0], s1 = sp[1];
    float4 t0 = tp[0], t1 = tp[1];
    float ss[8] = {s0.x, s0.y, s0.z, s0.w, s1.x, s1.y, s1.z, s1.w};
    float tt[8] = {t0.x, t0.y, t0.z, t0.w, t1.x, t1.y, t1.z, t1.w};
    bf16 o8[8];
    #pragma unroll
    for (int j = 0; j < 8; ++j)
        o8[j] = f2b(us2f(u[j]) * ss[j] * tt[j] * 2.0f);
    *reinterpret_cast<uint4*>(xf2 + base) = *reinterpret_cast<uint4*>(o8);
}

// =======================================================================================
extern "C" void kernel_launch(void* const* d_in, const int* in_sizes, int n_in,
                              void* d_out, int out_size, void* d_ws, size_t ws_size,
                              hipStream_t stream)
{
    const float* x      = (const float*)d_in[0];
    const float* ln1_g  = (const float*)d_in[3];
    const float* ln1_b  = (const float*)d_in[4];
    const float* qkv_w  = (const float*)d_in[5];
    const float* qkv_b  = (const float*)d_in[6];
    const float* proj_w = (const float*)d_in[7];
    const float* proj_b = (const float*)d_in[8];
    const float* dw_w   = (const float*)d_in[9];
    const float* pw_w   = (const float*)d_in[10];
    const float* gate_w = (const float*)d_in[11];
    const float* gate_b = (const float*)d_in[12];
    const float* temp_w = (const float*)d_in[13];
    const float* temp_b = (const float*)d_in[14];
    const float* spec_w = (const float*)d_in[15];
    const float* spec_b = (const float*)d_in[16];
    const float* fuse_w = (const float*)d_in[17];
    const float* ln2_g  = (const float*)d_in[18];
    const float* ln2_b  = (const float*)d_in[19];
    const float* mlp1_w = (const float*)d_in[20];
    const float* mlp1_b = (const float*)d_in[21];
    const float* mlp2_w = (const float*)d_in[22];
    const float* mlp2_b = (const float*)d_in[23];
    float* out = (float*)d_out;

    const size_t SLOT = (size_t)MM * CC * sizeof(bf16);   // 38,535,168 B
    char* ws = (char*)d_ws;

    bf16* s_xn    = (bf16*)(ws);
    bf16* s_qkv   = (bf16*)(ws + SLOT);        // 3 slots
    bf16* s_aw    = (bf16*)(ws + 4 * SLOT);
    bf16* s_xattn = (bf16*)(ws + SLOT);        // reuse qkv slot 1
    bf16* s_dwg   = (bf16*)(ws + 2 * SLOT);
    bf16* s_xf    = (bf16*)(ws + 4 * SLOT);    // reuse aw (combine fused into pw gemm)
    bf16* s_xf2   = (bf16*)(ws + 3 * SLOT);
    bf16* s_x2    = (bf16*)(ws);               // reuse xn (xn dead after pw+combine)
    bf16* s_hn    = (bf16*)(ws + 2 * SLOT);
    bf16* s_h1    = (bf16*)(ws + 3 * SLOT);    // spans slots 3..4 (384 ch)

    float* colsum  = (float*)(ws + 5 * SLOT);
    float* gatebuf = colsum + BB * CC;
    float* mean_h  = gatebuf + BB * CC;
    float* mean_w  = mean_h + (size_t)BB * 56 * CC;
    float* a_t     = mean_w + (size_t)BB * 56 * CC;
    float* a_s     = a_t    + (size_t)BB * CC * 56;
    // bf16 weight copies
    bf16* wb_qkv  = (bf16*)(a_s + (size_t)BB * CC * 56);
    bf16* wb_proj = wb_qkv  + C3 * CC;
    bf16* wb_pw   = wb_proj + CC * CC;
    bf16* wb_fuse = wb_pw   + CC * CC;
    bf16* wb_mlp1 = wb_fuse + CC * CC;
    bf16* wb_mlp2 = wb_mlp1 + HIDN * CC;
    size_t total_need = (char*)(wb_mlp2 + CC * HIDN) - ws;
    if (ws_size < total_need) return;   // workspace insufficient — visible failure

    const int VEC_BLOCKS = MM * 24 / 256;   // 9408, exact

    // 0. weight conversions (f32 -> bf16)
    cvt_kernel<<<(C3 * CC + 255) / 256, 256, 0, stream>>>(qkv_w, wb_qkv, C3 * CC);
    cvt_kernel<<<(CC * CC + 255) / 256, 256, 0, stream>>>(proj_w, wb_proj, CC * CC);
    cvt_kernel<<<(CC * CC + 255) / 256, 256, 0, stream>>>(pw_w, wb_pw, CC * CC);
    cvt_kernel<<<(CC * CC + 255) / 256, 256, 0, stream>>>(fuse_w, wb_fuse, CC * CC);
    cvt_kernel<<<(HIDN * CC + 255) / 256, 256, 0, stream>>>(mlp1_w, wb_mlp1, HIDN * CC);
    cvt_kernel<<<(CC * HIDN + 255) / 256, 256, 0, stream>>>(mlp2_w, wb_mlp2, CC * HIDN);

    // 1. LN1
    ln_kernel<float><<<MM / 4, 256, 0, stream>>>(x, ln1_g, ln1_b, s_xn);
    // 2. qkv
    mfma_gemm<0, false, C3, CC, bf16, bf16><<<dim3(C3 / 64, MM / 128), 256, 0, stream>>>(
        s_xn, wb_qkv, qkv_b, (const bf16*)nullptr, s_qkv, nullptr, nullptr);
    // 3. window attention (MFMA, 1 wave per (window, head), direct Q/K)
    winattn_kernel<<<dim3(NWIN, NHEAD), 64, 0, stream>>>(s_qkv, s_aw);
    // 4. proj
    mfma_gemm<0, false, CC, CC, bf16, bf16><<<dim3(CC / 64, MM / 128), 256, 0, stream>>>(
        s_aw, wb_proj, proj_b, (const bf16*)nullptr, s_xattn, nullptr, nullptr);
    // 5. depthwise + gelu (vec8)
    dwconv_kernel<<<VEC_BLOCKS, 256, 0, stream>>>(s_xn, dw_w, s_dwg);
    // 6. gate (needs only xn)
    hipMemsetAsync(colsum, 0, BB * CC * sizeof(float), stream);
    colsum_kernel<<<dim3(16, BB), 192, 0, stream>>>(s_xn, colsum);
    gate_kernel<<<BB, 192, 0, stream>>>(colsum, gate_w, gate_b, gatebuf);
    // 7. pointwise + fused combine: xf = dwg@pw^T + xattn + xn*gate
    mfma_gemm<2, false, CC, CC, bf16, bf16><<<dim3(CC / 64, MM / 128), 256, 0, stream>>>(
        s_dwg, wb_pw, (const float*)nullptr, s_xattn, s_xf, s_xn, gatebuf);
    // 8. axis means
    mean_h_kernel<<<(BB * WW * 24 + 255) / 256, 256, 0, stream>>>(s_xf, mean_h);
    mean_w_kernel<<<(BB * HH * 24 + 255) / 256, 256, 0, stream>>>(s_xf, mean_w);
    // 9. a_t (temporal, over W) and a_s (spectral, over H) — transposed [b][pos][c]
    axsoftmax_kernel<<<dim3(CC, BB), 64, 0, stream>>>(mean_h, temp_w, temp_b, a_t);
    axsoftmax_kernel<<<dim3(CC, BB), 64, 0, stream>>>(mean_w, spec_w, spec_b, a_s);
    // 10. modulate (coalesced)
    modulate_kernel<<<VEC_BLOCKS, 256, 0, stream>>>(s_xf, a_s, a_t, s_xf2);
    // 11. fuse (no bias) + residual from original x -> x2
    mfma_gemm<0, true, CC, CC, float, bf16><<<dim3(CC / 64, MM / 128), 256, 0, stream>>>(
        s_xf2, wb_fuse, (const float*)nullptr, x, s_x2, nullptr, nullptr);
    // 12. LN2
    ln_kernel<bf16><<<MM / 4, 256, 0, stream>>>(s_x2, ln2_g, ln2_b, s_hn);
    // 13. MLP1 + gelu
    mfma_gemm<1, false, HIDN, CC, bf16, bf16><<<dim3(HIDN / 64, MM / 128), 256, 0, stream>>>(
        s_hn, wb_mlp1, mlp1_b, (const bf16*)nullptr, s_h1, nullptr, nullptr);
    // 14. MLP2 + residual -> out (f32)
    mfma_gemm<0, true, CC, HIDN, bf16, float><<<dim3(CC / 64, MM / 128), 256, 0, stream>>>(
        s_h1, wb_mlp2, mlp2_b, s_x2, out, nullptr, nullptr);
}

// Round 9
// 452.074 us; speedup vs baseline: 3.7488x; 1.0509x over previous
//
#include <hip/hip_runtime.h>
#include <hip/hip_bf16.h>

typedef __hip_bfloat16 bf16;

// Problem constants (B=32, H=W=56, C=192, NH=6, WS=7)
#define BB 32
#define HH 56
#define WW 56
#define CC 192
#define LL 3136            // 56*56
#define MM (BB*LL)         // 100352 tokens
#define C3 576
#define HIDN 384
#define NHEAD 6
#define HD 32
#define NWIN 2048          // B * 8*8

typedef short short8 __attribute__((ext_vector_type(8)));
typedef float f32x4 __attribute__((ext_vector_type(4)));

__device__ __forceinline__ float us2f(unsigned short u) {
    union { unsigned int i; float f; } v; v.i = ((unsigned int)u) << 16; return v.f;
}
__device__ __forceinline__ float b2f(bf16 h) { return __bfloat162float(h); }
__device__ __forceinline__ bf16 f2b(float f) { return __float2bfloat16(f); }
__device__ __forceinline__ short f2bs(float f) { bf16 h = f2b(f); return *reinterpret_cast<short*>(&h); }
__device__ __forceinline__ float ldv(const bf16* p) { return b2f(*p); }
__device__ __forceinline__ float ldv(const float* p) { return *p; }
__device__ __forceinline__ void stv(bf16* p, float v) { *p = f2b(v); }
__device__ __forceinline__ void stv(float* p, float v) { *p = v; }
__device__ __forceinline__ float gelu_exact(float x) {
    return 0.5f * x * (1.0f + erff(x * 0.70710678118654752f));
}
__device__ __forceinline__ void async_lds16(const void* g, void* l) {
    __builtin_amdgcn_global_load_lds(
        (const __attribute__((address_space(1))) void*)g,
        (__attribute__((address_space(3))) void*)l, 16, 0, 0);
}

// ---------------- f32 -> bf16 conversion of all 6 weight matrices in one launch ------
__global__ __launch_bounds__(256)
void cvt6_kernel(const float* __restrict__ s0, bf16* __restrict__ d0, int n0,
                 const float* __restrict__ s1, bf16* __restrict__ d1, int n1,
                 const float* __restrict__ s2, bf16* __restrict__ d2, int n2,
                 const float* __restrict__ s3, bf16* __restrict__ d3, int n3,
                 const float* __restrict__ s4, bf16* __restrict__ d4, int n4,
                 const float* __restrict__ s5, bf16* __restrict__ d5, int n5)
{
    int i = blockIdx.x * 256 + threadIdx.x;
    if (i < n0) { d0[i] = f2b(s0[i]); return; } i -= n0;
    if (i < n1) { d1[i] = f2b(s1[i]); return; } i -= n1;
    if (i < n2) { d2[i] = f2b(s2[i]); return; } i -= n2;
    if (i < n3) { d3[i] = f2b(s3[i]); return; } i -= n3;
    if (i < n4) { d4[i] = f2b(s4[i]); return; } i -= n4;
    if (i < n5) { d5[i] = f2b(s5[i]); }
}

// ---------------- LayerNorm: one wave per row; optionally also emit bf16 copy of in --
template<typename IT>
__global__ __launch_bounds__(256)
void ln_kernel(const IT* __restrict__ in, const float* __restrict__ g,
               const float* __restrict__ bvec, bf16* __restrict__ out,
               bf16* __restrict__ xcopy)
{
    int wid = threadIdx.x >> 6, lane = threadIdx.x & 63;
    int row = blockIdx.x * 4 + wid;
    const IT* p = in + (size_t)row * CC;
    float x0 = ldv(p + lane);
    float x1 = ldv(p + lane + 64);
    float x2 = ldv(p + lane + 128);
    float s  = x0 + x1 + x2;
    float sq = x0*x0 + x1*x1 + x2*x2;
    #pragma unroll
    for (int o = 32; o > 0; o >>= 1) {
        s  += __shfl_xor(s,  o, 64);
        sq += __shfl_xor(sq, o, 64);
    }
    float mean = s * (1.0f / CC);
    float var  = sq * (1.0f / CC) - mean * mean;
    float inv  = rsqrtf(fmaxf(var, 0.0f) + 1e-5f);
    bf16* q = out + (size_t)row * CC;
    q[lane]       = f2b((x0 - mean) * inv * g[lane]       + bvec[lane]);
    q[lane + 64]  = f2b((x1 - mean) * inv * g[lane + 64]  + bvec[lane + 64]);
    q[lane + 128] = f2b((x2 - mean) * inv * g[lane + 128] + bvec[lane + 128]);
    if (xcopy) {
        bf16* xq = xcopy + (size_t)row * CC;
        xq[lane]       = f2b(x0);
        xq[lane + 64]  = f2b(x1);
        xq[lane + 128] = f2b(x2);
    }
}

// ---------------- MFMA GEMM: out[M,NN] = epi(A[M,KK] @ W[NN,KK]^T + bias) ----
// EPI: 0=none, 1=gelu, 2=combine (out = acc + resid + b2f(xn2)*gate[b,c]).
// 256 threads = 4 waves, block tile 128x64, wave tile 32x64, BK=64.
// XCD-chunked block swizzle (bijective when nwg%8==0).
template<int EPI, bool RESID, int NN, int KK, typename RT, typename OT>
__global__ __launch_bounds__(256)
void mfma_gemm(const bf16* __restrict__ A, const bf16* __restrict__ W,
               const float* __restrict__ bias, const RT* __restrict__ resid,
               OT* __restrict__ out,
               const bf16* __restrict__ xn2, const float* __restrict__ gate)
{
    __shared__ __align__(16) short As[128 * 64];
    __shared__ __align__(16) short Bs[64 * 64];
    const int t    = threadIdx.x;
    const int lane = t & 63;
    const int w    = t >> 6;        // wave 0..3
    const int nx   = gridDim.x;
    const int nwg  = gridDim.x * gridDim.y;
    int hw  = blockIdx.y * nx + blockIdx.x;
    int wid = (nwg & 7) ? hw : ((hw & 7) * (nwg >> 3) + (hw >> 3));
    const int m0   = (wid / nx) * 128;
    const int n0   = (wid % nx) * 64;
    const int lr   = lane & 15;     // row within 16
    const int lg   = lane >> 4;     // k-group 0..3

    f32x4 acc[2][4];
    #pragma unroll
    for (int i = 0; i < 2; ++i)
        #pragma unroll
        for (int j = 0; j < 4; ++j)
            acc[i][j] = (f32x4){0.f, 0.f, 0.f, 0.f};

    for (int k0 = 0; k0 < KK; k0 += 64) {
        const bf16* Ab = A + (size_t)m0 * KK + k0;
        const bf16* Wb = W + (size_t)n0 * KK + k0;
        #pragma unroll
        for (int li = 0; li < 4; ++li) {
            int chunk = li * 256 + t;
            int r = chunk >> 3, c = chunk & 7;
            int cs = c ^ (r & 7);
            async_lds16(Ab + (size_t)r * KK + (cs << 3),
                        &As[(li * 256 + w * 64) << 3]);
        }
        #pragma unroll
        for (int li = 0; li < 2; ++li) {
            int chunk = li * 256 + t;
            int r = chunk >> 3, c = chunk & 7;
            int cs = c ^ (r & 7);
            async_lds16(Wb + (size_t)r * KK + (cs << 3),
                        &Bs[(li * 256 + w * 64) << 3]);
        }
        __syncthreads();
        #pragma unroll
        for (int kf = 0; kf < 2; ++kf) {
            short8 a_[2], b_[4];
            #pragma unroll
            for (int mi = 0; mi < 2; ++mi) {
                int row = (w << 5) + (mi << 4) + lr;
                a_[mi] = *reinterpret_cast<const short8*>(
                    &As[(row << 6) + ((((kf << 2) + lg) ^ (row & 7)) << 3)]);
            }
            #pragma unroll
            for (int ni = 0; ni < 4; ++ni) {
                int rn = (ni << 4) + lr;
                b_[ni] = *reinterpret_cast<const short8*>(
                    &Bs[(rn << 6) + ((((kf << 2) + lg) ^ (rn & 7)) << 3)]);
            }
            #pragma unroll
            for (int mi = 0; mi < 2; ++mi)
                #pragma unroll
                for (int ni = 0; ni < 4; ++ni)
                    acc[mi][ni] = __builtin_amdgcn_mfma_f32_16x16x32_bf16(
                        a_[mi], b_[ni], acc[mi][ni], 0, 0, 0);
        }
        __syncthreads();
    }

    #pragma unroll
    for (int mi = 0; mi < 2; ++mi) {
        #pragma unroll
        for (int ni = 0; ni < 4; ++ni) {
            int col = n0 + (ni << 4) + lr;
            float bv = bias ? bias[col] : 0.f;
            #pragma unroll
            for (int r = 0; r < 4; ++r) {
                int row = m0 + (w << 5) + (mi << 4) + (lg << 2) + r;
                float c = acc[mi][ni][r] + bv;
                if (EPI == 1) c = gelu_exact(c);
                if (EPI == 2) {
                    int bidx = row / LL;
                    c += ldv(resid + (size_t)row * NN + col)
                       + b2f(xn2[(size_t)row * NN + col]) * gate[bidx * CC + col];
                }
                if (RESID) c += ldv(resid + (size_t)row * NN + col);
                stv(out + (size_t)row * NN + col, c);
            }
        }
    }
}

// ---------------- MFMA window attention v3: 4 waves/block, one (window,head)/wave ----
// Q,K fragments direct global->registers; per-wave LDS slices (no barriers).
// LDS 38.9 KB/block -> 4 blocks x 4 waves = 16 waves/CU.
__global__ __launch_bounds__(256)
void winattn_kernel(const bf16* __restrict__ qkv, bf16* __restrict__ aw)
{
    __shared__ __align__(16) short Ps[4][64 * 40];
    __shared__ __align__(16) short Vt[4][32 * 72];

    const int w  = threadIdx.x >> 6;     // wave in block
    const int t  = threadIdx.x & 63;     // lane
    const int p  = blockIdx.x * 4 + w;   // 0..12287 pair index
    const int wi = p / 6;
    const int head = p - wi * 6;
    const int b  = wi >> 6;
    const int wr = wi & 63;
    const int wy = wr >> 3, wx = wr & 7;
    const int lc = t & 15;
    const int lg = t >> 4;
    const float scale = 0.1767766952966369f;   // 32^-0.5
    const bf16* qbase = qkv + (size_t)b * LL * C3 + head * HD;
    short* ps = Ps[w];
    short* vt = Vt[w];

    // zero pad vt cols 48..63
    #pragma unroll
    for (int e = t; e < 512; e += 64) {
        int r = e >> 4, c = 48 + (e & 15);
        vt[r * 72 + c] = 0;
    }
    // stage V transposed
    for (int e = t; e < 196; e += 64) {
        int tok = e >> 2, part = e & 3;
        int iy = tok / 7, ix = tok - iy * 7;
        size_t l = (size_t)(wy * 7 + iy) * 56 + wx * 7 + ix;
        uint4 pv = *reinterpret_cast<const uint4*>(qbase + l * C3 + 384 + (part << 3));
        unsigned short uv[8];
        *reinterpret_cast<uint4*>(uv) = pv;
        #pragma unroll
        for (int jj = 0; jj < 8; ++jj)
            vt[((part << 3) + jj) * 72 + tok] = (short)uv[jj];
    }

    // Q, K fragments direct from global (predicated)
    const short8 zero8 = {0, 0, 0, 0, 0, 0, 0, 0};
    short8 a_[4], b_[4];
    #pragma unroll
    for (int mi = 0; mi < 4; ++mi) {
        int tk = (mi << 4) + lc;
        a_[mi] = zero8;
        if (tk < 49) {
            int iy = tk / 7, ix = tk - iy * 7;
            size_t l = (size_t)(wy * 7 + iy) * 56 + wx * 7 + ix;
            a_[mi] = *reinterpret_cast<const short8*>(qbase + l * C3 + (lg << 3));
        }
    }
    #pragma unroll
    for (int ni = 0; ni < 4; ++ni) {
        int rn = (ni << 4) + lc;
        b_[ni] = zero8;
        if (rn < 49) {
            int iy = rn / 7, ix = rn - iy * 7;
            size_t l = (size_t)(wy * 7 + iy) * 56 + wx * 7 + ix;
            b_[ni] = *reinterpret_cast<const short8*>(qbase + l * C3 + 192 + (lg << 3));
        }
    }

    // S = Q K^T
    f32x4 acc[4][4];
    #pragma unroll
    for (int i = 0; i < 4; ++i)
        #pragma unroll
        for (int j = 0; j < 4; ++j)
            acc[i][j] = (f32x4){0.f, 0.f, 0.f, 0.f};
    #pragma unroll
    for (int mi = 0; mi < 4; ++mi)
        #pragma unroll
        for (int ni = 0; ni < 4; ++ni)
            acc[mi][ni] = __builtin_amdgcn_mfma_f32_16x16x32_bf16(
                a_[mi], b_[ni], acc[mi][ni], 0, 0, 0);

    // softmax over cols; C layout: row = mi*16 + lg*4 + r, col = ni*16 + lc.
    float rinv[4][4];
    #pragma unroll
    for (int mi = 0; mi < 4; ++mi) {
        #pragma unroll
        for (int r = 0; r < 4; ++r) {
            float mx = -1e30f;
            #pragma unroll
            for (int ni = 0; ni < 4; ++ni) {
                float v = acc[mi][ni][r];
                if (ni == 3 && lc != 0) v = -1e30f;
                mx = fmaxf(mx, v);
            }
            mx = fmaxf(mx, __shfl_xor(mx, 1, 64));
            mx = fmaxf(mx, __shfl_xor(mx, 2, 64));
            mx = fmaxf(mx, __shfl_xor(mx, 4, 64));
            mx = fmaxf(mx, __shfl_xor(mx, 8, 64));
            float sm = 0.f;
            int row = (mi << 4) + (lg << 2) + r;
            #pragma unroll
            for (int ni = 0; ni < 4; ++ni) {
                float e = (ni == 3 && lc != 0) ? 0.f
                        : __expf(scale * (acc[mi][ni][r] - mx));
                ps[row * 40 + (ni << 4) + lc] = f2bs(e);
                sm += e;
            }
            sm += __shfl_xor(sm, 1, 64);
            sm += __shfl_xor(sm, 2, 64);
            sm += __shfl_xor(sm, 4, 64);
            sm += __shfl_xor(sm, 8, 64);
            rinv[mi][r] = 1.0f / sm;
        }
    }

    // O = P V
    f32x4 o[4][2];
    #pragma unroll
    for (int i = 0; i < 4; ++i) {
        o[i][0] = (f32x4){0.f, 0.f, 0.f, 0.f};
        o[i][1] = (f32x4){0.f, 0.f, 0.f, 0.f};
    }
    #pragma unroll
    for (int kf = 0; kf < 2; ++kf) {
        short8 pa[4], vb[2];
        #pragma unroll
        for (int mi = 0; mi < 4; ++mi)
            pa[mi] = *reinterpret_cast<const short8*>(
                &ps[((mi << 4) + lc) * 40 + (kf << 5) + (lg << 3)]);
        #pragma unroll
        for (int n2 = 0; n2 < 2; ++n2)
            vb[n2] = *reinterpret_cast<const short8*>(
                &vt[((n2 << 4) + lc) * 72 + (kf << 5) + (lg << 3)]);
        #pragma unroll
        for (int mi = 0; mi < 4; ++mi)
            #pragma unroll
            for (int n2 = 0; n2 < 2; ++n2)
                o[mi][n2] = __builtin_amdgcn_mfma_f32_16x16x32_bf16(
                    pa[mi], vb[n2], o[mi][n2], 0, 0, 0);
    }

    // normalized O -> ps, then coalesced 16B stores
    #pragma unroll
    for (int mi = 0; mi < 4; ++mi) {
        #pragma unroll
        for (int r = 0; r < 4; ++r) {
            int row = (mi << 4) + (lg << 2) + r;
            float inv = rinv[mi][r];
            ps[row * 40 + lc]      = f2bs(o[mi][0][r] * inv);
            ps[row * 40 + 16 + lc] = f2bs(o[mi][1][r] * inv);
        }
    }
    for (int e = t; e < 196; e += 64) {
        int tok = e >> 2, part = e & 3;
        int iy = tok / 7, ix = tok - iy * 7;
        size_t l = (size_t)(wy * 7 + iy) * 56 + wx * 7 + ix;
        *reinterpret_cast<uint4*>(aw + ((size_t)b * LL + l) * CC + head * HD + (part << 3)) =
            *reinterpret_cast<const uint4*>(&ps[tok * 40 + (part << 3)]);
    }
}

// ---------------- Depthwise 3x3 (SAME) + exact GELU, vectorized 8-ch/thread ----------
__global__ __launch_bounds__(256)
void dwconv_kernel(const bf16* __restrict__ xn, const float* __restrict__ w,
                   bf16* __restrict__ out)
{
    __shared__ float wl[9 * 288];
    const int t = threadIdx.x;
    for (int i = t; i < CC * 9; i += 256) {
        int c = i / 9, k = i - c * 9;
        wl[k * 288 + (c >> 3) * 12 + (c & 7)] = w[i];
    }
    __syncthreads();
    int e = blockIdx.x * 256 + t;          // 0 .. MM*24-1 (exact grid)
    int cg = e % 24;
    int pix = e / 24;
    int w_ = pix % WW;
    int t2 = pix / WW;
    int h_ = t2 % HH;
    int b  = t2 / HH;
    float acc[8] = {0.f,0.f,0.f,0.f,0.f,0.f,0.f,0.f};
    const bf16* rowbase = xn + ((size_t)b * HH * WW) * CC + (size_t)cg * 8;
    #pragma unroll
    for (int ky = 0; ky < 3; ++ky) {
        int hy = h_ + ky - 1;
        if (hy < 0 || hy >= HH) continue;
        #pragma unroll
        for (int kx = 0; kx < 3; ++kx) {
            int wx_ = w_ + kx - 1;
            if (wx_ < 0 || wx_ >= WW) continue;
            int k = ky * 3 + kx;
            const float4* wp = reinterpret_cast<const float4*>(&wl[k * 288 + cg * 12]);
            float4 w0 = wp[0];
            float4 w1 = wp[1];
            unsigned short u[8];
            *reinterpret_cast<uint4*>(u) = *reinterpret_cast<const uint4*>(
                rowbase + ((size_t)hy * WW + wx_) * CC);
            acc[0] += us2f(u[0]) * w0.x;
            acc[1] += us2f(u[1]) * w0.y;
            acc[2] += us2f(u[2]) * w0.z;
            acc[3] += us2f(u[3]) * w0.w;
            acc[4] += us2f(u[4]) * w1.x;
            acc[5] += us2f(u[5]) * w1.y;
            acc[6] += us2f(u[6]) * w1.z;
            acc[7] += us2f(u[7]) * w1.w;
        }
    }
    bf16 o8[8];
    #pragma unroll
    for (int j = 0; j < 8; ++j) o8[j] = f2b(gelu_exact(acc[j]));
    *reinterpret_cast<uint4*>(out + (size_t)e * 8) = *reinterpret_cast<uint4*>(o8);
}

// ---------------- column (spatial) sum of xn per (b, c) ----------------
__global__ __launch_bounds__(192)
void colsum_kernel(const bf16* __restrict__ xn, float* __restrict__ colsum)
{
    int b = blockIdx.y, g = blockIdx.x, c = threadIdx.x;
    float acc = 0.f;
    int l0 = g * 196;
    for (int l = l0; l < l0 + 196; ++l)
        acc += b2f(xn[((size_t)b * LL + l) * CC + c]);
    atomicAdd(&colsum[b * CC + c], acc);
}

__global__ __launch_bounds__(192)
void gate_kernel(const float* __restrict__ colsum, const float* __restrict__ gw,
                 const float* __restrict__ gb, float* __restrict__ gate)
{
    __shared__ float cm[CC];
    int b = blockIdx.x, o = threadIdx.x;
    cm[o] = colsum[b * CC + o] * (1.0f / LL);
    __syncthreads();
    float acc = gb[o];
    for (int c = 0; c < CC; ++c) acc += gw[o * CC + c] * cm[c];
    gate[b * CC + o] = 1.0f / (1.0f + expf(-acc));
}

// ---------------- means over H and W in one launch, vec8 ----------------
__global__ __launch_bounds__(256)
void means_kernel(const bf16* __restrict__ xf, float* __restrict__ mh,
                  float* __restrict__ mw)
{
    int e = blockIdx.x * 256 + threadIdx.x;
    const int NHALF = BB * WW * 24;   // == BB*HH*24
    if (e < NHALF) {
        int cg = e % 24, c0 = cg << 3;
        int w_ = (e / 24) % WW;
        int b  = e / (24 * WW);
        float s[8] = {0.f,0.f,0.f,0.f,0.f,0.f,0.f,0.f};
        const bf16* base = xf + ((size_t)b * HH * WW + w_) * CC + c0;
        for (int h_ = 0; h_ < HH; ++h_) {
            unsigned short u[8];
            *reinterpret_cast<uint4*>(u) = *reinterpret_cast<const uint4*>(base + (size_t)h_ * WW * CC);
            #pragma unroll
            for (int j = 0; j < 8; ++j) s[j] += us2f(u[j]);
        }
        float* dst = mh + ((size_t)b * WW + w_) * CC + c0;
        #pragma unroll
        for (int j = 0; j < 8; ++j) dst[j] = s[j] * (1.0f / HH);
    } else {
        e -= NHALF;
        int cg = e % 24, c0 = cg << 3;
        int h_ = (e / 24) % HH;
        int b  = e / (24 * HH);
        float s[8] = {0.f,0.f,0.f,0.f,0.f,0.f,0.f,0.f};
        const bf16* base = xf + ((size_t)b * HH + h_) * WW * CC + c0;
        for (int w_ = 0; w_ < WW; ++w_) {
            unsigned short u[8];
            *reinterpret_cast<uint4*>(u) = *reinterpret_cast<const uint4*>(base + (size_t)w_ * CC);
            #pragma unroll
            for (int j = 0; j < 8; ++j) s[j] += us2f(u[j]);
        }
        float* dst = mw + ((size_t)b * HH + h_) * CC + c0;
        #pragma unroll
        for (int j = 0; j < 8; ++j) dst[j] = s[j] * (1.0f / WW);
    }
}

// ---------------- both axis-softmaxes in one launch (blockIdx.z selects) -------------
// out layout TRANSPOSED: [B][56][CC].
__global__ __launch_bounds__(64)
void axsoftmax2_kernel(const float* __restrict__ mh, const float* __restrict__ tw,
                       const float* __restrict__ tb, float* __restrict__ at,
                       const float* __restrict__ mw, const float* __restrict__ sw,
                       const float* __restrict__ sb, float* __restrict__ as_)
{
    const float* mean; const float* w; const float* bias; float* out;
    if (blockIdx.z == 0) { mean = mh; w = tw; bias = tb; out = at; }
    else                 { mean = mw; w = sw; bias = sb; out = as_; }
    __shared__ float wrow[CC];
    int o = blockIdx.x, b = blockIdx.y, lane = threadIdx.x;
    for (int c = lane; c < CC; c += 64) wrow[c] = w[o * CC + c];
    __syncthreads();
    float logit = -1e30f;
    if (lane < 56) {
        const float* mr = mean + ((size_t)b * 56 + lane) * CC;
        float a = bias[o];
        for (int c = 0; c < CC; ++c) a += wrow[c] * mr[c];
        logit = a;
    }
    float m = logit;
    #pragma unroll
    for (int off = 32; off > 0; off >>= 1) m = fmaxf(m, __shfl_xor(m, off, 64));
    float e = (lane < 56) ? expf(logit - m) : 0.f;
    float s = e;
    #pragma unroll
    for (int off = 32; off > 0; off >>= 1) s += __shfl_xor(s, off, 64);
    if (lane < 56) out[((size_t)b * 56 + lane) * CC + o] = e / s;
}

// ---------------- xf2 = xf * a_s[b,h,c] * a_t[b,w,c] * 2  (vec8, coalesced) ----------
__global__ __launch_bounds__(256)
void modulate_kernel(const bf16* __restrict__ xf, const float* __restrict__ a_s,
                     const float* __restrict__ a_t, bf16* __restrict__ xf2)
{
    int e = blockIdx.x * 256 + threadIdx.x;    // 0 .. MM*24-1
    int cg = e % 24, c0 = cg << 3;
    int pix = e / 24;
    int w_ = pix % WW;
    int t2 = pix / WW;
    int h_ = t2 % HH;
    int b  = t2 / HH;
    unsigned short u[8];
    size_t base = (size_t)e * 8;
    *reinterpret_cast<uint4*>(u) = *reinterpret_cast<const uint4*>(xf + base);
    const float4* sp = reinterpret_cast<const float4*>(a_s + ((size_t)b * 56 + h_) * CC + c0);
    const float4* tp = reinterpret_cast<const float4*>(a_t + ((size_t)b * 56 + w_) * CC + c0);
    float4 s0 = sp[0], s1 = sp[1];
    float4 t0 = tp[0], t1 = tp[1];
    float ss[8] = {s0.x, s0.y, s0.z, s0.w, s1.x, s1.y, s1.z, s1.w};
    float tt[8] = {t0.x, t0.y, t0.z, t0.w, t1.x, t1.y, t1.z, t1.w};
    bf16 o8[8];
    #pragma unroll
    for (int j = 0; j < 8; ++j)
        o8[j] = f2b(us2f(u[j]) * ss[j] * tt[j] * 2.0f);
    *reinterpret_cast<uint4*>(xf2 + base) = *reinterpret_cast<uint4*>(o8);
}

// =======================================================================================
extern "C" void kernel_launch(void* const* d_in, const int* in_sizes, int n_in,
                              void* d_out, int out_size, void* d_ws, size_t ws_size,
                              hipStream_t stream)
{
    const float* x      = (const float*)d_in[0];
    const float* ln1_g  = (const float*)d_in[3];
    const float* ln1_b  = (const float*)d_in[4];
    const float* qkv_w  = (const float*)d_in[5];
    const float* qkv_b  = (const float*)d_in[6];
    const float* proj_w = (const float*)d_in[7];
    const float* proj_b = (const float*)d_in[8];
    const float* dw_w   = (const float*)d_in[9];
    const float* pw_w   = (const float*)d_in[10];
    const float* gate_w = (const float*)d_in[11];
    const float* gate_b = (const float*)d_in[12];
    const float* temp_w = (const float*)d_in[13];
    const float* temp_b = (const float*)d_in[14];
    const float* spec_w = (const float*)d_in[15];
    const float* spec_b = (const float*)d_in[16];
    const float* fuse_w = (const float*)d_in[17];
    const float* ln2_g  = (const float*)d_in[18];
    const float* ln2_b  = (const float*)d_in[19];
    const float* mlp1_w = (const float*)d_in[20];
    const float* mlp1_b = (const float*)d_in[21];
    const float* mlp2_w = (const float*)d_in[22];
    const float* mlp2_b = (const float*)d_in[23];
    float* out = (float*)d_out;

    const size_t SLOT = (size_t)MM * CC * sizeof(bf16);   // 38,535,168 B
    char* ws = (char*)d_ws;

    bf16* s_xn    = (bf16*)(ws);
    bf16* s_qkv   = (bf16*)(ws + SLOT);        // 3 slots
    bf16* s_aw    = (bf16*)(ws + 4 * SLOT);
    bf16* s_xattn = (bf16*)(ws + SLOT);        // reuse qkv slot 1
    bf16* s_dwg   = (bf16*)(ws + 2 * SLOT);
    bf16* s_xf    = (bf16*)(ws + 4 * SLOT);    // reuse aw (combine fused into pw gemm)
    bf16* s_xf2   = (bf16*)(ws + 3 * SLOT);
    bf16* s_x2    = (bf16*)(ws);               // reuse xn (xn dead after pw+combine)
    bf16* s_hn    = (bf16*)(ws + 2 * SLOT);
    bf16* s_h1    = (bf16*)(ws + 3 * SLOT);    // spans slots 3..4 (384 ch)

    float* colsum  = (float*)(ws + 5 * SLOT);
    float* gatebuf = colsum + BB * CC;
    float* mean_h  = gatebuf + BB * CC;
    float* mean_w  = mean_h + (size_t)BB * 56 * CC;
    float* a_t     = mean_w + (size_t)BB * 56 * CC;
    float* a_s     = a_t    + (size_t)BB * CC * 56;
    // bf16 weight copies
    bf16* wb_qkv  = (bf16*)(a_s + (size_t)BB * CC * 56);
    bf16* wb_proj = wb_qkv  + C3 * CC;
    bf16* wb_pw   = wb_proj + CC * CC;
    bf16* wb_fuse = wb_pw   + CC * CC;
    bf16* wb_mlp1 = wb_fuse + CC * CC;
    bf16* wb_mlp2 = wb_mlp1 + HIDN * CC;
    char* after_w = (char*)(wb_mlp2 + CC * HIDN);
    size_t total_need = after_w - ws;
    if (ws_size < total_need) return;   // workspace insufficient — visible failure
    // optional bf16 copy of x (saves 115 MB of f32 resid traffic in fuse GEMM)
    bf16* s_xb = (bf16*)after_w;
    bool have_xb = (ws_size >= total_need + SLOT);

    const int VEC_BLOCKS = MM * 24 / 256;   // 9408, exact
    const int CVT_N0 = C3 * CC, CVT_N1 = CC * CC, CVT_N4 = HIDN * CC;
    const int CVT_TOTAL = CVT_N0 + 3 * CVT_N1 + 2 * CVT_N4;   // 368640

    // 0. all weight conversions in one launch
    cvt6_kernel<<<(CVT_TOTAL + 255) / 256, 256, 0, stream>>>(
        qkv_w, wb_qkv, CVT_N0, proj_w, wb_proj, CVT_N1, pw_w, wb_pw, CVT_N1,
        fuse_w, wb_fuse, CVT_N1, mlp1_w, wb_mlp1, CVT_N4, mlp2_w, wb_mlp2, CVT_N4);

    // 1. LN1 (+ optional bf16 x copy)
    ln_kernel<float><<<MM / 4, 256, 0, stream>>>(x, ln1_g, ln1_b, s_xn,
                                                 have_xb ? s_xb : nullptr);
    // 2. qkv
    mfma_gemm<0, false, C3, CC, bf16, bf16><<<dim3(C3 / 64, MM / 128), 256, 0, stream>>>(
        s_xn, wb_qkv, qkv_b, (const bf16*)nullptr, s_qkv, nullptr, nullptr);
    // 3. window attention (4 waves/block, one (window,head)/wave)
    winattn_kernel<<<NWIN * NHEAD / 4, 256, 0, stream>>>(s_qkv, s_aw);
    // 4. proj
    mfma_gemm<0, false, CC, CC, bf16, bf16><<<dim3(CC / 64, MM / 128), 256, 0, stream>>>(
        s_aw, wb_proj, proj_b, (const bf16*)nullptr, s_xattn, nullptr, nullptr);
    // 5. depthwise + gelu (vec8)
    dwconv_kernel<<<VEC_BLOCKS, 256, 0, stream>>>(s_xn, dw_w, s_dwg);
    // 6. gate (needs only xn)
    hipMemsetAsync(colsum, 0, BB * CC * sizeof(float), stream);
    colsum_kernel<<<dim3(16, BB), 192, 0, stream>>>(s_xn, colsum);
    gate_kernel<<<BB, 192, 0, stream>>>(colsum, gate_w, gate_b, gatebuf);
    // 7. pointwise + fused combine: xf = dwg@pw^T + xattn + xn*gate
    mfma_gemm<2, false, CC, CC, bf16, bf16><<<dim3(CC / 64, MM / 128), 256, 0, stream>>>(
        s_dwg, wb_pw, (const float*)nullptr, s_xattn, s_xf, s_xn, gatebuf);
    // 8. axis means (one launch)
    means_kernel<<<(2 * BB * WW * 24) / 256, 256, 0, stream>>>(s_xf, mean_h, mean_w);
    // 9. both axis softmaxes (one launch) — transposed [b][pos][c]
    axsoftmax2_kernel<<<dim3(CC, BB, 2), 64, 0, stream>>>(
        mean_h, temp_w, temp_b, a_t, mean_w, spec_w, spec_b, a_s);
    // 10. modulate (coalesced)
    modulate_kernel<<<VEC_BLOCKS, 256, 0, stream>>>(s_xf, a_s, a_t, s_xf2);
    // 11. fuse (no bias) + residual x -> x2 (bf16 resid if workspace allows)
    if (have_xb)
        mfma_gemm<0, true, CC, CC, bf16, bf16><<<dim3(CC / 64, MM / 128), 256, 0, stream>>>(
            s_xf2, wb_fuse, (const float*)nullptr, s_xb, s_x2, nullptr, nullptr);
    else
        mfma_gemm<0, true, CC, CC, float, bf16><<<dim3(CC / 64, MM / 128), 256, 0, stream>>>(
            s_xf2, wb_fuse, (const float*)nullptr, x, s_x2, nullptr, nullptr);
    // 12. LN2
    ln_kernel<bf16><<<MM / 4, 256, 0, stream>>>(s_x2, ln2_g, ln2_b, s_hn, nullptr);
    // 13. MLP1 + gelu
    mfma_gemm<1, false, HIDN, CC, bf16, bf16><<<dim3(HIDN / 64, MM / 128), 256, 0, stream>>>(
        s_hn, wb_mlp1, mlp1_b, (const bf16*)nullptr, s_h1, nullptr, nullptr);
    // 14. MLP2 + residual -> out (f32)
    mfma_gemm<0, true, CC, HIDN, bf16, float><<<dim3(CC / 64, MM / 128), 256, 0, stream>>>(
        s_h1, wb_mlp2, mlp2_b, s_x2, out, nullptr, nullptr);
}

// Round 10
// 391.707 us; speedup vs baseline: 4.3265x; 1.1541x over previous
//
#include <hip/hip_runtime.h>
#include <hip/hip_bf16.h>

typedef __hip_bfloat16 bf16;

// Problem constants (B=32, H=W=56, C=192, NH=6, WS=7)
#define BB 32
#define HH 56
#define WW 56
#define CC 192
#define LL 3136            // 56*56
#define MM (BB*LL)         // 100352 tokens
#define C3 576
#define HIDN 384
#define NHEAD 6
#define HD 32
#define NWIN 2048          // B * 8*8

typedef short short8 __attribute__((ext_vector_type(8)));
typedef float f32x4 __attribute__((ext_vector_type(4)));

__device__ __forceinline__ float us2f(unsigned short u) {
    union { unsigned int i; float f; } v; v.i = ((unsigned int)u) << 16; return v.f;
}
__device__ __forceinline__ float b2f(bf16 h) { return __bfloat162float(h); }
__device__ __forceinline__ bf16 f2b(float f) { return __float2bfloat16(f); }
__device__ __forceinline__ short f2bs(float f) { bf16 h = f2b(f); return *reinterpret_cast<short*>(&h); }
__device__ __forceinline__ float ldv(const bf16* p) { return b2f(*p); }
__device__ __forceinline__ float ldv(const float* p) { return *p; }
__device__ __forceinline__ void stv(bf16* p, float v) { *p = f2b(v); }
__device__ __forceinline__ void stv(float* p, float v) { *p = v; }
__device__ __forceinline__ float gelu_exact(float x) {
    return 0.5f * x * (1.0f + erff(x * 0.70710678118654752f));
}
__device__ __forceinline__ void async_lds16(const void* g, void* l) {
    __builtin_amdgcn_global_load_lds(
        (const __attribute__((address_space(1))) void*)g,
        (__attribute__((address_space(3))) void*)l, 16, 0, 0);
}

// ---------------- f32 -> bf16 conversion of all 8 weight matrices in one launch ------
__global__ __launch_bounds__(256)
void cvt8_kernel(const float* __restrict__ s0, bf16* __restrict__ d0, int n0,
                 const float* __restrict__ s1, bf16* __restrict__ d1, int n1,
                 const float* __restrict__ s2, bf16* __restrict__ d2, int n2,
                 const float* __restrict__ s3, bf16* __restrict__ d3, int n3,
                 const float* __restrict__ s4, bf16* __restrict__ d4, int n4,
                 const float* __restrict__ s5, bf16* __restrict__ d5, int n5,
                 const float* __restrict__ s6, bf16* __restrict__ d6, int n6,
                 const float* __restrict__ s7, bf16* __restrict__ d7, int n7)
{
    int i = blockIdx.x * 256 + threadIdx.x;
    if (i < n0) { d0[i] = f2b(s0[i]); return; } i -= n0;
    if (i < n1) { d1[i] = f2b(s1[i]); return; } i -= n1;
    if (i < n2) { d2[i] = f2b(s2[i]); return; } i -= n2;
    if (i < n3) { d3[i] = f2b(s3[i]); return; } i -= n3;
    if (i < n4) { d4[i] = f2b(s4[i]); return; } i -= n4;
    if (i < n5) { d5[i] = f2b(s5[i]); return; } i -= n5;
    if (i < n6) { d6[i] = f2b(s6[i]); return; } i -= n6;
    if (i < n7) { d7[i] = f2b(s7[i]); }
}

// ---------------- LayerNorm: one wave per row; optionally also emit bf16 copy of in --
template<typename IT>
__global__ __launch_bounds__(256)
void ln_kernel(const IT* __restrict__ in, const float* __restrict__ g,
               const float* __restrict__ bvec, bf16* __restrict__ out,
               bf16* __restrict__ xcopy)
{
    int wid = threadIdx.x >> 6, lane = threadIdx.x & 63;
    int row = blockIdx.x * 4 + wid;
    const IT* p = in + (size_t)row * CC;
    float x0 = ldv(p + lane);
    float x1 = ldv(p + lane + 64);
    float x2 = ldv(p + lane + 128);
    float s  = x0 + x1 + x2;
    float sq = x0*x0 + x1*x1 + x2*x2;
    #pragma unroll
    for (int o = 32; o > 0; o >>= 1) {
        s  += __shfl_xor(s,  o, 64);
        sq += __shfl_xor(sq, o, 64);
    }
    float mean = s * (1.0f / CC);
    float var  = sq * (1.0f / CC) - mean * mean;
    float inv  = rsqrtf(fmaxf(var, 0.0f) + 1e-5f);
    bf16* q = out + (size_t)row * CC;
    q[lane]       = f2b((x0 - mean) * inv * g[lane]       + bvec[lane]);
    q[lane + 64]  = f2b((x1 - mean) * inv * g[lane + 64]  + bvec[lane + 64]);
    q[lane + 128] = f2b((x2 - mean) * inv * g[lane + 128] + bvec[lane + 128]);
    if (xcopy) {
        bf16* xq = xcopy + (size_t)row * CC;
        xq[lane]       = f2b(x0);
        xq[lane + 64]  = f2b(x1);
        xq[lane + 128] = f2b(x2);
    }
}

// ---------------- MFMA GEMM: out[M,NN] = epi(A[M,KK] @ W[NN,KK]^T + bias) ----
// EPI: 0=none, 1=gelu, 2=combine (out = acc + resid + b2f(xn2)*gate[b,c]).
// 256 threads = 4 waves, block tile 128x64, wave tile 32x64, BK=64.
// XCD-chunked block swizzle (bijective when nwg%8==0).
template<int EPI, bool RESID, int NN, int KK, typename RT, typename OT>
__global__ __launch_bounds__(256)
void mfma_gemm(const bf16* __restrict__ A, const bf16* __restrict__ W,
               const float* __restrict__ bias, const RT* __restrict__ resid,
               OT* __restrict__ out,
               const bf16* __restrict__ xn2, const float* __restrict__ gate)
{
    __shared__ __align__(16) short As[128 * 64];
    __shared__ __align__(16) short Bs[64 * 64];
    const int t    = threadIdx.x;
    const int lane = t & 63;
    const int w    = t >> 6;        // wave 0..3
    const int nx   = gridDim.x;
    const int nwg  = gridDim.x * gridDim.y;
    int hw  = blockIdx.y * nx + blockIdx.x;
    int wid = (nwg & 7) ? hw : ((hw & 7) * (nwg >> 3) + (hw >> 3));
    const int m0   = (wid / nx) * 128;
    const int n0   = (wid % nx) * 64;
    const int lr   = lane & 15;     // row within 16
    const int lg   = lane >> 4;     // k-group 0..3

    f32x4 acc[2][4];
    #pragma unroll
    for (int i = 0; i < 2; ++i)
        #pragma unroll
        for (int j = 0; j < 4; ++j)
            acc[i][j] = (f32x4){0.f, 0.f, 0.f, 0.f};

    for (int k0 = 0; k0 < KK; k0 += 64) {
        const bf16* Ab = A + (size_t)m0 * KK + k0;
        const bf16* Wb = W + (size_t)n0 * KK + k0;
        #pragma unroll
        for (int li = 0; li < 4; ++li) {
            int chunk = li * 256 + t;
            int r = chunk >> 3, c = chunk & 7;
            int cs = c ^ (r & 7);
            async_lds16(Ab + (size_t)r * KK + (cs << 3),
                        &As[(li * 256 + w * 64) << 3]);
        }
        #pragma unroll
        for (int li = 0; li < 2; ++li) {
            int chunk = li * 256 + t;
            int r = chunk >> 3, c = chunk & 7;
            int cs = c ^ (r & 7);
            async_lds16(Wb + (size_t)r * KK + (cs << 3),
                        &Bs[(li * 256 + w * 64) << 3]);
        }
        __syncthreads();
        #pragma unroll
        for (int kf = 0; kf < 2; ++kf) {
            short8 a_[2], b_[4];
            #pragma unroll
            for (int mi = 0; mi < 2; ++mi) {
                int row = (w << 5) + (mi << 4) + lr;
                a_[mi] = *reinterpret_cast<const short8*>(
                    &As[(row << 6) + ((((kf << 2) + lg) ^ (row & 7)) << 3)]);
            }
            #pragma unroll
            for (int ni = 0; ni < 4; ++ni) {
                int rn = (ni << 4) + lr;
                b_[ni] = *reinterpret_cast<const short8*>(
                    &Bs[(rn << 6) + ((((kf << 2) + lg) ^ (rn & 7)) << 3)]);
            }
            #pragma unroll
            for (int mi = 0; mi < 2; ++mi)
                #pragma unroll
                for (int ni = 0; ni < 4; ++ni)
                    acc[mi][ni] = __builtin_amdgcn_mfma_f32_16x16x32_bf16(
                        a_[mi], b_[ni], acc[mi][ni], 0, 0, 0);
        }
        __syncthreads();
    }

    #pragma unroll
    for (int mi = 0; mi < 2; ++mi) {
        #pragma unroll
        for (int ni = 0; ni < 4; ++ni) {
            int col = n0 + (ni << 4) + lr;
            float bv = bias ? bias[col] : 0.f;
            #pragma unroll
            for (int r = 0; r < 4; ++r) {
                int row = m0 + (w << 5) + (mi << 4) + (lg << 2) + r;
                float c = acc[mi][ni][r] + bv;
                if (EPI == 1) c = gelu_exact(c);
                if (EPI == 2) {
                    int bidx = row / LL;
                    c += ldv(resid + (size_t)row * NN + col)
                       + b2f(xn2[(size_t)row * NN + col]) * gate[bidx * CC + col];
                }
                if (RESID) c += ldv(resid + (size_t)row * NN + col);
                stv(out + (size_t)row * NN + col, c);
            }
        }
    }
}

// ---------------- MFMA window attention v3: 4 waves/block, one (window,head)/wave ----
__global__ __launch_bounds__(256)
void winattn_kernel(const bf16* __restrict__ qkv, bf16* __restrict__ aw)
{
    __shared__ __align__(16) short Ps[4][64 * 40];
    __shared__ __align__(16) short Vt[4][32 * 72];

    const int w  = threadIdx.x >> 6;     // wave in block
    const int t  = threadIdx.x & 63;     // lane
    const int p  = blockIdx.x * 4 + w;   // 0..12287 pair index
    const int wi = p / 6;
    const int head = p - wi * 6;
    const int b  = wi >> 6;
    const int wr = wi & 63;
    const int wy = wr >> 3, wx = wr & 7;
    const int lc = t & 15;
    const int lg = t >> 4;
    const float scale = 0.1767766952966369f;   // 32^-0.5
    const bf16* qbase = qkv + (size_t)b * LL * C3 + head * HD;
    short* ps = Ps[w];
    short* vt = Vt[w];

    // zero pad vt cols 48..63
    #pragma unroll
    for (int e = t; e < 512; e += 64) {
        int r = e >> 4, c = 48 + (e & 15);
        vt[r * 72 + c] = 0;
    }
    // stage V transposed
    for (int e = t; e < 196; e += 64) {
        int tok = e >> 2, part = e & 3;
        int iy = tok / 7, ix = tok - iy * 7;
        size_t l = (size_t)(wy * 7 + iy) * 56 + wx * 7 + ix;
        uint4 pv = *reinterpret_cast<const uint4*>(qbase + l * C3 + 384 + (part << 3));
        unsigned short uv[8];
        *reinterpret_cast<uint4*>(uv) = pv;
        #pragma unroll
        for (int jj = 0; jj < 8; ++jj)
            vt[((part << 3) + jj) * 72 + tok] = (short)uv[jj];
    }

    // Q, K fragments direct from global (predicated)
    const short8 zero8 = {0, 0, 0, 0, 0, 0, 0, 0};
    short8 a_[4], b_[4];
    #pragma unroll
    for (int mi = 0; mi < 4; ++mi) {
        int tk = (mi << 4) + lc;
        a_[mi] = zero8;
        if (tk < 49) {
            int iy = tk / 7, ix = tk - iy * 7;
            size_t l = (size_t)(wy * 7 + iy) * 56 + wx * 7 + ix;
            a_[mi] = *reinterpret_cast<const short8*>(qbase + l * C3 + (lg << 3));
        }
    }
    #pragma unroll
    for (int ni = 0; ni < 4; ++ni) {
        int rn = (ni << 4) + lc;
        b_[ni] = zero8;
        if (rn < 49) {
            int iy = rn / 7, ix = rn - iy * 7;
            size_t l = (size_t)(wy * 7 + iy) * 56 + wx * 7 + ix;
            b_[ni] = *reinterpret_cast<const short8*>(qbase + l * C3 + 192 + (lg << 3));
        }
    }

    // S = Q K^T
    f32x4 acc[4][4];
    #pragma unroll
    for (int i = 0; i < 4; ++i)
        #pragma unroll
        for (int j = 0; j < 4; ++j)
            acc[i][j] = (f32x4){0.f, 0.f, 0.f, 0.f};
    #pragma unroll
    for (int mi = 0; mi < 4; ++mi)
        #pragma unroll
        for (int ni = 0; ni < 4; ++ni)
            acc[mi][ni] = __builtin_amdgcn_mfma_f32_16x16x32_bf16(
                a_[mi], b_[ni], acc[mi][ni], 0, 0, 0);

    // softmax over cols; C layout: row = mi*16 + lg*4 + r, col = ni*16 + lc.
    float rinv[4][4];
    #pragma unroll
    for (int mi = 0; mi < 4; ++mi) {
        #pragma unroll
        for (int r = 0; r < 4; ++r) {
            float mx = -1e30f;
            #pragma unroll
            for (int ni = 0; ni < 4; ++ni) {
                float v = acc[mi][ni][r];
                if (ni == 3 && lc != 0) v = -1e30f;
                mx = fmaxf(mx, v);
            }
            mx = fmaxf(mx, __shfl_xor(mx, 1, 64));
            mx = fmaxf(mx, __shfl_xor(mx, 2, 64));
            mx = fmaxf(mx, __shfl_xor(mx, 4, 64));
            mx = fmaxf(mx, __shfl_xor(mx, 8, 64));
            float sm = 0.f;
            int row = (mi << 4) + (lg << 2) + r;
            #pragma unroll
            for (int ni = 0; ni < 4; ++ni) {
                float e = (ni == 3 && lc != 0) ? 0.f
                        : __expf(scale * (acc[mi][ni][r] - mx));
                ps[row * 40 + (ni << 4) + lc] = f2bs(e);
                sm += e;
            }
            sm += __shfl_xor(sm, 1, 64);
            sm += __shfl_xor(sm, 2, 64);
            sm += __shfl_xor(sm, 4, 64);
            sm += __shfl_xor(sm, 8, 64);
            rinv[mi][r] = 1.0f / sm;
        }
    }

    // O = P V
    f32x4 o[4][2];
    #pragma unroll
    for (int i = 0; i < 4; ++i) {
        o[i][0] = (f32x4){0.f, 0.f, 0.f, 0.f};
        o[i][1] = (f32x4){0.f, 0.f, 0.f, 0.f};
    }
    #pragma unroll
    for (int kf = 0; kf < 2; ++kf) {
        short8 pa[4], vb[2];
        #pragma unroll
        for (int mi = 0; mi < 4; ++mi)
            pa[mi] = *reinterpret_cast<const short8*>(
                &ps[((mi << 4) + lc) * 40 + (kf << 5) + (lg << 3)]);
        #pragma unroll
        for (int n2 = 0; n2 < 2; ++n2)
            vb[n2] = *reinterpret_cast<const short8*>(
                &vt[((n2 << 4) + lc) * 72 + (kf << 5) + (lg << 3)]);
        #pragma unroll
        for (int mi = 0; mi < 4; ++mi)
            #pragma unroll
            for (int n2 = 0; n2 < 2; ++n2)
                o[mi][n2] = __builtin_amdgcn_mfma_f32_16x16x32_bf16(
                    pa[mi], vb[n2], o[mi][n2], 0, 0, 0);
    }

    // normalized O -> ps, then coalesced 16B stores
    #pragma unroll
    for (int mi = 0; mi < 4; ++mi) {
        #pragma unroll
        for (int r = 0; r < 4; ++r) {
            int row = (mi << 4) + (lg << 2) + r;
            float inv = rinv[mi][r];
            ps[row * 40 + lc]      = f2bs(o[mi][0][r] * inv);
            ps[row * 40 + 16 + lc] = f2bs(o[mi][1][r] * inv);
        }
    }
    for (int e = t; e < 196; e += 64) {
        int tok = e >> 2, part = e & 3;
        int iy = tok / 7, ix = tok - iy * 7;
        size_t l = (size_t)(wy * 7 + iy) * 56 + wx * 7 + ix;
        *reinterpret_cast<uint4*>(aw + ((size_t)b * LL + l) * CC + head * HD + (part << 3)) =
            *reinterpret_cast<const uint4*>(&ps[tok * 40 + (part << 3)]);
    }
}

// ---------------- Depthwise 3x3 (SAME) + exact GELU, vectorized 8-ch/thread ----------
__global__ __launch_bounds__(256)
void dwconv_kernel(const bf16* __restrict__ xn, const float* __restrict__ w,
                   bf16* __restrict__ out)
{
    __shared__ float wl[9 * 288];
    const int t = threadIdx.x;
    for (int i = t; i < CC * 9; i += 256) {
        int c = i / 9, k = i - c * 9;
        wl[k * 288 + (c >> 3) * 12 + (c & 7)] = w[i];
    }
    __syncthreads();
    int e = blockIdx.x * 256 + t;          // 0 .. MM*24-1 (exact grid)
    int cg = e % 24;
    int pix = e / 24;
    int w_ = pix % WW;
    int t2 = pix / WW;
    int h_ = t2 % HH;
    int b  = t2 / HH;
    float acc[8] = {0.f,0.f,0.f,0.f,0.f,0.f,0.f,0.f};
    const bf16* rowbase = xn + ((size_t)b * HH * WW) * CC + (size_t)cg * 8;
    #pragma unroll
    for (int ky = 0; ky < 3; ++ky) {
        int hy = h_ + ky - 1;
        if (hy < 0 || hy >= HH) continue;
        #pragma unroll
        for (int kx = 0; kx < 3; ++kx) {
            int wx_ = w_ + kx - 1;
            if (wx_ < 0 || wx_ >= WW) continue;
            int k = ky * 3 + kx;
            const float4* wp = reinterpret_cast<const float4*>(&wl[k * 288 + cg * 12]);
            float4 w0 = wp[0];
            float4 w1 = wp[1];
            unsigned short u[8];
            *reinterpret_cast<uint4*>(u) = *reinterpret_cast<const uint4*>(
                rowbase + ((size_t)hy * WW + wx_) * CC);
            acc[0] += us2f(u[0]) * w0.x;
            acc[1] += us2f(u[1]) * w0.y;
            acc[2] += us2f(u[2]) * w0.z;
            acc[3] += us2f(u[3]) * w0.w;
            acc[4] += us2f(u[4]) * w1.x;
            acc[5] += us2f(u[5]) * w1.y;
            acc[6] += us2f(u[6]) * w1.z;
            acc[7] += us2f(u[7]) * w1.w;
        }
    }
    bf16 o8[8];
    #pragma unroll
    for (int j = 0; j < 8; ++j) o8[j] = f2b(gelu_exact(acc[j]));
    *reinterpret_cast<uint4*>(out + (size_t)e * 8) = *reinterpret_cast<uint4*>(o8);
}

// ---------------- column (spatial) sum of xn per (b, c) ----------------
__global__ __launch_bounds__(192)
void colsum_kernel(const bf16* __restrict__ xn, float* __restrict__ colsum)
{
    int b = blockIdx.y, g = blockIdx.x, c = threadIdx.x;
    float acc = 0.f;
    int l0 = g * 196;
    for (int l = l0; l < l0 + 196; ++l)
        acc += b2f(xn[((size_t)b * LL + l) * CC + c]);
    atomicAdd(&colsum[b * CC + c], acc);
}

__global__ __launch_bounds__(192)
void gate_kernel(const float* __restrict__ colsum, const float* __restrict__ gw,
                 const float* __restrict__ gb, float* __restrict__ gate)
{
    __shared__ float cm[CC];
    int b = blockIdx.x, o = threadIdx.x;
    cm[o] = colsum[b * CC + o] * (1.0f / LL);
    __syncthreads();
    float acc = gb[o];
    for (int c = 0; c < CC; ++c) acc += gw[o * CC + c] * cm[c];
    gate[b * CC + o] = 1.0f / (1.0f + expf(-acc));
}

// ---------------- means over H and W in one launch, vec8, bf16 out ----------------
__global__ __launch_bounds__(256)
void means_kernel(const bf16* __restrict__ xf, bf16* __restrict__ mh,
                  bf16* __restrict__ mw)
{
    int e = blockIdx.x * 256 + threadIdx.x;
    const int NHALF = BB * WW * 24;   // == BB*HH*24
    if (e < NHALF) {
        int cg = e % 24, c0 = cg << 3;
        int w_ = (e / 24) % WW;
        int b  = e / (24 * WW);
        float s[8] = {0.f,0.f,0.f,0.f,0.f,0.f,0.f,0.f};
        const bf16* base = xf + ((size_t)b * HH * WW + w_) * CC + c0;
        for (int h_ = 0; h_ < HH; ++h_) {
            unsigned short u[8];
            *reinterpret_cast<uint4*>(u) = *reinterpret_cast<const uint4*>(base + (size_t)h_ * WW * CC);
            #pragma unroll
            for (int j = 0; j < 8; ++j) s[j] += us2f(u[j]);
        }
        bf16 o8[8];
        #pragma unroll
        for (int j = 0; j < 8; ++j) o8[j] = f2b(s[j] * (1.0f / HH));
        *reinterpret_cast<uint4*>(mh + ((size_t)b * WW + w_) * CC + c0) =
            *reinterpret_cast<uint4*>(o8);
    } else {
        e -= NHALF;
        int cg = e % 24, c0 = cg << 3;
        int h_ = (e / 24) % HH;
        int b  = e / (24 * HH);
        float s[8] = {0.f,0.f,0.f,0.f,0.f,0.f,0.f,0.f};
        const bf16* base = xf + ((size_t)b * HH + h_) * WW * CC + c0;
        for (int w_ = 0; w_ < WW; ++w_) {
            unsigned short u[8];
            *reinterpret_cast<uint4*>(u) = *reinterpret_cast<const uint4*>(base + (size_t)w_ * CC);
            #pragma unroll
            for (int j = 0; j < 8; ++j) s[j] += us2f(u[j]);
        }
        bf16 o8[8];
        #pragma unroll
        for (int j = 0; j < 8; ++j) o8[j] = f2b(s[j] * (1.0f / WW));
        *reinterpret_cast<uint4*>(mw + ((size_t)b * HH + h_) * CC + c0) =
            *reinterpret_cast<uint4*>(o8);
    }
}

// ---------------- MFMA axis softmax: logits[o][pos] = W[o,:] . mean[b][pos,:] -------
// One block (4 waves) per (b, axis); wave w handles o-tiles w*3..w*3+2.
// Per-o bias cancels under softmax over pos (constant along softmax axis) -> dropped.
// Output f32 TRANSPOSED [b][pos][CC].
__global__ __launch_bounds__(256)
void axmfma_kernel(const bf16* __restrict__ mh, const bf16* __restrict__ wt,
                   float* __restrict__ at,
                   const bf16* __restrict__ mw, const bf16* __restrict__ ws,
                   float* __restrict__ as_)
{
    const int b = blockIdx.x;
    const bf16* mean; const bf16* wmat; float* out;
    if (blockIdx.y == 0) { mean = mh; wmat = wt; out = at; }
    else                 { mean = mw; wmat = ws; out = as_; }
    const int w  = threadIdx.x >> 6;
    const int t  = threadIdx.x & 63;
    const int lc = t & 15, lg = t >> 4;
    const bf16* mb = mean + (size_t)b * 56 * CC;
    const short8 zero8 = {0, 0, 0, 0, 0, 0, 0, 0};

    f32x4 acc[3][4];
    #pragma unroll
    for (int i = 0; i < 3; ++i)
        #pragma unroll
        for (int j = 0; j < 4; ++j)
            acc[i][j] = (f32x4){0.f, 0.f, 0.f, 0.f};

    #pragma unroll
    for (int kf = 0; kf < 6; ++kf) {
        short8 a_[3], b_[4];
        #pragma unroll
        for (int mi = 0; mi < 3; ++mi) {
            int o = ((w * 3 + mi) << 4) + lc;
            a_[mi] = *reinterpret_cast<const short8*>(wmat + (size_t)o * CC + (kf << 5) + (lg << 3));
        }
        #pragma unroll
        for (int ni = 0; ni < 4; ++ni) {
            int pos = (ni << 4) + lc;
            b_[ni] = (pos < 56)
                ? *reinterpret_cast<const short8*>(mb + (size_t)pos * CC + (kf << 5) + (lg << 3))
                : zero8;
        }
        #pragma unroll
        for (int mi = 0; mi < 3; ++mi)
            #pragma unroll
            for (int ni = 0; ni < 4; ++ni)
                acc[mi][ni] = __builtin_amdgcn_mfma_f32_16x16x32_bf16(
                    a_[mi], b_[ni], acc[mi][ni], 0, 0, 0);
    }

    // softmax over pos (cols): row o = (w*3+mi)*16 + lg*4 + r, col pos = ni*16 + lc.
    // invalid pos: ni==3 && lc>=8 (pos >= 56).
    #pragma unroll
    for (int mi = 0; mi < 3; ++mi) {
        #pragma unroll
        for (int r = 0; r < 4; ++r) {
            float mx = -1e30f;
            #pragma unroll
            for (int ni = 0; ni < 4; ++ni) {
                float v = acc[mi][ni][r];
                if (ni == 3 && lc >= 8) v = -1e30f;
                mx = fmaxf(mx, v);
            }
            mx = fmaxf(mx, __shfl_xor(mx, 1, 64));
            mx = fmaxf(mx, __shfl_xor(mx, 2, 64));
            mx = fmaxf(mx, __shfl_xor(mx, 4, 64));
            mx = fmaxf(mx, __shfl_xor(mx, 8, 64));
            float e[4];
            float sm = 0.f;
            #pragma unroll
            for (int ni = 0; ni < 4; ++ni) {
                e[ni] = (ni == 3 && lc >= 8) ? 0.f : __expf(acc[mi][ni][r] - mx);
                sm += e[ni];
            }
            sm += __shfl_xor(sm, 1, 64);
            sm += __shfl_xor(sm, 2, 64);
            sm += __shfl_xor(sm, 4, 64);
            sm += __shfl_xor(sm, 8, 64);
            float inv = 1.0f / sm;
            int o = ((w * 3 + mi) << 4) + (lg << 2) + r;
            #pragma unroll
            for (int ni = 0; ni < 4; ++ni) {
                int pos = (ni << 4) + lc;
                if (pos < 56)
                    out[((size_t)b * 56 + pos) * CC + o] = e[ni] * inv;
            }
        }
    }
}

// ---------------- xf2 = xf * a_s[b,h,c] * a_t[b,w,c] * 2  (vec8, coalesced) ----------
__global__ __launch_bounds__(256)
void modulate_kernel(const bf16* __restrict__ xf, const float* __restrict__ a_s,
                     const float* __restrict__ a_t, bf16* __restrict__ xf2)
{
    int e = blockIdx.x * 256 + threadIdx.x;    // 0 .. MM*24-1
    int cg = e % 24, c0 = cg << 3;
    int pix = e / 24;
    int w_ = pix % WW;
    int t2 = pix / WW;
    int h_ = t2 % HH;
    int b  = t2 / HH;
    unsigned short u[8];
    size_t base = (size_t)e * 8;
    *reinterpret_cast<uint4*>(u) = *reinterpret_cast<const uint4*>(xf + base);
    const float4* sp = reinterpret_cast<const float4*>(a_s + ((size_t)b * 56 + h_) * CC + c0);
    const float4* tp = reinterpret_cast<const float4*>(a_t + ((size_t)b * 56 + w_) * CC + c0);
    float4 s0 = sp[0], s1 = sp[1];
    float4 t0 = tp[0], t1 = tp[1];
    float ss[8] = {s0.x, s0.y, s0.z, s0.w, s1.x, s1.y, s1.z, s1.w};
    float tt[8] = {t0.x, t0.y, t0.z, t0.w, t1.x, t1.y, t1.z, t1.w};
    bf16 o8[8];
    #pragma unroll
    for (int j = 0; j < 8; ++j)
        o8[j] = f2b(us2f(u[j]) * ss[j] * tt[j] * 2.0f);
    *reinterpret_cast<uint4*>(xf2 + base) = *reinterpret_cast<uint4*>(o8);
}

// =======================================================================================
extern "C" void kernel_launch(void* const* d_in, const int* in_sizes, int n_in,
                              void* d_out, int out_size, void* d_ws, size_t ws_size,
                              hipStream_t stream)
{
    const float* x      = (const float*)d_in[0];
    const float* ln1_g  = (const float*)d_in[3];
    const float* ln1_b  = (const float*)d_in[4];
    const float* qkv_w  = (const float*)d_in[5];
    const float* qkv_b  = (const float*)d_in[6];
    const float* proj_w = (const float*)d_in[7];
    const float* proj_b = (const float*)d_in[8];
    const float* dw_w   = (const float*)d_in[9];
    const float* pw_w   = (const float*)d_in[10];
    const float* gate_w = (const float*)d_in[11];
    const float* gate_b = (const float*)d_in[12];
    const float* temp_w = (const float*)d_in[13];
    const float* spec_w = (const float*)d_in[15];
    const float* fuse_w = (const float*)d_in[17];
    const float* ln2_g  = (const float*)d_in[18];
    const float* ln2_b  = (const float*)d_in[19];
    const float* mlp1_w = (const float*)d_in[20];
    const float* mlp1_b = (const float*)d_in[21];
    const float* mlp2_w = (const float*)d_in[22];
    const float* mlp2_b = (const float*)d_in[23];
    float* out = (float*)d_out;

    const size_t SLOT = (size_t)MM * CC * sizeof(bf16);   // 38,535,168 B
    char* ws = (char*)d_ws;

    bf16* s_xn    = (bf16*)(ws);
    bf16* s_qkv   = (bf16*)(ws + SLOT);        // 3 slots
    bf16* s_aw    = (bf16*)(ws + 4 * SLOT);
    bf16* s_xattn = (bf16*)(ws + SLOT);        // reuse qkv slot 1
    bf16* s_dwg   = (bf16*)(ws + 2 * SLOT);
    bf16* s_xf    = (bf16*)(ws + 4 * SLOT);    // reuse aw (combine fused into pw gemm)
    bf16* s_xf2   = (bf16*)(ws + 3 * SLOT);
    bf16* s_x2    = (bf16*)(ws);               // reuse xn (xn dead after pw+combine)
    bf16* s_hn    = (bf16*)(ws + 2 * SLOT);
    bf16* s_h1    = (bf16*)(ws + 3 * SLOT);    // spans slots 3..4 (384 ch)

    float* colsum  = (float*)(ws + 5 * SLOT);
    float* gatebuf = colsum + BB * CC;
    bf16*  mean_h  = (bf16*)(gatebuf + BB * CC);
    bf16*  mean_w  = mean_h + (size_t)BB * 56 * CC;
    float* a_t     = (float*)(mean_w + (size_t)BB * 56 * CC);
    float* a_s     = a_t + (size_t)BB * CC * 56;
    // bf16 weight copies
    bf16* wb_qkv  = (bf16*)(a_s + (size_t)BB * CC * 56);
    bf16* wb_proj = wb_qkv  + C3 * CC;
    bf16* wb_pw   = wb_proj + CC * CC;
    bf16* wb_fuse = wb_pw   + CC * CC;
    bf16* wb_mlp1 = wb_fuse + CC * CC;
    bf16* wb_mlp2 = wb_mlp1 + HIDN * CC;
    bf16* wb_temp = wb_mlp2 + CC * HIDN;
    bf16* wb_spec = wb_temp + CC * CC;
    char* after_w = (char*)(wb_spec + CC * CC);
    size_t total_need = after_w - ws;
    if (ws_size < total_need) return;   // workspace insufficient — visible failure
    // optional bf16 copy of x (saves 115 MB of f32 resid traffic in fuse GEMM)
    bf16* s_xb = (bf16*)after_w;
    bool have_xb = (ws_size >= total_need + SLOT);

    const int VEC_BLOCKS = MM * 24 / 256;   // 9408, exact
    const int CVT_N0 = C3 * CC, CVT_N1 = CC * CC, CVT_N4 = HIDN * CC;
    const int CVT_TOTAL = CVT_N0 + 5 * CVT_N1 + 2 * CVT_N4;

    // 0. all weight conversions in one launch
    cvt8_kernel<<<(CVT_TOTAL + 255) / 256, 256, 0, stream>>>(
        qkv_w, wb_qkv, CVT_N0, proj_w, wb_proj, CVT_N1, pw_w, wb_pw, CVT_N1,
        fuse_w, wb_fuse, CVT_N1, mlp1_w, wb_mlp1, CVT_N4, mlp2_w, wb_mlp2, CVT_N4,
        temp_w, wb_temp, CVT_N1, spec_w, wb_spec, CVT_N1);

    // 1. LN1 (+ optional bf16 x copy)
    ln_kernel<float><<<MM / 4, 256, 0, stream>>>(x, ln1_g, ln1_b, s_xn,
                                                 have_xb ? s_xb : nullptr);
    // 2. qkv
    mfma_gemm<0, false, C3, CC, bf16, bf16><<<dim3(C3 / 64, MM / 128), 256, 0, stream>>>(
        s_xn, wb_qkv, qkv_b, (const bf16*)nullptr, s_qkv, nullptr, nullptr);
    // 3. window attention (4 waves/block, one (window,head)/wave)
    winattn_kernel<<<NWIN * NHEAD / 4, 256, 0, stream>>>(s_qkv, s_aw);
    // 4. proj
    mfma_gemm<0, false, CC, CC, bf16, bf16><<<dim3(CC / 64, MM / 128), 256, 0, stream>>>(
        s_aw, wb_proj, proj_b, (const bf16*)nullptr, s_xattn, nullptr, nullptr);
    // 5. depthwise + gelu (vec8)
    dwconv_kernel<<<VEC_BLOCKS, 256, 0, stream>>>(s_xn, dw_w, s_dwg);
    // 6. gate (needs only xn)
    hipMemsetAsync(colsum, 0, BB * CC * sizeof(float), stream);
    colsum_kernel<<<dim3(16, BB), 192, 0, stream>>>(s_xn, colsum);
    gate_kernel<<<BB, 192, 0, stream>>>(colsum, gate_w, gate_b, gatebuf);
    // 7. pointwise + fused combine: xf = dwg@pw^T + xattn + xn*gate
    mfma_gemm<2, false, CC, CC, bf16, bf16><<<dim3(CC / 64, MM / 128), 256, 0, stream>>>(
        s_dwg, wb_pw, (const float*)nullptr, s_xattn, s_xf, s_xn, gatebuf);
    // 8. axis means (one launch, bf16 out)
    means_kernel<<<(2 * BB * WW * 24) / 256, 256, 0, stream>>>(s_xf, mean_h, mean_w);
    // 9. both axis softmaxes via MFMA (bias cancels under softmax)
    axmfma_kernel<<<dim3(BB, 2), 256, 0, stream>>>(
        mean_h, wb_temp, a_t, mean_w, wb_spec, a_s);
    // 10. modulate (coalesced)
    modulate_kernel<<<VEC_BLOCKS, 256, 0, stream>>>(s_xf, a_s, a_t, s_xf2);
    // 11. fuse (no bias) + residual x -> x2 (bf16 resid if workspace allows)
    if (have_xb)
        mfma_gemm<0, true, CC, CC, bf16, bf16><<<dim3(CC / 64, MM / 128), 256, 0, stream>>>(
            s_xf2, wb_fuse, (const float*)nullptr, s_xb, s_x2, nullptr, nullptr);
    else
        mfma_gemm<0, true, CC, CC, float, bf16><<<dim3(CC / 64, MM / 128), 256, 0, stream>>>(
            s_xf2, wb_fuse, (const float*)nullptr, x, s_x2, nullptr, nullptr);
    // 12. LN2
    ln_kernel<bf16><<<MM / 4, 256, 0, stream>>>(s_x2, ln2_g, ln2_b, s_hn, nullptr);
    // 13. MLP1 + gelu
    mfma_gemm<1, false, HIDN, CC, bf16, bf16><<<dim3(HIDN / 64, MM / 128), 256, 0, stream>>>(
        s_hn, wb_mlp1, mlp1_b, (const bf16*)nullptr, s_h1, nullptr, nullptr);
    // 14. MLP2 + residual -> out (f32)
    mfma_gemm<0, true, CC, HIDN, bf16, float><<<dim3(CC / 64, MM / 128), 256, 0, stream>>>(
        s_h1, wb_mlp2, mlp2_b, s_x2, out, nullptr, nullptr);
}

// Round 11
// 374.637 us; speedup vs baseline: 4.5236x; 1.0456x over previous
//
#include <hip/hip_runtime.h>
#include <hip/hip_bf16.h>

typedef __hip_bfloat16 bf16;

// Problem constants (B=32, H=W=56, C=192, NH=6, WS=7)
#define BB 32
#define HH 56
#define WW 56
#define CC 192
#define LL 3136            // 56*56
#define MM (BB*LL)         // 100352 tokens
#define C3 576
#define HIDN 384
#define NHEAD 6
#define HD 32
#define NWIN 2048          // B * 8*8

typedef short short8 __attribute__((ext_vector_type(8)));
typedef float f32x4 __attribute__((ext_vector_type(4)));

__device__ __forceinline__ float us2f(unsigned short u) {
    union { unsigned int i; float f; } v; v.i = ((unsigned int)u) << 16; return v.f;
}
__device__ __forceinline__ float b2f(bf16 h) { return __bfloat162float(h); }
__device__ __forceinline__ bf16 f2b(float f) { return __float2bfloat16(f); }
__device__ __forceinline__ short f2bs(float f) { bf16 h = f2b(f); return *reinterpret_cast<short*>(&h); }
__device__ __forceinline__ unsigned pk2(float a, float b) {
    return (unsigned)(unsigned short)f2bs(a) | ((unsigned)(unsigned short)f2bs(b) << 16);
}
__device__ __forceinline__ float ldv(const bf16* p) { return b2f(*p); }
__device__ __forceinline__ float ldv(const float* p) { return *p; }
__device__ __forceinline__ void stv(bf16* p, float v) { *p = f2b(v); }
__device__ __forceinline__ void stv(float* p, float v) { *p = v; }
__device__ __forceinline__ float gelu_exact(float x) {
    return 0.5f * x * (1.0f + erff(x * 0.70710678118654752f));
}
__device__ __forceinline__ void async_lds16(const void* g, void* l) {
    __builtin_amdgcn_global_load_lds(
        (const __attribute__((address_space(1))) void*)g,
        (__attribute__((address_space(3))) void*)l, 16, 0, 0);
}

// ---------------- f32 -> bf16 conversion of all 8 weight matrices in one launch ------
__global__ __launch_bounds__(256)
void cvt8_kernel(const float* __restrict__ s0, bf16* __restrict__ d0, int n0,
                 const float* __restrict__ s1, bf16* __restrict__ d1, int n1,
                 const float* __restrict__ s2, bf16* __restrict__ d2, int n2,
                 const float* __restrict__ s3, bf16* __restrict__ d3, int n3,
                 const float* __restrict__ s4, bf16* __restrict__ d4, int n4,
                 const float* __restrict__ s5, bf16* __restrict__ d5, int n5,
                 const float* __restrict__ s6, bf16* __restrict__ d6, int n6,
                 const float* __restrict__ s7, bf16* __restrict__ d7, int n7)
{
    int i = blockIdx.x * 256 + threadIdx.x;
    if (i < n0) { d0[i] = f2b(s0[i]); return; } i -= n0;
    if (i < n1) { d1[i] = f2b(s1[i]); return; } i -= n1;
    if (i < n2) { d2[i] = f2b(s2[i]); return; } i -= n2;
    if (i < n3) { d3[i] = f2b(s3[i]); return; } i -= n3;
    if (i < n4) { d4[i] = f2b(s4[i]); return; } i -= n4;
    if (i < n5) { d5[i] = f2b(s5[i]); return; } i -= n5;
    if (i < n6) { d6[i] = f2b(s6[i]); return; } i -= n6;
    if (i < n7) { d7[i] = f2b(s7[i]); }
}

// ---------------- LayerNorm: one wave per row; optionally also emit bf16 copy of in --
template<typename IT>
__global__ __launch_bounds__(256)
void ln_kernel(const IT* __restrict__ in, const float* __restrict__ g,
               const float* __restrict__ bvec, bf16* __restrict__ out,
               bf16* __restrict__ xcopy)
{
    int wid = threadIdx.x >> 6, lane = threadIdx.x & 63;
    int row = blockIdx.x * 4 + wid;
    const IT* p = in + (size_t)row * CC;
    float x0 = ldv(p + lane);
    float x1 = ldv(p + lane + 64);
    float x2 = ldv(p + lane + 128);
    float s  = x0 + x1 + x2;
    float sq = x0*x0 + x1*x1 + x2*x2;
    #pragma unroll
    for (int o = 32; o > 0; o >>= 1) {
        s  += __shfl_xor(s,  o, 64);
        sq += __shfl_xor(sq, o, 64);
    }
    float mean = s * (1.0f / CC);
    float var  = sq * (1.0f / CC) - mean * mean;
    float inv  = rsqrtf(fmaxf(var, 0.0f) + 1e-5f);
    bf16* q = out + (size_t)row * CC;
    q[lane]       = f2b((x0 - mean) * inv * g[lane]       + bvec[lane]);
    q[lane + 64]  = f2b((x1 - mean) * inv * g[lane + 64]  + bvec[lane + 64]);
    q[lane + 128] = f2b((x2 - mean) * inv * g[lane + 128] + bvec[lane + 128]);
    if (xcopy) {
        bf16* xq = xcopy + (size_t)row * CC;
        xq[lane]       = f2b(x0);
        xq[lane + 64]  = f2b(x1);
        xq[lane + 128] = f2b(x2);
    }
}

// ---------------- MFMA GEMM: out[M,NN] = epi(A[M,KK] @ W[NN,KK]^T + bias) ----
// EPI: 0=none, 1=gelu, 2=combine (out = acc + resid + b2f(xn2)*gate[b,c]).
// 256 threads = 4 waves, block tile 128x64, wave tile 32x64, BK=64.
// XCD-chunked block swizzle (bijective when nwg%8==0).
template<int EPI, bool RESID, int NN, int KK, typename RT, typename OT>
__global__ __launch_bounds__(256)
void mfma_gemm(const bf16* __restrict__ A, const bf16* __restrict__ W,
               const float* __restrict__ bias, const RT* __restrict__ resid,
               OT* __restrict__ out,
               const bf16* __restrict__ xn2, const float* __restrict__ gate)
{
    __shared__ __align__(16) short As[128 * 64];
    __shared__ __align__(16) short Bs[64 * 64];
    const int t    = threadIdx.x;
    const int lane = t & 63;
    const int w    = t >> 6;        // wave 0..3
    const int nx   = gridDim.x;
    const int nwg  = gridDim.x * gridDim.y;
    int hw  = blockIdx.y * nx + blockIdx.x;
    int wid = (nwg & 7) ? hw : ((hw & 7) * (nwg >> 3) + (hw >> 3));
    const int m0   = (wid / nx) * 128;
    const int n0   = (wid % nx) * 64;
    const int lr   = lane & 15;     // row within 16
    const int lg   = lane >> 4;     // k-group 0..3

    f32x4 acc[2][4];
    #pragma unroll
    for (int i = 0; i < 2; ++i)
        #pragma unroll
        for (int j = 0; j < 4; ++j)
            acc[i][j] = (f32x4){0.f, 0.f, 0.f, 0.f};

    for (int k0 = 0; k0 < KK; k0 += 64) {
        const bf16* Ab = A + (size_t)m0 * KK + k0;
        const bf16* Wb = W + (size_t)n0 * KK + k0;
        #pragma unroll
        for (int li = 0; li < 4; ++li) {
            int chunk = li * 256 + t;
            int r = chunk >> 3, c = chunk & 7;
            int cs = c ^ (r & 7);
            async_lds16(Ab + (size_t)r * KK + (cs << 3),
                        &As[(li * 256 + w * 64) << 3]);
        }
        #pragma unroll
        for (int li = 0; li < 2; ++li) {
            int chunk = li * 256 + t;
            int r = chunk >> 3, c = chunk & 7;
            int cs = c ^ (r & 7);
            async_lds16(Wb + (size_t)r * KK + (cs << 3),
                        &Bs[(li * 256 + w * 64) << 3]);
        }
        __syncthreads();
        #pragma unroll
        for (int kf = 0; kf < 2; ++kf) {
            short8 a_[2], b_[4];
            #pragma unroll
            for (int mi = 0; mi < 2; ++mi) {
                int row = (w << 5) + (mi << 4) + lr;
                a_[mi] = *reinterpret_cast<const short8*>(
                    &As[(row << 6) + ((((kf << 2) + lg) ^ (row & 7)) << 3)]);
            }
            #pragma unroll
            for (int ni = 0; ni < 4; ++ni) {
                int rn = (ni << 4) + lr;
                b_[ni] = *reinterpret_cast<const short8*>(
                    &Bs[(rn << 6) + ((((kf << 2) + lg) ^ (rn & 7)) << 3)]);
            }
            #pragma unroll
            for (int mi = 0; mi < 2; ++mi)
                #pragma unroll
                for (int ni = 0; ni < 4; ++ni)
                    acc[mi][ni] = __builtin_amdgcn_mfma_f32_16x16x32_bf16(
                        a_[mi], b_[ni], acc[mi][ni], 0, 0, 0);
        }
        __syncthreads();
    }

    #pragma unroll
    for (int mi = 0; mi < 2; ++mi) {
        #pragma unroll
        for (int ni = 0; ni < 4; ++ni) {
            int col = n0 + (ni << 4) + lr;
            float bv = bias ? bias[col] : 0.f;
            #pragma unroll
            for (int r = 0; r < 4; ++r) {
                int row = m0 + (w << 5) + (mi << 4) + (lg << 2) + r;
                float c = acc[mi][ni][r] + bv;
                if (EPI == 1) c = gelu_exact(c);
                if (EPI == 2) {
                    int bidx = row / LL;
                    c += ldv(resid + (size_t)row * NN + col)
                       + b2f(xn2[(size_t)row * NN + col]) * gate[bidx * CC + col];
                }
                if (RESID) c += ldv(resid + (size_t)row * NN + col);
                stv(out + (size_t)row * NN + col, c);
            }
        }
    }
}

// ---------------- MFMA window attention v4: swapped QK^T, P in registers -------------
// 4 waves/block, one (window,head)/wave, no barriers.
// S^T = mfma(A=K, B=Q): lane (lc,lg) holds P[key=mi*16+lg*4+r][tok=nj*16+lc].
// Softmax over keys: 12-val local reduce + shfl_xor(16,32). P->PV B-frag via
// pack+shfl (no LDS P buffer). LDS per wave: Vt[32][64] swizzled (4KB) unioned
// with Os[64][40] (5KB) => 20.5KB/block -> 8 blocks/CU.
__global__ __launch_bounds__(256)
void winattn_kernel(const bf16* __restrict__ qkv, bf16* __restrict__ aw)
{
    __shared__ __align__(16) short Buf[4][2560];

    const int w  = threadIdx.x >> 6;     // wave in block
    const int t  = threadIdx.x & 63;     // lane
    const int p  = blockIdx.x * 4 + w;   // pair index
    const int wi = p / 6;
    const int head = p - wi * 6;
    const int b  = wi >> 6;
    const int wr = wi & 63;
    const int wy = wr >> 3, wx = wr & 7;
    const int lc = t & 15;
    const int lg = t >> 4;
    const float scale = 0.1767766952966369f;   // 32^-0.5
    const bf16* qbase = qkv + (size_t)b * LL * C3 + head * HD;
    short* buf = Buf[w];

    // zero Vt region keys 48..63 (chunk-swizzled)
    #pragma unroll
    for (int e = t; e < 512; e += 64) {
        int d = e >> 4, k = 48 + (e & 15);
        buf[(d << 6) + (((k >> 3) ^ (d & 7)) << 3) + (k & 7)] = 0;
    }
    // stage V: Vt[d][k=tok], chunk-XOR swizzled, row stride 64 shorts
    for (int e = t; e < 196; e += 64) {
        int tok = e >> 2, part = e & 3;
        int iy = tok / 7, ix = tok - iy * 7;
        size_t l = (size_t)(wy * 7 + iy) * 56 + wx * 7 + ix;
        uint4 pv = *reinterpret_cast<const uint4*>(qbase + l * C3 + 384 + (part << 3));
        unsigned short uv[8];
        *reinterpret_cast<uint4*>(uv) = pv;
        #pragma unroll
        for (int jj = 0; jj < 8; ++jj) {
            int d = (part << 3) + jj;
            buf[(d << 6) + (((tok >> 3) ^ (d & 7)) << 3) + (tok & 7)] = (short)uv[jj];
        }
    }

    // K (A-frag) and Q (B-frag) direct from global (predicated)
    const short8 zero8 = {0, 0, 0, 0, 0, 0, 0, 0};
    short8 ka[4], qb[4];
    #pragma unroll
    for (int mi = 0; mi < 4; ++mi) {
        int key = (mi << 4) + lc;
        ka[mi] = zero8;
        if (key < 49) {
            int iy = key / 7, ix = key - iy * 7;
            size_t l = (size_t)(wy * 7 + iy) * 56 + wx * 7 + ix;
            ka[mi] = *reinterpret_cast<const short8*>(qbase + l * C3 + 192 + (lg << 3));
        }
    }
    #pragma unroll
    for (int nj = 0; nj < 4; ++nj) {
        int tok = (nj << 4) + lc;
        qb[nj] = zero8;
        if (tok < 49) {
            int iy = tok / 7, ix = tok - iy * 7;
            size_t l = (size_t)(wy * 7 + iy) * 56 + wx * 7 + ix;
            qb[nj] = *reinterpret_cast<const short8*>(qbase + l * C3 + (lg << 3));
        }
    }

    // S^T = K Q^T : acc[mi(key-tile)][nj(tok-tile)]
    f32x4 acc[4][4];
    #pragma unroll
    for (int i = 0; i < 4; ++i)
        #pragma unroll
        for (int j = 0; j < 4; ++j)
            acc[i][j] = (f32x4){0.f, 0.f, 0.f, 0.f};
    #pragma unroll
    for (int mi = 0; mi < 4; ++mi)
        #pragma unroll
        for (int nj = 0; nj < 4; ++nj)
            acc[mi][nj] = __builtin_amdgcn_mfma_f32_16x16x32_bf16(
                ka[mi], qb[nj], acc[mi][nj], 0, 0, 0);

    // softmax over keys (rows). keys mi<3 all valid; mi==3: only key 48 (lg==0,r==0).
    float rinv[4];
    #pragma unroll
    for (int nj = 0; nj < 4; ++nj) {
        float mx = acc[0][nj][0];
        #pragma unroll
        for (int mi = 0; mi < 3; ++mi)
            #pragma unroll
            for (int r = 0; r < 4; ++r)
                mx = fmaxf(mx, acc[mi][nj][r]);
        float v48 = (lg == 0) ? acc[3][nj][0] : -1e30f;
        mx = fmaxf(mx, v48);
        mx = fmaxf(mx, __shfl_xor(mx, 16, 64));
        mx = fmaxf(mx, __shfl_xor(mx, 32, 64));
        float sm = 0.f;
        #pragma unroll
        for (int mi = 0; mi < 3; ++mi)
            #pragma unroll
            for (int r = 0; r < 4; ++r) {
                float e = __expf(scale * (acc[mi][nj][r] - mx));
                acc[mi][nj][r] = e;
                sm += e;
            }
        float e48 = (lg == 0) ? __expf(scale * (acc[3][nj][0] - mx)) : 0.f;
        acc[3][nj][0] = e48; sm += e48;
        acc[3][nj][1] = 0.f; acc[3][nj][2] = 0.f; acc[3][nj][3] = 0.f;
        sm += __shfl_xor(sm, 16, 64);
        sm += __shfl_xor(sm, 32, 64);
        rinv[nj] = 1.0f / sm;
    }

    // O^T = V^T P^T : acc2[mi2(d-tile)][nj(tok-tile)]
    f32x4 acc2[2][4];
    #pragma unroll
    for (int i = 0; i < 2; ++i)
        #pragma unroll
        for (int j = 0; j < 4; ++j)
            acc2[i][j] = (f32x4){0.f, 0.f, 0.f, 0.f};
    const int src0 = ((lg & 1) << 5) + lc;
    const int src1 = src0 + 16;
    const bool hi = (lg >> 1) != 0;
    #pragma unroll
    for (int kf = 0; kf < 2; ++kf) {
        short8 av[2];
        #pragma unroll
        for (int mi2 = 0; mi2 < 2; ++mi2) {
            int d = (mi2 << 4) + lc;
            av[mi2] = *reinterpret_cast<const short8*>(
                &buf[(d << 6) + ((((kf << 2) + lg) ^ (d & 7)) << 3)]);
        }
        #pragma unroll
        for (int nj = 0; nj < 4; ++nj) {
            unsigned A0 = pk2(acc[2*kf][nj][0],   acc[2*kf][nj][1]);
            unsigned A1 = pk2(acc[2*kf][nj][2],   acc[2*kf][nj][3]);
            unsigned B0 = pk2(acc[2*kf+1][nj][0], acc[2*kf+1][nj][1]);
            unsigned B1 = pk2(acc[2*kf+1][nj][2], acc[2*kf+1][nj][3]);
            unsigned xa0 = __shfl(A0, src0, 64), xa1 = __shfl(A1, src0, 64);
            unsigned xa2 = __shfl(A0, src1, 64), xa3 = __shfl(A1, src1, 64);
            unsigned xb0 = __shfl(B0, src0, 64), xb1 = __shfl(B1, src0, 64);
            unsigned xb2 = __shfl(B0, src1, 64), xb3 = __shfl(B1, src1, 64);
            union { unsigned u[4]; short8 s; } ub;
            ub.u[0] = hi ? xb0 : xa0;
            ub.u[1] = hi ? xb1 : xa1;
            ub.u[2] = hi ? xb2 : xa2;
            ub.u[3] = hi ? xb3 : xa3;
            #pragma unroll
            for (int mi2 = 0; mi2 < 2; ++mi2)
                acc2[mi2][nj] = __builtin_amdgcn_mfma_f32_16x16x32_bf16(
                    av[mi2], ub.s, acc2[mi2][nj], 0, 0, 0);
        }
    }

    // normalized O -> Os[tok][d] (stride 40 shorts), then coalesced 16B stores.
    // (Os unions Vt's space; same-wave DS ops are in-order so Vt reads complete first.)
    #pragma unroll
    for (int mi2 = 0; mi2 < 2; ++mi2)
        #pragma unroll
        for (int nj = 0; nj < 4; ++nj) {
            int tokrow = (nj << 4) + lc;
            #pragma unroll
            for (int r = 0; r < 4; ++r) {
                int d = (mi2 << 4) + (lg << 2) + r;
                buf[tokrow * 40 + d] = f2bs(acc2[mi2][nj][r] * rinv[nj]);
            }
        }
    for (int e = t; e < 196; e += 64) {
        int tok = e >> 2, part = e & 3;
        int iy = tok / 7, ix = tok - iy * 7;
        size_t l = (size_t)(wy * 7 + iy) * 56 + wx * 7 + ix;
        *reinterpret_cast<uint4*>(aw + ((size_t)b * LL + l) * CC + head * HD + (part << 3)) =
            *reinterpret_cast<const uint4*>(&buf[tok * 40 + (part << 3)]);
    }
}

// ---------------- Depthwise 3x3 (SAME) + exact GELU, vectorized 8-ch/thread ----------
__global__ __launch_bounds__(256)
void dwconv_kernel(const bf16* __restrict__ xn, const float* __restrict__ w,
                   bf16* __restrict__ out)
{
    __shared__ float wl[9 * 288];
    const int t = threadIdx.x;
    for (int i = t; i < CC * 9; i += 256) {
        int c = i / 9, k = i - c * 9;
        wl[k * 288 + (c >> 3) * 12 + (c & 7)] = w[i];
    }
    __syncthreads();
    int e = blockIdx.x * 256 + t;          // 0 .. MM*24-1 (exact grid)
    int cg = e % 24;
    int pix = e / 24;
    int w_ = pix % WW;
    int t2 = pix / WW;
    int h_ = t2 % HH;
    int b  = t2 / HH;
    float acc[8] = {0.f,0.f,0.f,0.f,0.f,0.f,0.f,0.f};
    const bf16* rowbase = xn + ((size_t)b * HH * WW) * CC + (size_t)cg * 8;
    #pragma unroll
    for (int ky = 0; ky < 3; ++ky) {
        int hy = h_ + ky - 1;
        if (hy < 0 || hy >= HH) continue;
        #pragma unroll
        for (int kx = 0; kx < 3; ++kx) {
            int wx_ = w_ + kx - 1;
            if (wx_ < 0 || wx_ >= WW) continue;
            int k = ky * 3 + kx;
            const float4* wp = reinterpret_cast<const float4*>(&wl[k * 288 + cg * 12]);
            float4 w0 = wp[0];
            float4 w1 = wp[1];
            unsigned short u[8];
            *reinterpret_cast<uint4*>(u) = *reinterpret_cast<const uint4*>(
                rowbase + ((size_t)hy * WW + wx_) * CC);
            acc[0] += us2f(u[0]) * w0.x;
            acc[1] += us2f(u[1]) * w0.y;
            acc[2] += us2f(u[2]) * w0.z;
            acc[3] += us2f(u[3]) * w0.w;
            acc[4] += us2f(u[4]) * w1.x;
            acc[5] += us2f(u[5]) * w1.y;
            acc[6] += us2f(u[6]) * w1.z;
            acc[7] += us2f(u[7]) * w1.w;
        }
    }
    bf16 o8[8];
    #pragma unroll
    for (int j = 0; j < 8; ++j) o8[j] = f2b(gelu_exact(acc[j]));
    *reinterpret_cast<uint4*>(out + (size_t)e * 8) = *reinterpret_cast<uint4*>(o8);
}

// ---------------- column (spatial) sum of xn per (b, c) ----------------
__global__ __launch_bounds__(192)
void colsum_kernel(const bf16* __restrict__ xn, float* __restrict__ colsum)
{
    int b = blockIdx.y, g = blockIdx.x, c = threadIdx.x;
    float acc = 0.f;
    int l0 = g * 196;
    for (int l = l0; l < l0 + 196; ++l)
        acc += b2f(xn[((size_t)b * LL + l) * CC + c]);
    atomicAdd(&colsum[b * CC + c], acc);
}

__global__ __launch_bounds__(192)
void gate_kernel(const float* __restrict__ colsum, const float* __restrict__ gw,
                 const float* __restrict__ gb, float* __restrict__ gate)
{
    __shared__ float cm[CC];
    int b = blockIdx.x, o = threadIdx.x;
    cm[o] = colsum[b * CC + o] * (1.0f / LL);
    __syncthreads();
    float acc = gb[o];
    for (int c = 0; c < CC; ++c) acc += gw[o * CC + c] * cm[c];
    gate[b * CC + o] = 1.0f / (1.0f + expf(-acc));
}

// ---------------- means over H and W in one launch, vec8, bf16 out ----------------
__global__ __launch_bounds__(256)
void means_kernel(const bf16* __restrict__ xf, bf16* __restrict__ mh,
                  bf16* __restrict__ mw)
{
    int e = blockIdx.x * 256 + threadIdx.x;
    const int NHALF = BB * WW * 24;   // == BB*HH*24
    if (e < NHALF) {
        int cg = e % 24, c0 = cg << 3;
        int w_ = (e / 24) % WW;
        int b  = e / (24 * WW);
        float s[8] = {0.f,0.f,0.f,0.f,0.f,0.f,0.f,0.f};
        const bf16* base = xf + ((size_t)b * HH * WW + w_) * CC + c0;
        for (int h_ = 0; h_ < HH; ++h_) {
            unsigned short u[8];
            *reinterpret_cast<uint4*>(u) = *reinterpret_cast<const uint4*>(base + (size_t)h_ * WW * CC);
            #pragma unroll
            for (int j = 0; j < 8; ++j) s[j] += us2f(u[j]);
        }
        bf16 o8[8];
        #pragma unroll
        for (int j = 0; j < 8; ++j) o8[j] = f2b(s[j] * (1.0f / HH));
        *reinterpret_cast<uint4*>(mh + ((size_t)b * WW + w_) * CC + c0) =
            *reinterpret_cast<uint4*>(o8);
    } else {
        e -= NHALF;
        int cg = e % 24, c0 = cg << 3;
        int h_ = (e / 24) % HH;
        int b  = e / (24 * HH);
        float s[8] = {0.f,0.f,0.f,0.f,0.f,0.f,0.f,0.f};
        const bf16* base = xf + ((size_t)b * HH + h_) * WW * CC + c0;
        for (int w_ = 0; w_ < WW; ++w_) {
            unsigned short u[8];
            *reinterpret_cast<uint4*>(u) = *reinterpret_cast<const uint4*>(base + (size_t)w_ * CC);
            #pragma unroll
            for (int j = 0; j < 8; ++j) s[j] += us2f(u[j]);
        }
        bf16 o8[8];
        #pragma unroll
        for (int j = 0; j < 8; ++j) o8[j] = f2b(s[j] * (1.0f / WW));
        *reinterpret_cast<uint4*>(mw + ((size_t)b * HH + h_) * CC + c0) =
            *reinterpret_cast<uint4*>(o8);
    }
}

// ---------------- MFMA axis softmax: logits[o][pos] = W[o,:] . mean[b][pos,:] -------
// One block (4 waves) per (b, axis); wave w handles o-tiles w*3..w*3+2.
// Per-o bias cancels under softmax over pos. Output f32 TRANSPOSED [b][pos][CC].
__global__ __launch_bounds__(256)
void axmfma_kernel(const bf16* __restrict__ mh, const bf16* __restrict__ wt,
                   float* __restrict__ at,
                   const bf16* __restrict__ mw, const bf16* __restrict__ ws,
                   float* __restrict__ as_)
{
    const int b = blockIdx.x;
    const bf16* mean; const bf16* wmat; float* out;
    if (blockIdx.y == 0) { mean = mh; wmat = wt; out = at; }
    else                 { mean = mw; wmat = ws; out = as_; }
    const int w  = threadIdx.x >> 6;
    const int t  = threadIdx.x & 63;
    const int lc = t & 15, lg = t >> 4;
    const bf16* mb = mean + (size_t)b * 56 * CC;
    const short8 zero8 = {0, 0, 0, 0, 0, 0, 0, 0};

    f32x4 acc[3][4];
    #pragma unroll
    for (int i = 0; i < 3; ++i)
        #pragma unroll
        for (int j = 0; j < 4; ++j)
            acc[i][j] = (f32x4){0.f, 0.f, 0.f, 0.f};

    #pragma unroll
    for (int kf = 0; kf < 6; ++kf) {
        short8 a_[3], b_[4];
        #pragma unroll
        for (int mi = 0; mi < 3; ++mi) {
            int o = ((w * 3 + mi) << 4) + lc;
            a_[mi] = *reinterpret_cast<const short8*>(wmat + (size_t)o * CC + (kf << 5) + (lg << 3));
        }
        #pragma unroll
        for (int ni = 0; ni < 4; ++ni) {
            int pos = (ni << 4) + lc;
            b_[ni] = (pos < 56)
                ? *reinterpret_cast<const short8*>(mb + (size_t)pos * CC + (kf << 5) + (lg << 3))
                : zero8;
        }
        #pragma unroll
        for (int mi = 0; mi < 3; ++mi)
            #pragma unroll
            for (int ni = 0; ni < 4; ++ni)
                acc[mi][ni] = __builtin_amdgcn_mfma_f32_16x16x32_bf16(
                    a_[mi], b_[ni], acc[mi][ni], 0, 0, 0);
    }

    #pragma unroll
    for (int mi = 0; mi < 3; ++mi) {
        #pragma unroll
        for (int r = 0; r < 4; ++r) {
            float mx = -1e30f;
            #pragma unroll
            for (int ni = 0; ni < 4; ++ni) {
                float v = acc[mi][ni][r];
                if (ni == 3 && lc >= 8) v = -1e30f;
                mx = fmaxf(mx, v);
            }
            mx = fmaxf(mx, __shfl_xor(mx, 1, 64));
            mx = fmaxf(mx, __shfl_xor(mx, 2, 64));
            mx = fmaxf(mx, __shfl_xor(mx, 4, 64));
            mx = fmaxf(mx, __shfl_xor(mx, 8, 64));
            float e[4];
            float sm = 0.f;
            #pragma unroll
            for (int ni = 0; ni < 4; ++ni) {
                e[ni] = (ni == 3 && lc >= 8) ? 0.f : __expf(acc[mi][ni][r] - mx);
                sm += e[ni];
            }
            sm += __shfl_xor(sm, 1, 64);
            sm += __shfl_xor(sm, 2, 64);
            sm += __shfl_xor(sm, 4, 64);
            sm += __shfl_xor(sm, 8, 64);
            float inv = 1.0f / sm;
            int o = ((w * 3 + mi) << 4) + (lg << 2) + r;
            #pragma unroll
            for (int ni = 0; ni < 4; ++ni) {
                int pos = (ni << 4) + lc;
                if (pos < 56)
                    out[((size_t)b * 56 + pos) * CC + o] = e[ni] * inv;
            }
        }
    }
}

// ---------------- xf2 = xf * a_s[b,h,c] * a_t[b,w,c] * 2  (vec8, coalesced) ----------
__global__ __launch_bounds__(256)
void modulate_kernel(const bf16* __restrict__ xf, const float* __restrict__ a_s,
                     const float* __restrict__ a_t, bf16* __restrict__ xf2)
{
    int e = blockIdx.x * 256 + threadIdx.x;    // 0 .. MM*24-1
    int cg = e % 24, c0 = cg << 3;
    int pix = e / 24;
    int w_ = pix % WW;
    int t2 = pix / WW;
    int h_ = t2 % HH;
    int b  = t2 / HH;
    unsigned short u[8];
    size_t base = (size_t)e * 8;
    *reinterpret_cast<uint4*>(u) = *reinterpret_cast<const uint4*>(xf + base);
    const float4* sp = reinterpret_cast<const float4*>(a_s + ((size_t)b * 56 + h_) * CC + c0);
    const float4* tp = reinterpret_cast<const float4*>(a_t + ((size_t)b * 56 + w_) * CC + c0);
    float4 s0 = sp[0], s1 = sp[1];
    float4 t0 = tp[0], t1 = tp[1];
    float ss[8] = {s0.x, s0.y, s0.z, s0.w, s1.x, s1.y, s1.z, s1.w};
    float tt[8] = {t0.x, t0.y, t0.z, t0.w, t1.x, t1.y, t1.z, t1.w};
    bf16 o8[8];
    #pragma unroll
    for (int j = 0; j < 8; ++j)
        o8[j] = f2b(us2f(u[j]) * ss[j] * tt[j] * 2.0f);
    *reinterpret_cast<uint4*>(xf2 + base) = *reinterpret_cast<uint4*>(o8);
}

// =======================================================================================
extern "C" void kernel_launch(void* const* d_in, const int* in_sizes, int n_in,
                              void* d_out, int out_size, void* d_ws, size_t ws_size,
                              hipStream_t stream)
{
    const float* x      = (const float*)d_in[0];
    const float* ln1_g  = (const float*)d_in[3];
    const float* ln1_b  = (const float*)d_in[4];
    const float* qkv_w  = (const float*)d_in[5];
    const float* qkv_b  = (const float*)d_in[6];
    const float* proj_w = (const float*)d_in[7];
    const float* proj_b = (const float*)d_in[8];
    const float* dw_w   = (const float*)d_in[9];
    const float* pw_w   = (const float*)d_in[10];
    const float* gate_w = (const float*)d_in[11];
    const float* gate_b = (const float*)d_in[12];
    const float* temp_w = (const float*)d_in[13];
    const float* spec_w = (const float*)d_in[15];
    const float* fuse_w = (const float*)d_in[17];
    const float* ln2_g  = (const float*)d_in[18];
    const float* ln2_b  = (const float*)d_in[19];
    const float* mlp1_w = (const float*)d_in[20];
    const float* mlp1_b = (const float*)d_in[21];
    const float* mlp2_w = (const float*)d_in[22];
    const float* mlp2_b = (const float*)d_in[23];
    float* out = (float*)d_out;

    const size_t SLOT = (size_t)MM * CC * sizeof(bf16);   // 38,535,168 B
    char* ws = (char*)d_ws;

    bf16* s_xn    = (bf16*)(ws);
    bf16* s_qkv   = (bf16*)(ws + SLOT);        // 3 slots
    bf16* s_aw    = (bf16*)(ws + 4 * SLOT);
    bf16* s_xattn = (bf16*)(ws + SLOT);        // reuse qkv slot 1
    bf16* s_dwg   = (bf16*)(ws + 2 * SLOT);
    bf16* s_xf    = (bf16*)(ws + 4 * SLOT);    // reuse aw (combine fused into pw gemm)
    bf16* s_xf2   = (bf16*)(ws + 3 * SLOT);
    bf16* s_x2    = (bf16*)(ws);               // reuse xn (xn dead after pw+combine)
    bf16* s_hn    = (bf16*)(ws + 2 * SLOT);
    bf16* s_h1    = (bf16*)(ws + 3 * SLOT);    // spans slots 3..4 (384 ch)

    float* colsum  = (float*)(ws + 5 * SLOT);
    float* gatebuf = colsum + BB * CC;
    bf16*  mean_h  = (bf16*)(gatebuf + BB * CC);
    bf16*  mean_w  = mean_h + (size_t)BB * 56 * CC;
    float* a_t     = (float*)(mean_w + (size_t)BB * 56 * CC);
    float* a_s     = a_t + (size_t)BB * CC * 56;
    // bf16 weight copies
    bf16* wb_qkv  = (bf16*)(a_s + (size_t)BB * CC * 56);
    bf16* wb_proj = wb_qkv  + C3 * CC;
    bf16* wb_pw   = wb_proj + CC * CC;
    bf16* wb_fuse = wb_pw   + CC * CC;
    bf16* wb_mlp1 = wb_fuse + CC * CC;
    bf16* wb_mlp2 = wb_mlp1 + HIDN * CC;
    bf16* wb_temp = wb_mlp2 + CC * HIDN;
    bf16* wb_spec = wb_temp + CC * CC;
    char* after_w = (char*)(wb_spec + CC * CC);
    size_t total_need = after_w - ws;
    if (ws_size < total_need) return;   // workspace insufficient — visible failure
    // optional bf16 copy of x (saves 115 MB of f32 resid traffic in fuse GEMM)
    bf16* s_xb = (bf16*)after_w;
    bool have_xb = (ws_size >= total_need + SLOT);

    const int VEC_BLOCKS = MM * 24 / 256;   // 9408, exact
    const int CVT_N0 = C3 * CC, CVT_N1 = CC * CC, CVT_N4 = HIDN * CC;
    const int CVT_TOTAL = CVT_N0 + 5 * CVT_N1 + 2 * CVT_N4;

    // 0. all weight conversions in one launch
    cvt8_kernel<<<(CVT_TOTAL + 255) / 256, 256, 0, stream>>>(
        qkv_w, wb_qkv, CVT_N0, proj_w, wb_proj, CVT_N1, pw_w, wb_pw, CVT_N1,
        fuse_w, wb_fuse, CVT_N1, mlp1_w, wb_mlp1, CVT_N4, mlp2_w, wb_mlp2, CVT_N4,
        temp_w, wb_temp, CVT_N1, spec_w, wb_spec, CVT_N1);

    // 1. LN1 (+ optional bf16 x copy)
    ln_kernel<float><<<MM / 4, 256, 0, stream>>>(x, ln1_g, ln1_b, s_xn,
                                                 have_xb ? s_xb : nullptr);
    // 2. qkv
    mfma_gemm<0, false, C3, CC, bf16, bf16><<<dim3(C3 / 64, MM / 128), 256, 0, stream>>>(
        s_xn, wb_qkv, qkv_b, (const bf16*)nullptr, s_qkv, nullptr, nullptr);
    // 3. window attention (swapped QK^T, P in registers)
    winattn_kernel<<<NWIN * NHEAD / 4, 256, 0, stream>>>(s_qkv, s_aw);
    // 4. proj
    mfma_gemm<0, false, CC, CC, bf16, bf16><<<dim3(CC / 64, MM / 128), 256, 0, stream>>>(
        s_aw, wb_proj, proj_b, (const bf16*)nullptr, s_xattn, nullptr, nullptr);
    // 5. depthwise + gelu (vec8)
    dwconv_kernel<<<VEC_BLOCKS, 256, 0, stream>>>(s_xn, dw_w, s_dwg);
    // 6. gate (needs only xn)
    hipMemsetAsync(colsum, 0, BB * CC * sizeof(float), stream);
    colsum_kernel<<<dim3(16, BB), 192, 0, stream>>>(s_xn, colsum);
    gate_kernel<<<BB, 192, 0, stream>>>(colsum, gate_w, gate_b, gatebuf);
    // 7. pointwise + fused combine: xf = dwg@pw^T + xattn + xn*gate
    mfma_gemm<2, false, CC, CC, bf16, bf16><<<dim3(CC / 64, MM / 128), 256, 0, stream>>>(
        s_dwg, wb_pw, (const float*)nullptr, s_xattn, s_xf, s_xn, gatebuf);
    // 8. axis means (one launch, bf16 out)
    means_kernel<<<(2 * BB * WW * 24) / 256, 256, 0, stream>>>(s_xf, mean_h, mean_w);
    // 9. both axis softmaxes via MFMA (bias cancels under softmax)
    axmfma_kernel<<<dim3(BB, 2), 256, 0, stream>>>(
        mean_h, wb_temp, a_t, mean_w, wb_spec, a_s);
    // 10. modulate (coalesced)
    modulate_kernel<<<VEC_BLOCKS, 256, 0, stream>>>(s_xf, a_s, a_t, s_xf2);
    // 11. fuse (no bias) + residual x -> x2 (bf16 resid if workspace allows)
    if (have_xb)
        mfma_gemm<0, true, CC, CC, bf16, bf16><<<dim3(CC / 64, MM / 128), 256, 0, stream>>>(
            s_xf2, wb_fuse, (const float*)nullptr, s_xb, s_x2, nullptr, nullptr);
    else
        mfma_gemm<0, true, CC, CC, float, bf16><<<dim3(CC / 64, MM / 128), 256, 0, stream>>>(
            s_xf2, wb_fuse, (const float*)nullptr, x, s_x2, nullptr, nullptr);
    // 12. LN2
    ln_kernel<bf16><<<MM / 4, 256, 0, stream>>>(s_x2, ln2_g, ln2_b, s_hn, nullptr);
    // 13. MLP1 + gelu
    mfma_gemm<1, false, HIDN, CC, bf16, bf16><<<dim3(HIDN / 64, MM / 128), 256, 0, stream>>>(
        s_hn, wb_mlp1, mlp1_b, (const bf16*)nullptr, s_h1, nullptr, nullptr);
    // 14. MLP2 + residual -> out (f32)
    mfma_gemm<0, true, CC, HIDN, bf16, float><<<dim3(CC / 64, MM / 128), 256, 0, stream>>>(
        s_h1, wb_mlp2, mlp2_b, s_x2, out, nullptr, nullptr);
}

// Round 12
// 367.976 us; speedup vs baseline: 4.6055x; 1.0181x over previous
//
#include <hip/hip_runtime.h>
#include <hip/hip_bf16.h>

typedef __hip_bfloat16 bf16;

// Problem constants (B=32, H=W=56, C=192, NH=6, WS=7)
#define BB 32
#define HH 56
#define WW 56
#define CC 192
#define LL 3136            // 56*56
#define MM (BB*LL)         // 100352 tokens
#define C3 576
#define HIDN 384
#define NHEAD 6
#define HD 32
#define NWIN 2048          // B * 8*8

typedef short short8 __attribute__((ext_vector_type(8)));
typedef float f32x4 __attribute__((ext_vector_type(4)));

__device__ __forceinline__ float us2f(unsigned short u) {
    union { unsigned int i; float f; } v; v.i = ((unsigned int)u) << 16; return v.f;
}
__device__ __forceinline__ float b2f(bf16 h) { return __bfloat162float(h); }
__device__ __forceinline__ bf16 f2b(float f) { return __float2bfloat16(f); }
__device__ __forceinline__ short f2bs(float f) { bf16 h = f2b(f); return *reinterpret_cast<short*>(&h); }
__device__ __forceinline__ unsigned pk2(float a, float b) {
    return (unsigned)(unsigned short)f2bs(a) | ((unsigned)(unsigned short)f2bs(b) << 16);
}
__device__ __forceinline__ float ldv(const bf16* p) { return b2f(*p); }
__device__ __forceinline__ float ldv(const float* p) { return *p; }
__device__ __forceinline__ void stv(bf16* p, float v) { *p = f2b(v); }
__device__ __forceinline__ void stv(float* p, float v) { *p = v; }
__device__ __forceinline__ float gelu_exact(float x) {
    return 0.5f * x * (1.0f + erff(x * 0.70710678118654752f));
}
__device__ __forceinline__ void async_lds16(const void* g, void* l) {
    __builtin_amdgcn_global_load_lds(
        (const __attribute__((address_space(1))) void*)g,
        (__attribute__((address_space(3))) void*)l, 16, 0, 0);
}

// ---------------- f32 -> bf16 conversion of all 8 weight matrices in one launch ------
__global__ __launch_bounds__(256)
void cvt8_kernel(const float* __restrict__ s0, bf16* __restrict__ d0, int n0,
                 const float* __restrict__ s1, bf16* __restrict__ d1, int n1,
                 const float* __restrict__ s2, bf16* __restrict__ d2, int n2,
                 const float* __restrict__ s3, bf16* __restrict__ d3, int n3,
                 const float* __restrict__ s4, bf16* __restrict__ d4, int n4,
                 const float* __restrict__ s5, bf16* __restrict__ d5, int n5,
                 const float* __restrict__ s6, bf16* __restrict__ d6, int n6,
                 const float* __restrict__ s7, bf16* __restrict__ d7, int n7)
{
    int i = blockIdx.x * 256 + threadIdx.x;
    if (i < n0) { d0[i] = f2b(s0[i]); return; } i -= n0;
    if (i < n1) { d1[i] = f2b(s1[i]); return; } i -= n1;
    if (i < n2) { d2[i] = f2b(s2[i]); return; } i -= n2;
    if (i < n3) { d3[i] = f2b(s3[i]); return; } i -= n3;
    if (i < n4) { d4[i] = f2b(s4[i]); return; } i -= n4;
    if (i < n5) { d5[i] = f2b(s5[i]); return; } i -= n5;
    if (i < n6) { d6[i] = f2b(s6[i]); return; } i -= n6;
    if (i < n7) { d7[i] = f2b(s7[i]); }
}

// ---------------- LayerNorm: one wave per row; optionally also emit bf16 copy of in --
template<typename IT>
__global__ __launch_bounds__(256)
void ln_kernel(const IT* __restrict__ in, const float* __restrict__ g,
               const float* __restrict__ bvec, bf16* __restrict__ out,
               bf16* __restrict__ xcopy)
{
    int wid = threadIdx.x >> 6, lane = threadIdx.x & 63;
    int row = blockIdx.x * 4 + wid;
    const IT* p = in + (size_t)row * CC;
    float x0 = ldv(p + lane);
    float x1 = ldv(p + lane + 64);
    float x2 = ldv(p + lane + 128);
    float s  = x0 + x1 + x2;
    float sq = x0*x0 + x1*x1 + x2*x2;
    #pragma unroll
    for (int o = 32; o > 0; o >>= 1) {
        s  += __shfl_xor(s,  o, 64);
        sq += __shfl_xor(sq, o, 64);
    }
    float mean = s * (1.0f / CC);
    float var  = sq * (1.0f / CC) - mean * mean;
    float inv  = rsqrtf(fmaxf(var, 0.0f) + 1e-5f);
    bf16* q = out + (size_t)row * CC;
    q[lane]       = f2b((x0 - mean) * inv * g[lane]       + bvec[lane]);
    q[lane + 64]  = f2b((x1 - mean) * inv * g[lane + 64]  + bvec[lane + 64]);
    q[lane + 128] = f2b((x2 - mean) * inv * g[lane + 128] + bvec[lane + 128]);
    if (xcopy) {
        bf16* xq = xcopy + (size_t)row * CC;
        xq[lane]       = f2b(x0);
        xq[lane + 64]  = f2b(x1);
        xq[lane + 128] = f2b(x2);
    }
}

// ---------------- MFMA GEMM: out[M,NN] = epi(A[M,KK] @ W[NN,KK]^T + bias) ----
// EPI: 0=none, 1=gelu, 2=combine (out = acc + resid + b2f(xn2)*gate[b,c]).
// 256 threads = 4 waves, block tile 128x64, wave tile 32x64, BK=64.
// XCD-chunked block swizzle (bijective when nwg%8==0).
// bf16 output: C staged through (dead) As/Bs LDS -> 16B/lane coalesced stores.
template<int EPI, bool RESID, int NN, int KK, typename RT, typename OT>
__global__ __launch_bounds__(256)
void mfma_gemm(const bf16* __restrict__ A, const bf16* __restrict__ W,
               const float* __restrict__ bias, const RT* __restrict__ resid,
               OT* __restrict__ out,
               const bf16* __restrict__ xn2, const float* __restrict__ gate)
{
    __shared__ __align__(16) short Smem[128 * 64 + 64 * 64];   // As (8192) + Bs (4096)
    short* As = Smem;
    short* Bs = Smem + 128 * 64;
    const int t    = threadIdx.x;
    const int lane = t & 63;
    const int w    = t >> 6;        // wave 0..3
    const int nx   = gridDim.x;
    const int nwg  = gridDim.x * gridDim.y;
    int hw  = blockIdx.y * nx + blockIdx.x;
    int wid = (nwg & 7) ? hw : ((hw & 7) * (nwg >> 3) + (hw >> 3));
    const int m0   = (wid / nx) * 128;
    const int n0   = (wid % nx) * 64;
    const int lr   = lane & 15;     // row within 16
    const int lg   = lane >> 4;     // k-group 0..3

    f32x4 acc[2][4];
    #pragma unroll
    for (int i = 0; i < 2; ++i)
        #pragma unroll
        for (int j = 0; j < 4; ++j)
            acc[i][j] = (f32x4){0.f, 0.f, 0.f, 0.f};

    for (int k0 = 0; k0 < KK; k0 += 64) {
        const bf16* Ab = A + (size_t)m0 * KK + k0;
        const bf16* Wb = W + (size_t)n0 * KK + k0;
        #pragma unroll
        for (int li = 0; li < 4; ++li) {
            int chunk = li * 256 + t;
            int r = chunk >> 3, c = chunk & 7;
            int cs = c ^ (r & 7);
            async_lds16(Ab + (size_t)r * KK + (cs << 3),
                        &As[(li * 256 + w * 64) << 3]);
        }
        #pragma unroll
        for (int li = 0; li < 2; ++li) {
            int chunk = li * 256 + t;
            int r = chunk >> 3, c = chunk & 7;
            int cs = c ^ (r & 7);
            async_lds16(Wb + (size_t)r * KK + (cs << 3),
                        &Bs[(li * 256 + w * 64) << 3]);
        }
        __syncthreads();
        #pragma unroll
        for (int kf = 0; kf < 2; ++kf) {
            short8 a_[2], b_[4];
            #pragma unroll
            for (int mi = 0; mi < 2; ++mi) {
                int row = (w << 5) + (mi << 4) + lr;
                a_[mi] = *reinterpret_cast<const short8*>(
                    &As[(row << 6) + ((((kf << 2) + lg) ^ (row & 7)) << 3)]);
            }
            #pragma unroll
            for (int ni = 0; ni < 4; ++ni) {
                int rn = (ni << 4) + lr;
                b_[ni] = *reinterpret_cast<const short8*>(
                    &Bs[(rn << 6) + ((((kf << 2) + lg) ^ (rn & 7)) << 3)]);
            }
            #pragma unroll
            for (int mi = 0; mi < 2; ++mi)
                #pragma unroll
                for (int ni = 0; ni < 4; ++ni)
                    acc[mi][ni] = __builtin_amdgcn_mfma_f32_16x16x32_bf16(
                        a_[mi], b_[ni], acc[mi][ni], 0, 0, 0);
        }
        __syncthreads();
    }

    if constexpr (sizeof(OT) == 2) {
        // stage C in LDS (per-wave slice of dead As/Bs), then coalesced 16B stores
        short* cs = Smem + w * 3072;    // 32 rows x stride 72 = 2304 < 3072
        #pragma unroll
        for (int mi = 0; mi < 2; ++mi) {
            #pragma unroll
            for (int ni = 0; ni < 4; ++ni) {
                int col = n0 + (ni << 4) + lr;
                float bv = bias ? bias[col] : 0.f;
                #pragma unroll
                for (int r = 0; r < 4; ++r) {
                    int row = m0 + (w << 5) + (mi << 4) + (lg << 2) + r;
                    float c = acc[mi][ni][r] + bv;
                    if (EPI == 1) c = gelu_exact(c);
                    if (EPI == 2) {
                        int bidx = row / LL;
                        c += ldv(resid + (size_t)row * NN + col)
                           + b2f(xn2[(size_t)row * NN + col]) * gate[bidx * CC + col];
                    }
                    if (RESID) c += ldv(resid + (size_t)row * NN + col);
                    cs[((mi << 4) + (lg << 2) + r) * 72 + (ni << 4) + lr] = f2bs(c);
                }
            }
        }
        // same-wave DS ordering: no barrier needed
        #pragma unroll
        for (int pass = 0; pass < 4; ++pass) {
            int r8 = (lane >> 3) + (pass << 3);   // 0..31
            int c8 = lane & 7;
            uint4 v = *reinterpret_cast<const uint4*>(&cs[r8 * 72 + (c8 << 3)]);
            *reinterpret_cast<uint4*>((bf16*)out + (size_t)(m0 + (w << 5) + r8) * NN
                                      + n0 + (c8 << 3)) = v;
        }
    } else {
        #pragma unroll
        for (int mi = 0; mi < 2; ++mi) {
            #pragma unroll
            for (int ni = 0; ni < 4; ++ni) {
                int col = n0 + (ni << 4) + lr;
                float bv = bias ? bias[col] : 0.f;
                #pragma unroll
                for (int r = 0; r < 4; ++r) {
                    int row = m0 + (w << 5) + (mi << 4) + (lg << 2) + r;
                    float c = acc[mi][ni][r] + bv;
                    if (EPI == 1) c = gelu_exact(c);
                    if (EPI == 2) {
                        int bidx = row / LL;
                        c += ldv(resid + (size_t)row * NN + col)
                           + b2f(xn2[(size_t)row * NN + col]) * gate[bidx * CC + col];
                    }
                    if (RESID) c += ldv(resid + (size_t)row * NN + col);
                    stv(out + (size_t)row * NN + col, c);
                }
            }
        }
    }
}

// ---------------- MFMA window attention v4: swapped QK^T, P in registers -------------
// 4 waves/block, one (window,head)/wave, no barriers.
__global__ __launch_bounds__(256)
void winattn_kernel(const bf16* __restrict__ qkv, bf16* __restrict__ aw)
{
    __shared__ __align__(16) short Buf[4][2560];

    const int w  = threadIdx.x >> 6;     // wave in block
    const int t  = threadIdx.x & 63;     // lane
    const int p  = blockIdx.x * 4 + w;   // pair index
    const int wi = p / 6;
    const int head = p - wi * 6;
    const int b  = wi >> 6;
    const int wr = wi & 63;
    const int wy = wr >> 3, wx = wr & 7;
    const int lc = t & 15;
    const int lg = t >> 4;
    const float scale = 0.1767766952966369f;   // 32^-0.5
    const bf16* qbase = qkv + (size_t)b * LL * C3 + head * HD;
    short* buf = Buf[w];

    // zero Vt region keys 48..63 (chunk-swizzled)
    #pragma unroll
    for (int e = t; e < 512; e += 64) {
        int d = e >> 4, k = 48 + (e & 15);
        buf[(d << 6) + (((k >> 3) ^ (d & 7)) << 3) + (k & 7)] = 0;
    }
    // stage V: Vt[d][k=tok], chunk-XOR swizzled, row stride 64 shorts
    for (int e = t; e < 196; e += 64) {
        int tok = e >> 2, part = e & 3;
        int iy = tok / 7, ix = tok - iy * 7;
        size_t l = (size_t)(wy * 7 + iy) * 56 + wx * 7 + ix;
        uint4 pv = *reinterpret_cast<const uint4*>(qbase + l * C3 + 384 + (part << 3));
        unsigned short uv[8];
        *reinterpret_cast<uint4*>(uv) = pv;
        #pragma unroll
        for (int jj = 0; jj < 8; ++jj) {
            int d = (part << 3) + jj;
            buf[(d << 6) + (((tok >> 3) ^ (d & 7)) << 3) + (tok & 7)] = (short)uv[jj];
        }
    }

    // K (A-frag) and Q (B-frag) direct from global (predicated)
    const short8 zero8 = {0, 0, 0, 0, 0, 0, 0, 0};
    short8 ka[4], qb[4];
    #pragma unroll
    for (int mi = 0; mi < 4; ++mi) {
        int key = (mi << 4) + lc;
        ka[mi] = zero8;
        if (key < 49) {
            int iy = key / 7, ix = key - iy * 7;
            size_t l = (size_t)(wy * 7 + iy) * 56 + wx * 7 + ix;
            ka[mi] = *reinterpret_cast<const short8*>(qbase + l * C3 + 192 + (lg << 3));
        }
    }
    #pragma unroll
    for (int nj = 0; nj < 4; ++nj) {
        int tok = (nj << 4) + lc;
        qb[nj] = zero8;
        if (tok < 49) {
            int iy = tok / 7, ix = tok - iy * 7;
            size_t l = (size_t)(wy * 7 + iy) * 56 + wx * 7 + ix;
            qb[nj] = *reinterpret_cast<const short8*>(qbase + l * C3 + (lg << 3));
        }
    }

    // S^T = K Q^T : acc[mi(key-tile)][nj(tok-tile)]
    f32x4 acc[4][4];
    #pragma unroll
    for (int i = 0; i < 4; ++i)
        #pragma unroll
        for (int j = 0; j < 4; ++j)
            acc[i][j] = (f32x4){0.f, 0.f, 0.f, 0.f};
    #pragma unroll
    for (int mi = 0; mi < 4; ++mi)
        #pragma unroll
        for (int nj = 0; nj < 4; ++nj)
            acc[mi][nj] = __builtin_amdgcn_mfma_f32_16x16x32_bf16(
                ka[mi], qb[nj], acc[mi][nj], 0, 0, 0);

    // softmax over keys (rows). keys mi<3 all valid; mi==3: only key 48 (lg==0,r==0).
    float rinv[4];
    #pragma unroll
    for (int nj = 0; nj < 4; ++nj) {
        float mx = acc[0][nj][0];
        #pragma unroll
        for (int mi = 0; mi < 3; ++mi)
            #pragma unroll
            for (int r = 0; r < 4; ++r)
                mx = fmaxf(mx, acc[mi][nj][r]);
        float v48 = (lg == 0) ? acc[3][nj][0] : -1e30f;
        mx = fmaxf(mx, v48);
        mx = fmaxf(mx, __shfl_xor(mx, 16, 64));
        mx = fmaxf(mx, __shfl_xor(mx, 32, 64));
        float sm = 0.f;
        #pragma unroll
        for (int mi = 0; mi < 3; ++mi)
            #pragma unroll
            for (int r = 0; r < 4; ++r) {
                float e = __expf(scale * (acc[mi][nj][r] - mx));
                acc[mi][nj][r] = e;
                sm += e;
            }
        float e48 = (lg == 0) ? __expf(scale * (acc[3][nj][0] - mx)) : 0.f;
        acc[3][nj][0] = e48; sm += e48;
        acc[3][nj][1] = 0.f; acc[3][nj][2] = 0.f; acc[3][nj][3] = 0.f;
        sm += __shfl_xor(sm, 16, 64);
        sm += __shfl_xor(sm, 32, 64);
        rinv[nj] = 1.0f / sm;
    }

    // O^T = V^T P^T : acc2[mi2(d-tile)][nj(tok-tile)]
    f32x4 acc2[2][4];
    #pragma unroll
    for (int i = 0; i < 2; ++i)
        #pragma unroll
        for (int j = 0; j < 4; ++j)
            acc2[i][j] = (f32x4){0.f, 0.f, 0.f, 0.f};
    const int src0 = ((lg & 1) << 5) + lc;
    const int src1 = src0 + 16;
    const bool hi = (lg >> 1) != 0;
    #pragma unroll
    for (int kf = 0; kf < 2; ++kf) {
        short8 av[2];
        #pragma unroll
        for (int mi2 = 0; mi2 < 2; ++mi2) {
            int d = (mi2 << 4) + lc;
            av[mi2] = *reinterpret_cast<const short8*>(
                &buf[(d << 6) + ((((kf << 2) + lg) ^ (d & 7)) << 3)]);
        }
        #pragma unroll
        for (int nj = 0; nj < 4; ++nj) {
            unsigned A0 = pk2(acc[2*kf][nj][0],   acc[2*kf][nj][1]);
            unsigned A1 = pk2(acc[2*kf][nj][2],   acc[2*kf][nj][3]);
            unsigned B0 = pk2(acc[2*kf+1][nj][0], acc[2*kf+1][nj][1]);
            unsigned B1 = pk2(acc[2*kf+1][nj][2], acc[2*kf+1][nj][3]);
            unsigned xa0 = __shfl(A0, src0, 64), xa1 = __shfl(A1, src0, 64);
            unsigned xa2 = __shfl(A0, src1, 64), xa3 = __shfl(A1, src1, 64);
            unsigned xb0 = __shfl(B0, src0, 64), xb1 = __shfl(B1, src0, 64);
            unsigned xb2 = __shfl(B0, src1, 64), xb3 = __shfl(B1, src1, 64);
            union { unsigned u[4]; short8 s; } ub;
            ub.u[0] = hi ? xb0 : xa0;
            ub.u[1] = hi ? xb1 : xa1;
            ub.u[2] = hi ? xb2 : xa2;
            ub.u[3] = hi ? xb3 : xa3;
            #pragma unroll
            for (int mi2 = 0; mi2 < 2; ++mi2)
                acc2[mi2][nj] = __builtin_amdgcn_mfma_f32_16x16x32_bf16(
                    av[mi2], ub.s, acc2[mi2][nj], 0, 0, 0);
        }
    }

    // normalized O -> Os[tok][d] (stride 40 shorts), then coalesced 16B stores.
    #pragma unroll
    for (int mi2 = 0; mi2 < 2; ++mi2)
        #pragma unroll
        for (int nj = 0; nj < 4; ++nj) {
            int tokrow = (nj << 4) + lc;
            #pragma unroll
            for (int r = 0; r < 4; ++r) {
                int d = (mi2 << 4) + (lg << 2) + r;
                buf[tokrow * 40 + d] = f2bs(acc2[mi2][nj][r] * rinv[nj]);
            }
        }
    for (int e = t; e < 196; e += 64) {
        int tok = e >> 2, part = e & 3;
        int iy = tok / 7, ix = tok - iy * 7;
        size_t l = (size_t)(wy * 7 + iy) * 56 + wx * 7 + ix;
        *reinterpret_cast<uint4*>(aw + ((size_t)b * LL + l) * CC + head * HD + (part << 3)) =
            *reinterpret_cast<const uint4*>(&buf[tok * 40 + (part << 3)]);
    }
}

// ---------------- Depthwise 3x3 (SAME) + exact GELU, vectorized 8-ch/thread ----------
__global__ __launch_bounds__(256)
void dwconv_kernel(const bf16* __restrict__ xn, const float* __restrict__ w,
                   bf16* __restrict__ out)
{
    __shared__ float wl[9 * 288];
    const int t = threadIdx.x;
    for (int i = t; i < CC * 9; i += 256) {
        int c = i / 9, k = i - c * 9;
        wl[k * 288 + (c >> 3) * 12 + (c & 7)] = w[i];
    }
    __syncthreads();
    int e = blockIdx.x * 256 + t;          // 0 .. MM*24-1 (exact grid)
    int cg = e % 24;
    int pix = e / 24;
    int w_ = pix % WW;
    int t2 = pix / WW;
    int h_ = t2 % HH;
    int b  = t2 / HH;
    float acc[8] = {0.f,0.f,0.f,0.f,0.f,0.f,0.f,0.f};
    const bf16* rowbase = xn + ((size_t)b * HH * WW) * CC + (size_t)cg * 8;
    #pragma unroll
    for (int ky = 0; ky < 3; ++ky) {
        int hy = h_ + ky - 1;
        if (hy < 0 || hy >= HH) continue;
        #pragma unroll
        for (int kx = 0; kx < 3; ++kx) {
            int wx_ = w_ + kx - 1;
            if (wx_ < 0 || wx_ >= WW) continue;
            int k = ky * 3 + kx;
            const float4* wp = reinterpret_cast<const float4*>(&wl[k * 288 + cg * 12]);
            float4 w0 = wp[0];
            float4 w1 = wp[1];
            unsigned short u[8];
            *reinterpret_cast<uint4*>(u) = *reinterpret_cast<const uint4*>(
                rowbase + ((size_t)hy * WW + wx_) * CC);
            acc[0] += us2f(u[0]) * w0.x;
            acc[1] += us2f(u[1]) * w0.y;
            acc[2] += us2f(u[2]) * w0.z;
            acc[3] += us2f(u[3]) * w0.w;
            acc[4] += us2f(u[4]) * w1.x;
            acc[5] += us2f(u[5]) * w1.y;
            acc[6] += us2f(u[6]) * w1.z;
            acc[7] += us2f(u[7]) * w1.w;
        }
    }
    bf16 o8[8];
    #pragma unroll
    for (int j = 0; j < 8; ++j) o8[j] = f2b(gelu_exact(acc[j]));
    *reinterpret_cast<uint4*>(out + (size_t)e * 8) = *reinterpret_cast<uint4*>(o8);
}

// ---------------- column (spatial) sum of xn per (b, c) ----------------
__global__ __launch_bounds__(192)
void colsum_kernel(const bf16* __restrict__ xn, float* __restrict__ colsum)
{
    int b = blockIdx.y, g = blockIdx.x, c = threadIdx.x;
    float acc = 0.f;
    int l0 = g * 196;
    for (int l = l0; l < l0 + 196; ++l)
        acc += b2f(xn[((size_t)b * LL + l) * CC + c]);
    atomicAdd(&colsum[b * CC + c], acc);
}

__global__ __launch_bounds__(192)
void gate_kernel(const float* __restrict__ colsum, const float* __restrict__ gw,
                 const float* __restrict__ gb, float* __restrict__ gate)
{
    __shared__ float cm[CC];
    int b = blockIdx.x, o = threadIdx.x;
    cm[o] = colsum[b * CC + o] * (1.0f / LL);
    __syncthreads();
    float acc = gb[o];
    for (int c = 0; c < CC; ++c) acc += gw[o * CC + c] * cm[c];
    gate[b * CC + o] = 1.0f / (1.0f + expf(-acc));
}

// ---------------- means over H and W in one launch, vec8, bf16 out ----------------
__global__ __launch_bounds__(256)
void means_kernel(const bf16* __restrict__ xf, bf16* __restrict__ mh,
                  bf16* __restrict__ mw)
{
    int e = blockIdx.x * 256 + threadIdx.x;
    const int NHALF = BB * WW * 24;   // == BB*HH*24
    if (e < NHALF) {
        int cg = e % 24, c0 = cg << 3;
        int w_ = (e / 24) % WW;
        int b  = e / (24 * WW);
        float s[8] = {0.f,0.f,0.f,0.f,0.f,0.f,0.f,0.f};
        const bf16* base = xf + ((size_t)b * HH * WW + w_) * CC + c0;
        for (int h_ = 0; h_ < HH; ++h_) {
            unsigned short u[8];
            *reinterpret_cast<uint4*>(u) = *reinterpret_cast<const uint4*>(base + (size_t)h_ * WW * CC);
            #pragma unroll
            for (int j = 0; j < 8; ++j) s[j] += us2f(u[j]);
        }
        bf16 o8[8];
        #pragma unroll
        for (int j = 0; j < 8; ++j) o8[j] = f2b(s[j] * (1.0f / HH));
        *reinterpret_cast<uint4*>(mh + ((size_t)b * WW + w_) * CC + c0) =
            *reinterpret_cast<uint4*>(o8);
    } else {
        e -= NHALF;
        int cg = e % 24, c0 = cg << 3;
        int h_ = (e / 24) % HH;
        int b  = e / (24 * HH);
        float s[8] = {0.f,0.f,0.f,0.f,0.f,0.f,0.f,0.f};
        const bf16* base = xf + ((size_t)b * HH + h_) * WW * CC + c0;
        for (int w_ = 0; w_ < WW; ++w_) {
            unsigned short u[8];
            *reinterpret_cast<uint4*>(u) = *reinterpret_cast<const uint4*>(base + (size_t)w_ * CC);
            #pragma unroll
            for (int j = 0; j < 8; ++j) s[j] += us2f(u[j]);
        }
        bf16 o8[8];
        #pragma unroll
        for (int j = 0; j < 8; ++j) o8[j] = f2b(s[j] * (1.0f / WW));
        *reinterpret_cast<uint4*>(mw + ((size_t)b * HH + h_) * CC + c0) =
            *reinterpret_cast<uint4*>(o8);
    }
}

// ---------------- MFMA axis softmax: logits[o][pos] = W[o,:] . mean[b][pos,:] -------
__global__ __launch_bounds__(256)
void axmfma_kernel(const bf16* __restrict__ mh, const bf16* __restrict__ wt,
                   float* __restrict__ at,
                   const bf16* __restrict__ mw, const bf16* __restrict__ ws,
                   float* __restrict__ as_)
{
    const int b = blockIdx.x;
    const bf16* mean; const bf16* wmat; float* out;
    if (blockIdx.y == 0) { mean = mh; wmat = wt; out = at; }
    else                 { mean = mw; wmat = ws; out = as_; }
    const int w  = threadIdx.x >> 6;
    const int t  = threadIdx.x & 63;
    const int lc = t & 15, lg = t >> 4;
    const bf16* mb = mean + (size_t)b * 56 * CC;
    const short8 zero8 = {0, 0, 0, 0, 0, 0, 0, 0};

    f32x4 acc[3][4];
    #pragma unroll
    for (int i = 0; i < 3; ++i)
        #pragma unroll
        for (int j = 0; j < 4; ++j)
            acc[i][j] = (f32x4){0.f, 0.f, 0.f, 0.f};

    #pragma unroll
    for (int kf = 0; kf < 6; ++kf) {
        short8 a_[3], b_[4];
        #pragma unroll
        for (int mi = 0; mi < 3; ++mi) {
            int o = ((w * 3 + mi) << 4) + lc;
            a_[mi] = *reinterpret_cast<const short8*>(wmat + (size_t)o * CC + (kf << 5) + (lg << 3));
        }
        #pragma unroll
        for (int ni = 0; ni < 4; ++ni) {
            int pos = (ni << 4) + lc;
            b_[ni] = (pos < 56)
                ? *reinterpret_cast<const short8*>(mb + (size_t)pos * CC + (kf << 5) + (lg << 3))
                : zero8;
        }
        #pragma unroll
        for (int mi = 0; mi < 3; ++mi)
            #pragma unroll
            for (int ni = 0; ni < 4; ++ni)
                acc[mi][ni] = __builtin_amdgcn_mfma_f32_16x16x32_bf16(
                    a_[mi], b_[ni], acc[mi][ni], 0, 0, 0);
    }

    #pragma unroll
    for (int mi = 0; mi < 3; ++mi) {
        #pragma unroll
        for (int r = 0; r < 4; ++r) {
            float mx = -1e30f;
            #pragma unroll
            for (int ni = 0; ni < 4; ++ni) {
                float v = acc[mi][ni][r];
                if (ni == 3 && lc >= 8) v = -1e30f;
                mx = fmaxf(mx, v);
            }
            mx = fmaxf(mx, __shfl_xor(mx, 1, 64));
            mx = fmaxf(mx, __shfl_xor(mx, 2, 64));
            mx = fmaxf(mx, __shfl_xor(mx, 4, 64));
            mx = fmaxf(mx, __shfl_xor(mx, 8, 64));
            float e[4];
            float sm = 0.f;
            #pragma unroll
            for (int ni = 0; ni < 4; ++ni) {
                e[ni] = (ni == 3 && lc >= 8) ? 0.f : __expf(acc[mi][ni][r] - mx);
                sm += e[ni];
            }
            sm += __shfl_xor(sm, 1, 64);
            sm += __shfl_xor(sm, 2, 64);
            sm += __shfl_xor(sm, 4, 64);
            sm += __shfl_xor(sm, 8, 64);
            float inv = 1.0f / sm;
            int o = ((w * 3 + mi) << 4) + (lg << 2) + r;
            #pragma unroll
            for (int ni = 0; ni < 4; ++ni) {
                int pos = (ni << 4) + lc;
                if (pos < 56)
                    out[((size_t)b * 56 + pos) * CC + o] = e[ni] * inv;
            }
        }
    }
}

// ---------------- xf2 = xf * a_s[b,h,c] * a_t[b,w,c] * 2  (vec8, coalesced) ----------
__global__ __launch_bounds__(256)
void modulate_kernel(const bf16* __restrict__ xf, const float* __restrict__ a_s,
                     const float* __restrict__ a_t, bf16* __restrict__ xf2)
{
    int e = blockIdx.x * 256 + threadIdx.x;    // 0 .. MM*24-1
    int cg = e % 24, c0 = cg << 3;
    int pix = e / 24;
    int w_ = pix % WW;
    int t2 = pix / WW;
    int h_ = t2 % HH;
    int b  = t2 / HH;
    unsigned short u[8];
    size_t base = (size_t)e * 8;
    *reinterpret_cast<uint4*>(u) = *reinterpret_cast<const uint4*>(xf + base);
    const float4* sp = reinterpret_cast<const float4*>(a_s + ((size_t)b * 56 + h_) * CC + c0);
    const float4* tp = reinterpret_cast<const float4*>(a_t + ((size_t)b * 56 + w_) * CC + c0);
    float4 s0 = sp[0], s1 = sp[1];
    float4 t0 = tp[0], t1 = tp[1];
    float ss[8] = {s0.x, s0.y, s0.z, s0.w, s1.x, s1.y, s1.z, s1.w};
    float tt[8] = {t0.x, t0.y, t0.z, t0.w, t1.x, t1.y, t1.z, t1.w};
    bf16 o8[8];
    #pragma unroll
    for (int j = 0; j < 8; ++j)
        o8[j] = f2b(us2f(u[j]) * ss[j] * tt[j] * 2.0f);
    *reinterpret_cast<uint4*>(xf2 + base) = *reinterpret_cast<uint4*>(o8);
}

// =======================================================================================
extern "C" void kernel_launch(void* const* d_in, const int* in_sizes, int n_in,
                              void* d_out, int out_size, void* d_ws, size_t ws_size,
                              hipStream_t stream)
{
    const float* x      = (const float*)d_in[0];
    const float* ln1_g  = (const float*)d_in[3];
    const float* ln1_b  = (const float*)d_in[4];
    const float* qkv_w  = (const float*)d_in[5];
    const float* qkv_b  = (const float*)d_in[6];
    const float* proj_w = (const float*)d_in[7];
    const float* proj_b = (const float*)d_in[8];
    const float* dw_w   = (const float*)d_in[9];
    const float* pw_w   = (const float*)d_in[10];
    const float* gate_w = (const float*)d_in[11];
    const float* gate_b = (const float*)d_in[12];
    const float* temp_w = (const float*)d_in[13];
    const float* spec_w = (const float*)d_in[15];
    const float* fuse_w = (const float*)d_in[17];
    const float* ln2_g  = (const float*)d_in[18];
    const float* ln2_b  = (const float*)d_in[19];
    const float* mlp1_w = (const float*)d_in[20];
    const float* mlp1_b = (const float*)d_in[21];
    const float* mlp2_w = (const float*)d_in[22];
    const float* mlp2_b = (const float*)d_in[23];
    float* out = (float*)d_out;

    const size_t SLOT = (size_t)MM * CC * sizeof(bf16);   // 38,535,168 B
    char* ws = (char*)d_ws;

    bf16* s_xn    = (bf16*)(ws);
    bf16* s_qkv   = (bf16*)(ws + SLOT);        // 3 slots
    bf16* s_aw    = (bf16*)(ws + 4 * SLOT);
    bf16* s_xattn = (bf16*)(ws + SLOT);        // reuse qkv slot 1
    bf16* s_dwg   = (bf16*)(ws + 2 * SLOT);
    bf16* s_xf    = (bf16*)(ws + 4 * SLOT);    // reuse aw (combine fused into pw gemm)
    bf16* s_xf2   = (bf16*)(ws + 3 * SLOT);
    bf16* s_x2    = (bf16*)(ws);               // reuse xn (xn dead after pw+combine)
    bf16* s_hn    = (bf16*)(ws + 2 * SLOT);
    bf16* s_h1    = (bf16*)(ws + 3 * SLOT);    // spans slots 3..4 (384 ch)

    float* colsum  = (float*)(ws + 5 * SLOT);
    float* gatebuf = colsum + BB * CC;
    bf16*  mean_h  = (bf16*)(gatebuf + BB * CC);
    bf16*  mean_w  = mean_h + (size_t)BB * 56 * CC;
    float* a_t     = (float*)(mean_w + (size_t)BB * 56 * CC);
    float* a_s     = a_t + (size_t)BB * CC * 56;
    // bf16 weight copies
    bf16* wb_qkv  = (bf16*)(a_s + (size_t)BB * CC * 56);
    bf16* wb_proj = wb_qkv  + C3 * CC;
    bf16* wb_pw   = wb_proj + CC * CC;
    bf16* wb_fuse = wb_pw   + CC * CC;
    bf16* wb_mlp1 = wb_fuse + CC * CC;
    bf16* wb_mlp2 = wb_mlp1 + HIDN * CC;
    bf16* wb_temp = wb_mlp2 + CC * HIDN;
    bf16* wb_spec = wb_temp + CC * CC;
    char* after_w = (char*)(wb_spec + CC * CC);
    size_t total_need = after_w - ws;
    if (ws_size < total_need) return;   // workspace insufficient — visible failure
    // optional bf16 copy of x (saves 115 MB of f32 resid traffic in fuse GEMM)
    bf16* s_xb = (bf16*)after_w;
    bool have_xb = (ws_size >= total_need + SLOT);

    const int VEC_BLOCKS = MM * 24 / 256;   // 9408, exact
    const int CVT_N0 = C3 * CC, CVT_N1 = CC * CC, CVT_N4 = HIDN * CC;
    const int CVT_TOTAL = CVT_N0 + 5 * CVT_N1 + 2 * CVT_N4;

    // 0. all weight conversions in one launch
    cvt8_kernel<<<(CVT_TOTAL + 255) / 256, 256, 0, stream>>>(
        qkv_w, wb_qkv, CVT_N0, proj_w, wb_proj, CVT_N1, pw_w, wb_pw, CVT_N1,
        fuse_w, wb_fuse, CVT_N1, mlp1_w, wb_mlp1, CVT_N4, mlp2_w, wb_mlp2, CVT_N4,
        temp_w, wb_temp, CVT_N1, spec_w, wb_spec, CVT_N1);

    // 1. LN1 (+ optional bf16 x copy)
    ln_kernel<float><<<MM / 4, 256, 0, stream>>>(x, ln1_g, ln1_b, s_xn,
                                                 have_xb ? s_xb : nullptr);
    // 2. qkv
    mfma_gemm<0, false, C3, CC, bf16, bf16><<<dim3(C3 / 64, MM / 128), 256, 0, stream>>>(
        s_xn, wb_qkv, qkv_b, (const bf16*)nullptr, s_qkv, nullptr, nullptr);
    // 3. window attention (swapped QK^T, P in registers)
    winattn_kernel<<<NWIN * NHEAD / 4, 256, 0, stream>>>(s_qkv, s_aw);
    // 4. proj
    mfma_gemm<0, false, CC, CC, bf16, bf16><<<dim3(CC / 64, MM / 128), 256, 0, stream>>>(
        s_aw, wb_proj, proj_b, (const bf16*)nullptr, s_xattn, nullptr, nullptr);
    // 5. depthwise + gelu (vec8)
    dwconv_kernel<<<VEC_BLOCKS, 256, 0, stream>>>(s_xn, dw_w, s_dwg);
    // 6. gate (needs only xn)
    hipMemsetAsync(colsum, 0, BB * CC * sizeof(float), stream);
    colsum_kernel<<<dim3(16, BB), 192, 0, stream>>>(s_xn, colsum);
    gate_kernel<<<BB, 192, 0, stream>>>(colsum, gate_w, gate_b, gatebuf);
    // 7. pointwise + fused combine: xf = dwg@pw^T + xattn + xn*gate
    mfma_gemm<2, false, CC, CC, bf16, bf16><<<dim3(CC / 64, MM / 128), 256, 0, stream>>>(
        s_dwg, wb_pw, (const float*)nullptr, s_xattn, s_xf, s_xn, gatebuf);
    // 8. axis means (one launch, bf16 out)
    means_kernel<<<(2 * BB * WW * 24) / 256, 256, 0, stream>>>(s_xf, mean_h, mean_w);
    // 9. both axis softmaxes via MFMA (bias cancels under softmax)
    axmfma_kernel<<<dim3(BB, 2), 256, 0, stream>>>(
        mean_h, wb_temp, a_t, mean_w, wb_spec, a_s);
    // 10. modulate (coalesced)
    modulate_kernel<<<VEC_BLOCKS, 256, 0, stream>>>(s_xf, a_s, a_t, s_xf2);
    // 11. fuse (no bias) + residual x -> x2 (bf16 resid if workspace allows)
    if (have_xb)
        mfma_gemm<0, true, CC, CC, bf16, bf16><<<dim3(CC / 64, MM / 128), 256, 0, stream>>>(
            s_xf2, wb_fuse, (const float*)nullptr, s_xb, s_x2, nullptr, nullptr);
    else
        mfma_gemm<0, true, CC, CC, float, bf16><<<dim3(CC / 64, MM / 128), 256, 0, stream>>>(
            s_xf2, wb_fuse, (const float*)nullptr, x, s_x2, nullptr, nullptr);
    // 12. LN2
    ln_kernel<bf16><<<MM / 4, 256, 0, stream>>>(s_x2, ln2_g, ln2_b, s_hn, nullptr);
    // 13. MLP1 + gelu
    mfma_gemm<1, false, HIDN, CC, bf16, bf16><<<dim3(HIDN / 64, MM / 128), 256, 0, stream>>>(
        s_hn, wb_mlp1, mlp1_b, (const bf16*)nullptr, s_h1, nullptr, nullptr);
    // 14. MLP2 + residual -> out (f32)
    mfma_gemm<0, true, CC, HIDN, bf16, float><<<dim3(CC / 64, MM / 128), 256, 0, stream>>>(
        s_h1, wb_mlp2, mlp2_b, s_x2, out, nullptr, nullptr);
}